// Round 1
// baseline (973.395 us; speedup 1.0000x reference)
//
#include <hip/hip_runtime.h>
#include <math.h>

#define NQ    8192   // B*S
#define T3    48
#define INDIM 1024
#define HID   128
#define MSLOT 8192
#define HD    256
#define KBIG  48
#define KBASE 32
#define CHUNK 1024

// ---- workspace layout (bytes) ----
#define OFF_H    ((size_t)0)                         // 8192*48 f32   = 1,572,864
#define OFF_M2   ((size_t)1572864)                   // 8192 f32
#define OFF_CW   ((size_t)1605632)                   // 8192 f32
#define OFF_TOPV ((size_t)1638400)                   // 8192*48 f32
#define OFF_TOPI ((size_t)3211264)                   // 8192*48 i32
#define OFF_RMIN ((size_t)4784128)                   // 8192 f32
#define OFF_FLAG ((size_t)4816896)                   // 1 i32 (+pad)
#define OFF_ATT  ((size_t)4817152)                   // 8192*256 f32 = 8,388,608
#define OFF_DIST ((size_t)13205760)                  // CHUNK*8192 f32 = 33,554,432

__device__ __forceinline__ float gelu_exact(float x) {
    return 0.5f * x * (1.0f + erff(x * 0.70710678118654752f));
}

// ---- K0: m2[m] = ||mem_pos[m]||^2 ; cw[m] = exp(-alpha*||curv[m]||) ----
__global__ __launch_bounds__(256) void k0_prep(const float* __restrict__ pe,
        const float* __restrict__ curv, const float* __restrict__ alpha,
        float* __restrict__ m2, float* __restrict__ cw) {
    int m = blockIdx.x * 256 + threadIdx.x;
    float s = 0.f;
    for (int d = 0; d < T3; d++) { float v = pe[(size_t)m * T3 + d]; s += v * v; }
    m2[m] = s;
    float c = 0.f;
    for (int d = 0; d < 16; d++) { float v = curv[m * 16 + d]; c += v * v; }
    cw[m] = expf(-alpha[0] * sqrtf(c));
}

// ---- K1: h0 = x @ W_proj + b_proj  (8192x1024 @ 1024x48) ----
__global__ __launch_bounds__(256) void k1_proj(const float* __restrict__ x,
        const float* __restrict__ Wp, const float* __restrict__ bp,
        float* __restrict__ h0) {
    __shared__ float xs[128][65];
    __shared__ float ws[64][T3];
    int tid = threadIdx.x;
    int r0 = blockIdx.x * 128;
    int tr = tid >> 3, tc = tid & 7;           // 32 x 8
    float acc[4][6];
    #pragma unroll
    for (int i = 0; i < 4; i++)
        #pragma unroll
        for (int j = 0; j < 6; j++) acc[i][j] = 0.f;
    for (int k0 = 0; k0 < INDIM; k0 += 64) {
        for (int idx = tid; idx < 2048; idx += 256) {
            int r = idx >> 4, c4 = idx & 15;
            float4 v = *(const float4*)(x + (size_t)(r0 + r) * INDIM + k0 + c4 * 4);
            xs[r][c4 * 4 + 0] = v.x; xs[r][c4 * 4 + 1] = v.y;
            xs[r][c4 * 4 + 2] = v.z; xs[r][c4 * 4 + 3] = v.w;
        }
        for (int idx = tid; idx < 64 * T3; idx += 256) {
            int r = idx / T3, c = idx % T3;
            ws[r][c] = Wp[(size_t)(k0 + r) * T3 + c];
        }
        __syncthreads();
        #pragma unroll 8
        for (int kk = 0; kk < 64; kk++) {
            float a[4], b[6];
            #pragma unroll
            for (int i = 0; i < 4; i++) a[i] = xs[tr + 32 * i][kk];
            #pragma unroll
            for (int j = 0; j < 6; j++) b[j] = ws[kk][tc + 8 * j];
            #pragma unroll
            for (int i = 0; i < 4; i++)
                #pragma unroll
                for (int j = 0; j < 6; j++) acc[i][j] += a[i] * b[j];
        }
        __syncthreads();
    }
    #pragma unroll
    for (int i = 0; i < 4; i++)
        #pragma unroll
        for (int j = 0; j < 6; j++) {
            int row = r0 + tr + 32 * i, col = tc + 8 * j;
            h0[(size_t)row * T3 + col] = acc[i][j] + bp[col];
        }
}

// ---- K1b: per row: LN + GELU + 2 ODE steps (in place on h0) ----
__global__ __launch_bounds__(64) void k1b_ode(float* __restrict__ h,
        const float* __restrict__ g1, const float* __restrict__ b1ln,
        const float* __restrict__ W1, const float* __restrict__ bb1,
        const float* __restrict__ W2, const float* __restrict__ bb2) {
    __shared__ float hs[T3];
    __shared__ float t1s[HID];
    int lane = threadIdx.x;
    size_t row = blockIdx.x;
    float y = (lane < T3) ? h[row * T3 + lane] : 0.f;
    float s = (lane < T3) ? y : 0.f;
    #pragma unroll
    for (int off = 32; off; off >>= 1) s += __shfl_xor(s, off);
    float mean = s * (1.f / T3);
    float d = (lane < T3) ? (y - mean) : 0.f;
    float ss = d * d;
    #pragma unroll
    for (int off = 32; off; off >>= 1) ss += __shfl_xor(ss, off);
    float var = ss * (1.f / T3);
    float hv = 0.f;
    if (lane < T3) {
        float yn = d * rsqrtf(var + 1e-5f) * g1[lane] + b1ln[lane];
        hv = gelu_exact(yn);
        hs[lane] = hv;
    }
    __syncthreads();
    for (int step = 0; step < 2; step++) {
        #pragma unroll
        for (int half = 0; half < 2; half++) {
            int j = lane + 64 * half;
            float a = bb1[j];
            for (int dd = 0; dd < T3; dd++) a += hs[dd] * W1[dd * HID + j];
            t1s[j] = tanhf(a);
        }
        __syncthreads();
        if (lane < T3) {
            float a = bb2[lane];
            for (int j = 0; j < HID; j++) a += t1s[j] * W2[j * T3 + lane];
            hv = hv + 0.5f * a;
            hs[lane] = hv;
        }
        __syncthreads();
    }
    if (lane < T3) h[row * T3 + lane] = hv;
}

// ---- K2a: dist chunk = max(q2+m2-2 q.m, 0)*cw  (64q x 256m tiles) ----
__global__ __launch_bounds__(256) void k2a_dist(const float* __restrict__ h,
        const float* __restrict__ mp, const float* __restrict__ m2,
        const float* __restrict__ cw, float* __restrict__ dist, int rowbase) {
    __shared__ float qs[64][49];
    __shared__ float ms[256][49];
    __shared__ float q2s[64];
    int tid = threadIdx.x;
    int r0 = rowbase + blockIdx.y * 64;
    int c0 = blockIdx.x * 256;
    for (int idx = tid; idx < 64 * T3; idx += 256) {
        int r = idx / T3, c = idx % T3;
        qs[r][c] = h[(size_t)(r0 + r) * T3 + c];
    }
    for (int idx = tid; idx < 256 * T3; idx += 256) {
        int r = idx / T3, c = idx % T3;
        ms[r][c] = mp[(size_t)(c0 + r) * T3 + c];
    }
    __syncthreads();
    if (tid < 64) {
        float s = 0.f;
        for (int k = 0; k < T3; k++) { float v = qs[tid][k]; s += v * v; }
        q2s[tid] = s;
    }
    __syncthreads();
    int tr = tid >> 4, tc = tid & 15;          // 16 x 16
    float acc[4][16];
    #pragma unroll
    for (int i = 0; i < 4; i++)
        #pragma unroll
        for (int j = 0; j < 16; j++) acc[i][j] = 0.f;
    #pragma unroll 4
    for (int k = 0; k < T3; k++) {
        float a[4], b[16];
        #pragma unroll
        for (int i = 0; i < 4; i++) a[i] = qs[tr + 16 * i][k];
        #pragma unroll
        for (int j = 0; j < 16; j++) b[j] = ms[tc + 16 * j][k];
        #pragma unroll
        for (int i = 0; i < 4; i++)
            #pragma unroll
            for (int j = 0; j < 16; j++) acc[i][j] += a[i] * b[j];
    }
    int rl0 = blockIdx.y * 64;
    #pragma unroll
    for (int i = 0; i < 4; i++) {
        float q2 = q2s[tr + 16 * i];
        #pragma unroll
        for (int j = 0; j < 16; j++) {
            int rl = rl0 + tr + 16 * i;
            int col = c0 + tc + 16 * j;
            float dd = q2 + m2[col] - 2.f * acc[i][j];
            dd = fmaxf(dd, 0.f) * cw[col];
            dist[(size_t)rl * MSLOT + col] = dd;
        }
    }
}

// ---- K2b: exact per-row top-48 (ascending, index tie-break) ----
__global__ __launch_bounds__(256) void k2b_topk(const float* __restrict__ dist,
        float* __restrict__ topv, int* __restrict__ topi,
        float* __restrict__ rowmin, int rowbase) {
    __shared__ float vals[MSLOT];
    __shared__ unsigned long long head[256];
    __shared__ unsigned long long win_s;
    int tid = threadIdx.x;
    int rl = blockIdx.x;
    size_t row = (size_t)(rowbase + rl);
    const float4* src = (const float4*)(dist + (size_t)rl * MSLOT);
    for (int j = 0; j < 8; j++) {
        int idx = tid + 256 * j;
        float4 v = src[idx];
        vals[idx * 4 + 0] = v.x; vals[idx * 4 + 1] = v.y;
        vals[idx * 4 + 2] = v.z; vals[idx * 4 + 3] = v.w;
    }
    __syncthreads();
    unsigned long long hmin = ~0ULL;
    for (int j = 0; j < 32; j++) {
        int m = tid + 256 * j;
        unsigned long long p =
            ((unsigned long long)__float_as_uint(vals[m]) << 32) | (unsigned)m;
        hmin = p < hmin ? p : hmin;
    }
    head[tid] = hmin;
    __syncthreads();
    for (int k = 0; k < KBIG; k++) {
        if (tid < 64) {
            unsigned long long a = head[tid], b = head[tid + 64];
            unsigned long long c = head[tid + 128], dd = head[tid + 192];
            unsigned long long mn = a < b ? a : b;
            unsigned long long mn2 = c < dd ? c : dd;
            mn = mn < mn2 ? mn : mn2;
            #pragma unroll
            for (int off = 32; off; off >>= 1) {
                unsigned long long o = __shfl_xor(mn, off);
                mn = o < mn ? o : mn;
            }
            if (tid == 0) {
                win_s = mn;
                float v = __uint_as_float((unsigned)(mn >> 32));
                int m = (int)(mn & 0xFFFFFFFFULL);
                topv[row * KBIG + k] = v;
                topi[row * KBIG + k] = m;
                if (k == 0) rowmin[row] = v;
            }
        }
        __syncthreads();
        unsigned long long w = win_s;
        int wm = (int)(w & 0xFFFFFFFFULL);
        if ((wm & 255) == tid) {
            vals[wm] = __int_as_float(0x7F800000);   // +inf
            unsigned long long nm = ~0ULL;
            for (int j = 0; j < 32; j++) {
                int m = tid + 256 * j;
                unsigned long long p =
                    ((unsigned long long)__float_as_uint(vals[m]) << 32) | (unsigned)m;
                nm = p < nm ? p : nm;
            }
            head[tid] = nm;
        }
        __syncthreads();
    }
}

// ---- K3a: fire flag = (mean of row mins) < 0.7 ----
__global__ __launch_bounds__(256) void k3a_flag(const float* __restrict__ rowmin,
        int* __restrict__ flag) {
    __shared__ float red[256];
    int tid = threadIdx.x;
    float s = 0.f;
    for (int j = 0; j < NQ / 256; j++) s += rowmin[tid + 256 * j];
    red[tid] = s;
    __syncthreads();
    for (int st = 128; st; st >>= 1) {
        if (tid < st) red[tid] += red[tid + st];
        __syncthreads();
    }
    if (tid == 0) {
        float top1 = red[0] / (float)NQ;
        flag[0] = (top1 < 0.7f) ? 1 : 0;
    }
}

// ---- K3: softmax over kept + weighted gather of memory slots ----
__global__ __launch_bounds__(256) void k3_attend(const float* __restrict__ topv,
        const int* __restrict__ topi, const int* __restrict__ flag,
        const float* __restrict__ slots, float* __restrict__ att) {
    __shared__ float es[KBIG];
    __shared__ int is_[KBIG];
    int tid = threadIdx.x;
    size_t row = blockIdx.x;
    int kc = flag[0] ? KBIG : KBASE;
    float v0 = topv[row * KBIG];
    if (tid < KBIG) {
        float v = topv[row * KBIG + tid];
        es[tid] = (tid < kc) ? expf(-(v - v0)) : 0.f;
        is_[tid] = topi[row * KBIG + tid];
    }
    __syncthreads();
    float ssum = 0.f;
    for (int k = 0; k < kc; k++) ssum += es[k];
    float inv = 1.f / ssum;
    float acc = 0.f;
    for (int k = 0; k < kc; k++) {
        float wv = es[k] * inv;
        int m = is_[k];
        acc += wv * slots[(size_t)m * HD + tid];
    }
    att[row * HD + tid] = acc;
}

// ---- K4: z = att @ W_out + b_out -> d_out (pre-LN) ----
__global__ __launch_bounds__(256) void k4_out(const float* __restrict__ att,
        const float* __restrict__ Wo, const float* __restrict__ bo,
        float* __restrict__ out) {
    __shared__ float As[64][33];
    __shared__ float Bs[32][129];
    int tid = threadIdx.x;
    int c0 = blockIdx.x * 128;
    int r0 = blockIdx.y * 64;
    int tr = tid >> 4, tc = tid & 15;          // 16 x 16
    float acc[4][8];
    #pragma unroll
    for (int i = 0; i < 4; i++)
        #pragma unroll
        for (int j = 0; j < 8; j++) acc[i][j] = 0.f;
    for (int k0 = 0; k0 < HD; k0 += 32) {
        for (int idx = tid; idx < 512; idx += 256) {
            int r = idx >> 3, c4 = idx & 7;
            float4 v = *(const float4*)(att + (size_t)(r0 + r) * HD + k0 + c4 * 4);
            As[r][c4 * 4 + 0] = v.x; As[r][c4 * 4 + 1] = v.y;
            As[r][c4 * 4 + 2] = v.z; As[r][c4 * 4 + 3] = v.w;
        }
        for (int idx = tid; idx < 4096; idx += 256) {
            int r = idx >> 7, c = idx & 127;
            Bs[r][c] = Wo[(size_t)(k0 + r) * INDIM + c0 + c];
        }
        __syncthreads();
        #pragma unroll 8
        for (int kk = 0; kk < 32; kk++) {
            float a[4], b[8];
            #pragma unroll
            for (int i = 0; i < 4; i++) a[i] = As[tr + 16 * i][kk];
            #pragma unroll
            for (int j = 0; j < 8; j++) b[j] = Bs[kk][tc + 16 * j];
            #pragma unroll
            for (int i = 0; i < 4; i++)
                #pragma unroll
                for (int j = 0; j < 8; j++) acc[i][j] += a[i] * b[j];
        }
        __syncthreads();
    }
    #pragma unroll
    for (int i = 0; i < 4; i++)
        #pragma unroll
        for (int j = 0; j < 8; j++) {
            int row = r0 + tr + 16 * i, col = c0 + tc + 16 * j;
            out[(size_t)row * INDIM + col] = acc[i][j] + bo[col];
        }
}

// ---- K5: LN + GELU in place on d_out ----
__global__ __launch_bounds__(256) void k5_ln(float* __restrict__ out,
        const float* __restrict__ g, const float* __restrict__ b) {
    __shared__ float red[4];
    int tid = threadIdx.x;
    size_t row = blockIdx.x;
    float4 v = *(const float4*)(out + row * INDIM + tid * 4);
    float s = v.x + v.y + v.z + v.w;
    #pragma unroll
    for (int off = 32; off; off >>= 1) s += __shfl_xor(s, off);
    int wid = tid >> 6, lane = tid & 63;
    if (!lane) red[wid] = s;
    __syncthreads();
    float mean = (red[0] + red[1] + red[2] + red[3]) * (1.f / (float)INDIM);
    __syncthreads();
    float dx = v.x - mean, dy = v.y - mean, dz = v.z - mean, dw = v.w - mean;
    float ss = dx * dx + dy * dy + dz * dz + dw * dw;
    #pragma unroll
    for (int off = 32; off; off >>= 1) ss += __shfl_xor(ss, off);
    if (!lane) red[wid] = ss;
    __syncthreads();
    float var = (red[0] + red[1] + red[2] + red[3]) * (1.f / (float)INDIM);
    float rs = rsqrtf(var + 1e-5f);
    int c = tid * 4;
    float4 o;
    o.x = gelu_exact(dx * rs * g[c + 0] + b[c + 0]);
    o.y = gelu_exact(dy * rs * g[c + 1] + b[c + 1]);
    o.z = gelu_exact(dz * rs * g[c + 2] + b[c + 2]);
    o.w = gelu_exact(dw * rs * g[c + 3] + b[c + 3]);
    *(float4*)(out + row * INDIM + c) = o;
}

extern "C" void kernel_launch(void* const* d_in, const int* in_sizes, int n_in,
                              void* d_out, int out_size, void* d_ws, size_t ws_size,
                              hipStream_t stream) {
    const float* x     = (const float*)d_in[0];
    const float* Wp    = (const float*)d_in[1];
    const float* bp    = (const float*)d_in[2];
    const float* ln1g  = (const float*)d_in[3];
    const float* ln1b  = (const float*)d_in[4];
    const float* oW1   = (const float*)d_in[5];
    const float* ob1   = (const float*)d_in[6];
    const float* oW2   = (const float*)d_in[7];
    const float* ob2   = (const float*)d_in[8];
    const float* slots = (const float*)d_in[9];
    const float* pe    = (const float*)d_in[10];
    const float* curv  = (const float*)d_in[11];
    const float* alpha = (const float*)d_in[12];
    const float* Wo    = (const float*)d_in[13];
    const float* bo    = (const float*)d_in[14];
    const float* ln2g  = (const float*)d_in[15];
    const float* ln2b  = (const float*)d_in[16];
    float* out = (float*)d_out;
    char* ws = (char*)d_ws;

    float* h0     = (float*)(ws + OFF_H);
    float* m2     = (float*)(ws + OFF_M2);
    float* cwv    = (float*)(ws + OFF_CW);
    float* topv   = (float*)(ws + OFF_TOPV);
    int*   topi   = (int*)  (ws + OFF_TOPI);
    float* rowmin = (float*)(ws + OFF_RMIN);
    int*   flag   = (int*)  (ws + OFF_FLAG);
    float* att    = (float*)(ws + OFF_ATT);
    float* dist   = (float*)(ws + OFF_DIST);

    k0_prep<<<MSLOT / 256, 256, 0, stream>>>(pe, curv, alpha, m2, cwv);
    k1_proj<<<NQ / 128, 256, 0, stream>>>(x, Wp, bp, h0);
    k1b_ode<<<NQ, 64, 0, stream>>>(h0, ln1g, ln1b, oW1, ob1, oW2, ob2);
    for (int ch = 0; ch < NQ / CHUNK; ch++) {
        k2a_dist<<<dim3(32, 16), 256, 0, stream>>>(h0, pe, m2, cwv, dist, ch * CHUNK);
        k2b_topk<<<CHUNK, 256, 0, stream>>>(dist, topv, topi, rowmin, ch * CHUNK);
    }
    k3a_flag<<<1, 256, 0, stream>>>(rowmin, flag);
    k3_attend<<<NQ, 256, 0, stream>>>(topv, topi, flag, slots, att);
    k4_out<<<dim3(INDIM / 128, NQ / 64), 256, 0, stream>>>(att, Wo, bo, out);
    k5_ln<<<NQ, 256, 0, stream>>>(out, ln2g, ln2b);
}

// Round 2
// 814.477 us; speedup vs baseline: 1.1951x; 1.1951x over previous
//
#include <hip/hip_runtime.h>
#include <math.h>

#define NQ    8192   // B*S
#define T3    48
#define INDIM 1024
#define HID   128
#define MSLOT 8192
#define HD    256
#define KBIG  48
#define KBASE 32
#define CHUNK 1024

// ---- workspace layout (bytes) ----
#define OFF_H    ((size_t)0)                         // 8192*48 f32   = 1,572,864
#define OFF_M2   ((size_t)1572864)                   // 8192 f32
#define OFF_CW   ((size_t)1605632)                   // 8192 f32
#define OFF_TOPV ((size_t)1638400)                   // 8192*48 f32
#define OFF_TOPI ((size_t)3211264)                   // 8192*48 i32
#define OFF_RMIN ((size_t)4784128)                   // 8192 f32
#define OFF_FLAG ((size_t)4816896)                   // 1 i32 (+pad)
#define OFF_ATT  ((size_t)4817152)                   // 8192*256 f32 = 8,388,608
#define OFF_DIST ((size_t)13205760)                  // CHUNK*8192 f32 = 33,554,432
// hpart (4*8192*48 f32 = 6.3MB) aliases OFF_DIST: consumed by k1b before k2a writes dist

__device__ __forceinline__ float gelu_exact(float x) {
    return 0.5f * x * (1.0f + erff(x * 0.70710678118654752f));
}

__device__ __forceinline__ unsigned long long shfl_xor_u64(unsigned long long v, int off) {
    unsigned lo = (unsigned)v, hi = (unsigned)(v >> 32);
    lo = (unsigned)__shfl_xor((int)lo, off);
    hi = (unsigned)__shfl_xor((int)hi, off);
    return ((unsigned long long)hi << 32) | lo;
}

// ---- K0: m2[m] = ||mem_pos[m]||^2 ; cw[m] = exp(-alpha*||curv[m]||) ----
__global__ __launch_bounds__(256) void k0_prep(const float* __restrict__ pe,
        const float* __restrict__ curv, const float* __restrict__ alpha,
        float* __restrict__ m2, float* __restrict__ cw) {
    int m = blockIdx.x * 256 + threadIdx.x;
    float s = 0.f;
    for (int d = 0; d < T3; d++) { float v = pe[(size_t)m * T3 + d]; s += v * v; }
    m2[m] = s;
    float c = 0.f;
    for (int d = 0; d < 16; d++) { float v = curv[m * 16 + d]; c += v * v; }
    cw[m] = expf(-alpha[0] * sqrtf(c));
}

// ---- K1: hpart[slice] = x[:, slice*256:(slice+1)*256] @ Wp[slice rows] ----
__global__ __launch_bounds__(256) void k1_proj(const float* __restrict__ x,
        const float* __restrict__ Wp, float* __restrict__ hpart) {
    __shared__ float xs[64][65];
    __shared__ float ws[64][T3];
    int tid = threadIdx.x;
    int slice = blockIdx.x;            // 0..3
    int r0 = blockIdx.y * 64;
    int kbase = slice * 256;
    int tr = tid >> 3, tc = tid & 7;   // 32 x 8; rows {tr, tr+32}
    float acc[2][6];
    #pragma unroll
    for (int i = 0; i < 2; i++)
        #pragma unroll
        for (int j = 0; j < 6; j++) acc[i][j] = 0.f;
    for (int kt = 0; kt < 256; kt += 64) {
        int k0 = kbase + kt;
        for (int idx = tid; idx < 1024; idx += 256) {
            int r = idx >> 4, c4 = idx & 15;
            float4 v = *(const float4*)(x + (size_t)(r0 + r) * INDIM + k0 + c4 * 4);
            xs[r][c4 * 4 + 0] = v.x; xs[r][c4 * 4 + 1] = v.y;
            xs[r][c4 * 4 + 2] = v.z; xs[r][c4 * 4 + 3] = v.w;
        }
        for (int idx = tid; idx < 64 * T3; idx += 256) {
            int r = idx / T3, c = idx - r * T3;
            ws[r][c] = Wp[(size_t)(k0 + r) * T3 + c];
        }
        __syncthreads();
        #pragma unroll 8
        for (int kk = 0; kk < 64; kk++) {
            float a0 = xs[tr][kk], a1 = xs[tr + 32][kk];
            float b[6];
            #pragma unroll
            for (int j = 0; j < 6; j++) b[j] = ws[kk][tc + 8 * j];
            #pragma unroll
            for (int j = 0; j < 6; j++) {
                acc[0][j] += a0 * b[j];
                acc[1][j] += a1 * b[j];
            }
        }
        __syncthreads();
    }
    float* dst = hpart + (size_t)slice * NQ * T3;
    #pragma unroll
    for (int i = 0; i < 2; i++)
        #pragma unroll
        for (int j = 0; j < 6; j++)
            dst[(size_t)(r0 + tr + 32 * i) * T3 + tc + 8 * j] = acc[i][j];
}

// ---- K1b: 32 rows/block: sum partials + bias, LN, GELU, 2 ODE steps ----
__global__ __launch_bounds__(256) void k1b_ode(const float* __restrict__ hpart,
        const float* __restrict__ bp,
        const float* __restrict__ g1, const float* __restrict__ b1ln,
        const float* __restrict__ W1, const float* __restrict__ bb1,
        const float* __restrict__ W2, const float* __restrict__ bb2,
        float* __restrict__ h) {
    __shared__ float W1s[T3 * HID];    // 24KB
    __shared__ float W2s[HID * T3];    // 24KB
    __shared__ float hs[32 * T3];      // 6KB
    __shared__ float t1s[32 * HID];    // 16KB (also scratch for pre-LN y)
    int tid = threadIdx.x;
    size_t base = (size_t)blockIdx.x * 32 * T3;
    for (int idx = tid; idx < T3 * HID; idx += 256) {
        W1s[idx] = W1[idx];
        W2s[idx] = W2[idx];
    }
    for (int idx = tid; idx < 32 * T3; idx += 256) {
        int c = idx % T3;
        float a = bp[c];
        #pragma unroll
        for (int s = 0; s < 4; s++) a += hpart[(size_t)s * NQ * T3 + base + idx];
        t1s[idx] = a;
    }
    __syncthreads();
    // LN + GELU -> hs ; 8 lanes per row
    {
        int r = tid >> 3, c8 = tid & 7;
        float v[6];
        float ssum = 0.f;
        #pragma unroll
        for (int i = 0; i < 6; i++) { v[i] = t1s[r * T3 + c8 * 6 + i]; ssum += v[i]; }
        #pragma unroll
        for (int off = 1; off < 8; off <<= 1) ssum += __shfl_xor(ssum, off);
        float mean = ssum * (1.f / T3);
        float vv = 0.f;
        #pragma unroll
        for (int i = 0; i < 6; i++) { v[i] -= mean; vv += v[i] * v[i]; }
        #pragma unroll
        for (int off = 1; off < 8; off <<= 1) vv += __shfl_xor(vv, off);
        float rstd = rsqrtf(vv * (1.f / T3) + 1e-5f);
        #pragma unroll
        for (int i = 0; i < 6; i++) {
            int c = c8 * 6 + i;
            hs[r * T3 + c] = gelu_exact(v[i] * rstd * g1[c] + b1ln[c]);
        }
    }
    __syncthreads();
    for (int step = 0; step < 2; step++) {
        for (int idx = tid; idx < 32 * HID; idx += 256) {
            int rr = idx >> 7, j = idx & 127;
            float a = bb1[j];
            #pragma unroll 8
            for (int d = 0; d < T3; d++) a += hs[rr * T3 + d] * W1s[d * HID + j];
            t1s[idx] = tanhf(a);
        }
        __syncthreads();
        for (int idx = tid; idx < 32 * T3; idx += 256) {
            int rr = idx / T3, c = idx - rr * T3;
            float a = bb2[c];
            #pragma unroll 8
            for (int j = 0; j < HID; j++) a += t1s[rr * HID + j] * W2s[j * T3 + c];
            hs[idx] += 0.5f * a;
        }
        __syncthreads();
    }
    for (int idx = tid; idx < 32 * T3; idx += 256) h[base + idx] = hs[idx];
}

// ---- K2a: dist chunk = max(q2+m2-2 q.m, 0)*cw  (64q x 256m tiles) ----
__global__ __launch_bounds__(256) void k2a_dist(const float* __restrict__ h,
        const float* __restrict__ mp, const float* __restrict__ m2,
        const float* __restrict__ cw, float* __restrict__ dist, int rowbase) {
    __shared__ float qs[64][49];
    __shared__ float ms[256][49];
    __shared__ float q2s[64];
    int tid = threadIdx.x;
    int r0 = rowbase + blockIdx.y * 64;
    int c0 = blockIdx.x * 256;
    for (int idx = tid; idx < 64 * T3; idx += 256) {
        int r = idx / T3, c = idx - r * T3;
        qs[r][c] = h[(size_t)(r0 + r) * T3 + c];
    }
    for (int idx = tid; idx < 256 * T3; idx += 256) {
        int r = idx / T3, c = idx - r * T3;
        ms[r][c] = mp[(size_t)(c0 + r) * T3 + c];
    }
    __syncthreads();
    if (tid < 64) {
        float s = 0.f;
        for (int k = 0; k < T3; k++) { float v = qs[tid][k]; s += v * v; }
        q2s[tid] = s;
    }
    __syncthreads();
    int tr = tid >> 4, tc = tid & 15;          // 16 x 16
    float acc[4][16];
    #pragma unroll
    for (int i = 0; i < 4; i++)
        #pragma unroll
        for (int j = 0; j < 16; j++) acc[i][j] = 0.f;
    #pragma unroll 4
    for (int k = 0; k < T3; k++) {
        float a[4], b[16];
        #pragma unroll
        for (int i = 0; i < 4; i++) a[i] = qs[tr + 16 * i][k];
        #pragma unroll
        for (int j = 0; j < 16; j++) b[j] = ms[tc + 16 * j][k];
        #pragma unroll
        for (int i = 0; i < 4; i++)
            #pragma unroll
            for (int j = 0; j < 16; j++) acc[i][j] += a[i] * b[j];
    }
    int rl0 = blockIdx.y * 64;
    #pragma unroll
    for (int i = 0; i < 4; i++) {
        float q2 = q2s[tr + 16 * i];
        #pragma unroll
        for (int j = 0; j < 16; j++) {
            int rl = rl0 + tr + 16 * i;
            int col = c0 + tc + 16 * j;
            float dd = q2 + m2[col] - 2.f * acc[i][j];
            dd = fmaxf(dd, 0.f) * cw[col];
            dist[(size_t)rl * MSLOT + col] = dd;
        }
    }
}

// ---- K2b v2: per-wave sorted top-48 extraction + rank merge ----
__global__ __launch_bounds__(256) void k2b_topk(const float* __restrict__ dist,
        float* __restrict__ topv, int* __restrict__ topi,
        float* __restrict__ rowmin, int rowbase) {
    __shared__ float vals[MSLOT];                       // 32KB
    __shared__ unsigned long long wl[4][KBIG];          // 1.5KB
    int tid = threadIdx.x;
    int lane = tid & 63, wv = tid >> 6;
    int rl = blockIdx.x;
    size_t row = (size_t)(rowbase + rl);
    const float* src = dist + (size_t)rl * MSLOT;
    int base = wv * 2048;
    // load slice; build per-lane sorted-4 cache of u64 keys (valbits<<32 | idx)
    unsigned long long c0 = ~0ULL, c1 = ~0ULL, c2 = ~0ULL, c3 = ~0ULL;
    for (int j = 0; j < 32; j++) {
        int m = base + j * 64 + lane;
        float v = src[m];
        vals[m] = v;
        unsigned long long k = ((unsigned long long)__float_as_uint(v) << 32) | (unsigned)m;
        if (k < c3) {
            c3 = k;
            if (c3 < c2) { unsigned long long t = c2; c2 = c3; c3 = t;
                if (c2 < c1) { t = c1; c1 = c2; c2 = t;
                    if (c1 < c0) { t = c0; c0 = c1; c1 = t; } } }
        }
    }
    // extract wave-local top-48 in ascending order
    int p = 0;
    unsigned long long head = c0;
    for (int k = 0; k < KBIG; k++) {
        unsigned long long mn = head;
        #pragma unroll
        for (int off = 32; off; off >>= 1) {
            unsigned long long o = shfl_xor_u64(mn, off);
            mn = o < mn ? o : mn;
        }
        if (lane == 0) wl[wv][k] = mn;
        if (head == mn) {       // unique winner
            p++;
            if (p == 1) head = c1;
            else if (p == 2) head = c2;
            else if (p == 3) head = c3;
            else {
                unsigned long long nm = ~0ULL;
                for (int j = 0; j < 32; j++) {
                    int m = base + j * 64 + lane;
                    unsigned long long kk =
                        ((unsigned long long)__float_as_uint(vals[m]) << 32) | (unsigned)m;
                    if (kk > mn && kk < nm) nm = kk;
                }
                head = nm;
            }
        }
    }
    __syncthreads();
    // merge 4 sorted lists by rank (keys unique)
    if (tid < 4 * KBIG) {
        int l = tid / KBIG, pos = tid - l * KBIG;
        unsigned long long key = wl[l][pos];
        int rank = pos;
        #pragma unroll
        for (int ol = 0; ol < 4; ol++) {
            if (ol == l) continue;
            int lo = 0, hi = KBIG;
            while (lo < hi) {
                int mid = (lo + hi) >> 1;
                if (wl[ol][mid] < key) lo = mid + 1; else hi = mid;
            }
            rank += lo;
        }
        if (rank < KBIG) {
            float v = __uint_as_float((unsigned)(key >> 32));
            topv[row * KBIG + rank] = v;
            topi[row * KBIG + rank] = (int)(key & 0xFFFFFFFFu);
            if (rank == 0) rowmin[row] = v;
        }
    }
}

// ---- K3a: fire flag = (mean of row mins) < 0.7 ----
__global__ __launch_bounds__(256) void k3a_flag(const float* __restrict__ rowmin,
        int* __restrict__ flag) {
    __shared__ float red[256];
    int tid = threadIdx.x;
    float s = 0.f;
    for (int j = 0; j < NQ / 256; j++) s += rowmin[tid + 256 * j];
    red[tid] = s;
    __syncthreads();
    for (int st = 128; st; st >>= 1) {
        if (tid < st) red[tid] += red[tid + st];
        __syncthreads();
    }
    if (tid == 0) {
        float top1 = red[0] / (float)NQ;
        flag[0] = (top1 < 0.7f) ? 1 : 0;
    }
}

// ---- K3: softmax over kept + weighted gather of memory slots ----
__global__ __launch_bounds__(256) void k3_attend(const float* __restrict__ topv,
        const int* __restrict__ topi, const int* __restrict__ flag,
        const float* __restrict__ slots, float* __restrict__ att) {
    __shared__ float es[KBIG];
    __shared__ int is_[KBIG];
    int tid = threadIdx.x;
    size_t row = blockIdx.x;
    int kc = flag[0] ? KBIG : KBASE;
    float v0 = topv[row * KBIG];
    if (tid < KBIG) {
        float v = topv[row * KBIG + tid];
        es[tid] = (tid < kc) ? expf(-(v - v0)) : 0.f;
        is_[tid] = topi[row * KBIG + tid];
    }
    __syncthreads();
    float ssum = 0.f;
    for (int k = 0; k < kc; k++) ssum += es[k];
    float inv = 1.f / ssum;
    float acc = 0.f;
    for (int k = 0; k < kc; k++) {
        float wv = es[k] * inv;
        int m = is_[k];
        acc += wv * slots[(size_t)m * HD + tid];
    }
    att[row * HD + tid] = acc;
}

// ---- K4: z = att @ W_out + b_out -> d_out (pre-LN) ----
__global__ __launch_bounds__(256) void k4_out(const float* __restrict__ att,
        const float* __restrict__ Wo, const float* __restrict__ bo,
        float* __restrict__ out) {
    __shared__ float As[64][33];
    __shared__ float Bs[32][129];
    int tid = threadIdx.x;
    int c0 = blockIdx.x * 128;
    int r0 = blockIdx.y * 64;
    int tr = tid >> 4, tc = tid & 15;          // 16 x 16
    float acc[4][8];
    #pragma unroll
    for (int i = 0; i < 4; i++)
        #pragma unroll
        for (int j = 0; j < 8; j++) acc[i][j] = 0.f;
    for (int k0 = 0; k0 < HD; k0 += 32) {
        for (int idx = tid; idx < 512; idx += 256) {
            int r = idx >> 3, c4 = idx & 7;
            float4 v = *(const float4*)(att + (size_t)(r0 + r) * HD + k0 + c4 * 4);
            As[r][c4 * 4 + 0] = v.x; As[r][c4 * 4 + 1] = v.y;
            As[r][c4 * 4 + 2] = v.z; As[r][c4 * 4 + 3] = v.w;
        }
        for (int idx = tid; idx < 4096; idx += 256) {
            int r = idx >> 7, c = idx & 127;
            Bs[r][c] = Wo[(size_t)(k0 + r) * INDIM + c0 + c];
        }
        __syncthreads();
        #pragma unroll 8
        for (int kk = 0; kk < 32; kk++) {
            float a[4], b[8];
            #pragma unroll
            for (int i = 0; i < 4; i++) a[i] = As[tr + 16 * i][kk];
            #pragma unroll
            for (int j = 0; j < 8; j++) b[j] = Bs[kk][tc + 16 * j];
            #pragma unroll
            for (int i = 0; i < 4; i++)
                #pragma unroll
                for (int j = 0; j < 8; j++) acc[i][j] += a[i] * b[j];
        }
        __syncthreads();
    }
    #pragma unroll
    for (int i = 0; i < 4; i++)
        #pragma unroll
        for (int j = 0; j < 8; j++) {
            int row = r0 + tr + 16 * i, col = c0 + tc + 16 * j;
            out[(size_t)row * INDIM + col] = acc[i][j] + bo[col];
        }
}

// ---- K5: LN + GELU in place on d_out ----
__global__ __launch_bounds__(256) void k5_ln(float* __restrict__ out,
        const float* __restrict__ g, const float* __restrict__ b) {
    __shared__ float red[4];
    int tid = threadIdx.x;
    size_t row = blockIdx.x;
    float4 v = *(const float4*)(out + row * INDIM + tid * 4);
    float s = v.x + v.y + v.z + v.w;
    #pragma unroll
    for (int off = 32; off; off >>= 1) s += __shfl_xor(s, off);
    int wid = tid >> 6, lane = tid & 63;
    if (!lane) red[wid] = s;
    __syncthreads();
    float mean = (red[0] + red[1] + red[2] + red[3]) * (1.f / (float)INDIM);
    __syncthreads();
    float dx = v.x - mean, dy = v.y - mean, dz = v.z - mean, dw = v.w - mean;
    float ss = dx * dx + dy * dy + dz * dz + dw * dw;
    #pragma unroll
    for (int off = 32; off; off >>= 1) ss += __shfl_xor(ss, off);
    if (!lane) red[wid] = ss;
    __syncthreads();
    float var = (red[0] + red[1] + red[2] + red[3]) * (1.f / (float)INDIM);
    float rs = rsqrtf(var + 1e-5f);
    int c = tid * 4;
    float4 o;
    o.x = gelu_exact(dx * rs * g[c + 0] + b[c + 0]);
    o.y = gelu_exact(dy * rs * g[c + 1] + b[c + 1]);
    o.z = gelu_exact(dz * rs * g[c + 2] + b[c + 2]);
    o.w = gelu_exact(dw * rs * g[c + 3] + b[c + 3]);
    *(float4*)(out + row * INDIM + c) = o;
}

extern "C" void kernel_launch(void* const* d_in, const int* in_sizes, int n_in,
                              void* d_out, int out_size, void* d_ws, size_t ws_size,
                              hipStream_t stream) {
    const float* x     = (const float*)d_in[0];
    const float* Wp    = (const float*)d_in[1];
    const float* bp    = (const float*)d_in[2];
    const float* ln1g  = (const float*)d_in[3];
    const float* ln1b  = (const float*)d_in[4];
    const float* oW1   = (const float*)d_in[5];
    const float* ob1   = (const float*)d_in[6];
    const float* oW2   = (const float*)d_in[7];
    const float* ob2   = (const float*)d_in[8];
    const float* slots = (const float*)d_in[9];
    const float* pe    = (const float*)d_in[10];
    const float* curv  = (const float*)d_in[11];
    const float* alpha = (const float*)d_in[12];
    const float* Wo    = (const float*)d_in[13];
    const float* bo    = (const float*)d_in[14];
    const float* ln2g  = (const float*)d_in[15];
    const float* ln2b  = (const float*)d_in[16];
    float* out = (float*)d_out;
    char* ws = (char*)d_ws;

    float* h0     = (float*)(ws + OFF_H);
    float* m2     = (float*)(ws + OFF_M2);
    float* cwv    = (float*)(ws + OFF_CW);
    float* topv   = (float*)(ws + OFF_TOPV);
    int*   topi   = (int*)  (ws + OFF_TOPI);
    float* rowmin = (float*)(ws + OFF_RMIN);
    int*   flag   = (int*)  (ws + OFF_FLAG);
    float* att    = (float*)(ws + OFF_ATT);
    float* dist   = (float*)(ws + OFF_DIST);
    float* hpart  = dist;   // aliased: consumed before dist is produced

    k0_prep<<<MSLOT / 256, 256, 0, stream>>>(pe, curv, alpha, m2, cwv);
    k1_proj<<<dim3(4, NQ / 64), 256, 0, stream>>>(x, Wp, hpart);
    k1b_ode<<<NQ / 32, 256, 0, stream>>>(hpart, bp, ln1g, ln1b, oW1, ob1, oW2, ob2, h0);
    for (int ch = 0; ch < NQ / CHUNK; ch++) {
        k2a_dist<<<dim3(32, 16), 256, 0, stream>>>(h0, pe, m2, cwv, dist, ch * CHUNK);
        k2b_topk<<<CHUNK, 256, 0, stream>>>(dist, topv, topi, rowmin, ch * CHUNK);
    }
    k3a_flag<<<1, 256, 0, stream>>>(rowmin, flag);
    k3_attend<<<NQ, 256, 0, stream>>>(topv, topi, flag, slots, att);
    k4_out<<<dim3(INDIM / 128, NQ / 64), 256, 0, stream>>>(att, Wo, bo, out);
    k5_ln<<<NQ, 256, 0, stream>>>(out, ln2g, ln2b);
}

// Round 3
// 729.635 us; speedup vs baseline: 1.3341x; 1.1163x over previous
//
#include <hip/hip_runtime.h>
#include <math.h>

#define NQ    8192   // B*S
#define T3    48
#define INDIM 1024
#define HID   128
#define MSLOT 8192
#define HD    256
#define KBIG  48
#define KBASE 32
#define CHUNK 1024

// ---- workspace layout (bytes) ----
#define OFF_H    ((size_t)0)                         // 8192*48 f32   = 1,572,864
#define OFF_M2   ((size_t)1572864)                   // 8192 f32
#define OFF_CW   ((size_t)1605632)                   // 8192 f32
#define OFF_TOPV ((size_t)1638400)                   // 8192*48 f32
#define OFF_TOPI ((size_t)3211264)                   // 8192*48 i32
#define OFF_RMIN ((size_t)4784128)                   // 8192 f32
#define OFF_FLAG ((size_t)4816896)                   // 1 i32 (+pad)
#define OFF_ATTB ((size_t)4817152)                   // 8192*256 bf16 = 4,194,304
#define OFF_WOT  ((size_t)9011456)                   // 1024*256 bf16 = 524,288
#define OFF_DIST ((size_t)13205760)                  // CHUNK*8192 f32 = 33,554,432
// hpart (4*8192*48 f32 = 6.3MB) aliases OFF_DIST: consumed by k1b before k2a writes dist

typedef __attribute__((ext_vector_type(8))) short short8;
typedef __attribute__((ext_vector_type(4))) float f32x4;

__device__ __forceinline__ float gelu_exact(float x) {
    return 0.5f * x * (1.0f + erff(x * 0.70710678118654752f));
}

__device__ __forceinline__ unsigned short bf16_rne(float f) {
    unsigned int x = __float_as_uint(f);
    unsigned int r = (x + 0x7fffu + ((x >> 16) & 1u)) >> 16;
    return (unsigned short)r;
}

__device__ __forceinline__ unsigned long long shfl_xor_u64(unsigned long long v, int off) {
    unsigned lo = (unsigned)v, hi = (unsigned)(v >> 32);
    lo = (unsigned)__shfl_xor((int)lo, off);
    hi = (unsigned)__shfl_xor((int)hi, off);
    return ((unsigned long long)hi << 32) | lo;
}

// ---- K0: m2[m] = ||mem_pos[m]||^2 ; cw[m] = exp(-alpha*||curv[m]||) ----
__global__ __launch_bounds__(256) void k0_prep(const float* __restrict__ pe,
        const float* __restrict__ curv, const float* __restrict__ alpha,
        float* __restrict__ m2, float* __restrict__ cw) {
    int m = blockIdx.x * 256 + threadIdx.x;
    float s = 0.f;
    for (int d = 0; d < T3; d++) { float v = pe[(size_t)m * T3 + d]; s += v * v; }
    m2[m] = s;
    float c = 0.f;
    for (int d = 0; d < 16; d++) { float v = curv[m * 16 + d]; c += v * v; }
    cw[m] = expf(-alpha[0] * sqrtf(c));
}

// ---- K0b: Wo_t[n][k] = bf16(Wo[k][n])  (tiled transpose) ----
__global__ __launch_bounds__(256) void k0b_cvt(const float* __restrict__ Wo,
        unsigned short* __restrict__ Wot) {
    __shared__ float t[64][65];
    int k0 = blockIdx.x * 64;   // 4 tiles over K=256
    int n0 = blockIdx.y * 64;   // 16 tiles over N=1024
    int c = threadIdx.x & 63, r4 = threadIdx.x >> 6;
    #pragma unroll
    for (int i = 0; i < 16; i++) {
        int kr = i * 4 + r4;
        t[kr][c] = Wo[(size_t)(k0 + kr) * INDIM + n0 + c];
    }
    __syncthreads();
    #pragma unroll
    for (int i = 0; i < 16; i++) {
        int nr = i * 4 + r4;
        Wot[(size_t)(n0 + nr) * HD + k0 + c] = bf16_rne(t[c][nr]);
    }
}

// ---- K1: hpart[slice] = x[:, slice*256:(slice+1)*256] @ Wp[slice rows] ----
__global__ __launch_bounds__(256) void k1_proj(const float* __restrict__ x,
        const float* __restrict__ Wp, float* __restrict__ hpart) {
    __shared__ float xs[64][65];
    __shared__ float ws[64][T3];
    int tid = threadIdx.x;
    int slice = blockIdx.x;            // 0..3
    int r0 = blockIdx.y * 64;
    int kbase = slice * 256;
    int tr = tid >> 3, tc = tid & 7;   // 32 x 8; rows {tr, tr+32}
    float acc[2][6];
    #pragma unroll
    for (int i = 0; i < 2; i++)
        #pragma unroll
        for (int j = 0; j < 6; j++) acc[i][j] = 0.f;
    for (int kt = 0; kt < 256; kt += 64) {
        int k0 = kbase + kt;
        for (int idx = tid; idx < 1024; idx += 256) {
            int r = idx >> 4, c4 = idx & 15;
            float4 v = *(const float4*)(x + (size_t)(r0 + r) * INDIM + k0 + c4 * 4);
            xs[r][c4 * 4 + 0] = v.x; xs[r][c4 * 4 + 1] = v.y;
            xs[r][c4 * 4 + 2] = v.z; xs[r][c4 * 4 + 3] = v.w;
        }
        for (int idx = tid; idx < 64 * T3; idx += 256) {
            int r = idx / T3, c = idx - r * T3;
            ws[r][c] = Wp[(size_t)(k0 + r) * T3 + c];
        }
        __syncthreads();
        #pragma unroll 8
        for (int kk = 0; kk < 64; kk++) {
            float a0 = xs[tr][kk], a1 = xs[tr + 32][kk];
            float b[6];
            #pragma unroll
            for (int j = 0; j < 6; j++) b[j] = ws[kk][tc + 8 * j];
            #pragma unroll
            for (int j = 0; j < 6; j++) {
                acc[0][j] += a0 * b[j];
                acc[1][j] += a1 * b[j];
            }
        }
        __syncthreads();
    }
    float* dst = hpart + (size_t)slice * NQ * T3;
    #pragma unroll
    for (int i = 0; i < 2; i++)
        #pragma unroll
        for (int j = 0; j < 6; j++)
            dst[(size_t)(r0 + tr + 32 * i) * T3 + tc + 8 * j] = acc[i][j];
}

// ---- K1b: 32 rows/block: sum partials + bias, LN, GELU, 2 ODE steps ----
__global__ __launch_bounds__(256) void k1b_ode(const float* __restrict__ hpart,
        const float* __restrict__ bp,
        const float* __restrict__ g1, const float* __restrict__ b1ln,
        const float* __restrict__ W1, const float* __restrict__ bb1,
        const float* __restrict__ W2, const float* __restrict__ bb2,
        float* __restrict__ h) {
    __shared__ float W1s[T3 * HID];    // 24KB
    __shared__ float W2s[HID * T3];    // 24KB
    __shared__ float hs[32 * T3];      // 6KB
    __shared__ float t1s[32 * HID];    // 16KB (also scratch for pre-LN y)
    int tid = threadIdx.x;
    size_t base = (size_t)blockIdx.x * 32 * T3;
    for (int idx = tid; idx < T3 * HID; idx += 256) {
        W1s[idx] = W1[idx];
        W2s[idx] = W2[idx];
    }
    for (int idx = tid; idx < 32 * T3; idx += 256) {
        int c = idx % T3;
        float a = bp[c];
        #pragma unroll
        for (int s = 0; s < 4; s++) a += hpart[(size_t)s * NQ * T3 + base + idx];
        t1s[idx] = a;
    }
    __syncthreads();
    // LN + GELU -> hs ; 8 lanes per row
    {
        int r = tid >> 3, c8 = tid & 7;
        float v[6];
        float ssum = 0.f;
        #pragma unroll
        for (int i = 0; i < 6; i++) { v[i] = t1s[r * T3 + c8 * 6 + i]; ssum += v[i]; }
        #pragma unroll
        for (int off = 1; off < 8; off <<= 1) ssum += __shfl_xor(ssum, off);
        float mean = ssum * (1.f / T3);
        float vv = 0.f;
        #pragma unroll
        for (int i = 0; i < 6; i++) { v[i] -= mean; vv += v[i] * v[i]; }
        #pragma unroll
        for (int off = 1; off < 8; off <<= 1) vv += __shfl_xor(vv, off);
        float rstd = rsqrtf(vv * (1.f / T3) + 1e-5f);
        #pragma unroll
        for (int i = 0; i < 6; i++) {
            int c = c8 * 6 + i;
            hs[r * T3 + c] = gelu_exact(v[i] * rstd * g1[c] + b1ln[c]);
        }
    }
    __syncthreads();
    for (int step = 0; step < 2; step++) {
        for (int idx = tid; idx < 32 * HID; idx += 256) {
            int rr = idx >> 7, j = idx & 127;
            float a = bb1[j];
            #pragma unroll 8
            for (int d = 0; d < T3; d++) a += hs[rr * T3 + d] * W1s[d * HID + j];
            t1s[idx] = tanhf(a);
        }
        __syncthreads();
        for (int idx = tid; idx < 32 * T3; idx += 256) {
            int rr = idx / T3, c = idx - rr * T3;
            float a = bb2[c];
            #pragma unroll 8
            for (int j = 0; j < HID; j++) a += t1s[rr * HID + j] * W2s[j * T3 + c];
            hs[idx] += 0.5f * a;
        }
        __syncthreads();
    }
    for (int idx = tid; idx < 32 * T3; idx += 256) h[base + idx] = hs[idx];
}

// ---- K2a v2: transposed LDS + b128 reads; 64q x 256m per block ----
#define QST 68    // qs_t row stride (floats), 272B (16B-aligned)
#define MST 260   // ms_t row stride (floats), 1040B (16B-aligned)
__global__ __launch_bounds__(256) void k2a_dist(const float* __restrict__ h,
        const float* __restrict__ mp, const float* __restrict__ m2,
        const float* __restrict__ cw, float* __restrict__ dist, int rowbase) {
    __shared__ __align__(16) float qs_t[T3 * QST];   // 13.1KB
    __shared__ __align__(16) float ms_t[T3 * MST];   // 49.9KB
    __shared__ float q2s[64];
    __shared__ float m2s[256];
    __shared__ float cws[256];
    int tid = threadIdx.x;
    int r0 = rowbase + blockIdx.y * 64;
    int c0 = blockIdx.x * 256;
    for (int idx = tid; idx < 64 * T3; idx += 256) {
        int r = idx / T3, c = idx - r * T3;
        qs_t[c * QST + r] = h[(size_t)(r0 + r) * T3 + c];
    }
    for (int idx = tid; idx < 256 * T3; idx += 256) {
        int r = idx / T3, c = idx - r * T3;
        ms_t[c * MST + r] = mp[(size_t)(c0 + r) * T3 + c];
    }
    m2s[tid] = m2[c0 + tid];
    cws[tid] = cw[c0 + tid];
    __syncthreads();
    if (tid < 64) {
        float s = 0.f;
        for (int k = 0; k < T3; k++) { float v = qs_t[k * QST + tid]; s += v * v; }
        q2s[tid] = s;
    }
    __syncthreads();
    int tr = tid >> 4, tc = tid & 15;   // 16 x 16; rows tr*4+i, cols tc*4+64*jj+q
    float acc[4][16];
    #pragma unroll
    for (int i = 0; i < 4; i++)
        #pragma unroll
        for (int j = 0; j < 16; j++) acc[i][j] = 0.f;
    #pragma unroll 4
    for (int k = 0; k < T3; k++) {
        float4 av = *(const float4*)&qs_t[k * QST + tr * 4];
        float4 bv[4];
        #pragma unroll
        for (int jj = 0; jj < 4; jj++)
            bv[jj] = *(const float4*)&ms_t[k * MST + tc * 4 + 64 * jj];
        #pragma unroll
        for (int i = 0; i < 4; i++) {
            float a = (i == 0) ? av.x : (i == 1) ? av.y : (i == 2) ? av.z : av.w;
            #pragma unroll
            for (int jj = 0; jj < 4; jj++) {
                acc[i][jj * 4 + 0] += a * bv[jj].x;
                acc[i][jj * 4 + 1] += a * bv[jj].y;
                acc[i][jj * 4 + 2] += a * bv[jj].z;
                acc[i][jj * 4 + 3] += a * bv[jj].w;
            }
        }
    }
    int rl0 = blockIdx.y * 64;
    #pragma unroll
    for (int i = 0; i < 4; i++) {
        int rl = rl0 + tr * 4 + i;
        float q2 = q2s[tr * 4 + i];
        #pragma unroll
        for (int jj = 0; jj < 4; jj++) {
            int c = tc * 4 + 64 * jj;
            float4 o;
            o.x = fmaxf(q2 + m2s[c + 0] - 2.f * acc[i][jj * 4 + 0], 0.f) * cws[c + 0];
            o.y = fmaxf(q2 + m2s[c + 1] - 2.f * acc[i][jj * 4 + 1], 0.f) * cws[c + 1];
            o.z = fmaxf(q2 + m2s[c + 2] - 2.f * acc[i][jj * 4 + 2], 0.f) * cws[c + 2];
            o.w = fmaxf(q2 + m2s[c + 3] - 2.f * acc[i][jj * 4 + 3], 0.f) * cws[c + 3];
            *(float4*)(dist + (size_t)rl * MSLOT + c0 + c) = o;
        }
    }
}

// ---- K2b: per-wave sorted top-48 extraction + rank merge ----
__global__ __launch_bounds__(256) void k2b_topk(const float* __restrict__ dist,
        float* __restrict__ topv, int* __restrict__ topi,
        float* __restrict__ rowmin, int rowbase) {
    __shared__ float vals[MSLOT];                       // 32KB
    __shared__ unsigned long long wl[4][KBIG];          // 1.5KB
    int tid = threadIdx.x;
    int lane = tid & 63, wv = tid >> 6;
    int rl = blockIdx.x;
    size_t row = (size_t)(rowbase + rl);
    const float* src = dist + (size_t)rl * MSLOT;
    int base = wv * 2048;
    unsigned long long c0 = ~0ULL, c1 = ~0ULL, c2 = ~0ULL, c3 = ~0ULL;
    for (int j = 0; j < 32; j++) {
        int m = base + j * 64 + lane;
        float v = src[m];
        vals[m] = v;
        unsigned long long k = ((unsigned long long)__float_as_uint(v) << 32) | (unsigned)m;
        if (k < c3) {
            c3 = k;
            if (c3 < c2) { unsigned long long t = c2; c2 = c3; c3 = t;
                if (c2 < c1) { t = c1; c1 = c2; c2 = t;
                    if (c1 < c0) { t = c0; c0 = c1; c1 = t; } } }
        }
    }
    int p = 0;
    unsigned long long head = c0;
    for (int k = 0; k < KBIG; k++) {
        unsigned long long mn = head;
        #pragma unroll
        for (int off = 32; off; off >>= 1) {
            unsigned long long o = shfl_xor_u64(mn, off);
            mn = o < mn ? o : mn;
        }
        if (lane == 0) wl[wv][k] = mn;
        if (head == mn) {
            p++;
            if (p == 1) head = c1;
            else if (p == 2) head = c2;
            else if (p == 3) head = c3;
            else {
                unsigned long long nm = ~0ULL;
                for (int j = 0; j < 32; j++) {
                    int m = base + j * 64 + lane;
                    unsigned long long kk =
                        ((unsigned long long)__float_as_uint(vals[m]) << 32) | (unsigned)m;
                    if (kk > mn && kk < nm) nm = kk;
                }
                head = nm;
            }
        }
    }
    __syncthreads();
    if (tid < 4 * KBIG) {
        int l = tid / KBIG, pos = tid - l * KBIG;
        unsigned long long key = wl[l][pos];
        int rank = pos;
        #pragma unroll
        for (int ol = 0; ol < 4; ol++) {
            if (ol == l) continue;
            int lo = 0, hi = KBIG;
            while (lo < hi) {
                int mid = (lo + hi) >> 1;
                if (wl[ol][mid] < key) lo = mid + 1; else hi = mid;
            }
            rank += lo;
        }
        if (rank < KBIG) {
            float v = __uint_as_float((unsigned)(key >> 32));
            topv[row * KBIG + rank] = v;
            topi[row * KBIG + rank] = (int)(key & 0xFFFFFFFFu);
            if (rank == 0) rowmin[row] = v;
        }
    }
}

// ---- K3a: fire flag = (mean of row mins) < 0.7 ----
__global__ __launch_bounds__(256) void k3a_flag(const float* __restrict__ rowmin,
        int* __restrict__ flag) {
    __shared__ float red[256];
    int tid = threadIdx.x;
    float s = 0.f;
    for (int j = 0; j < NQ / 256; j++) s += rowmin[tid + 256 * j];
    red[tid] = s;
    __syncthreads();
    for (int st = 128; st; st >>= 1) {
        if (tid < st) red[tid] += red[tid + st];
        __syncthreads();
    }
    if (tid == 0) {
        float top1 = red[0] / (float)NQ;
        flag[0] = (top1 < 0.7f) ? 1 : 0;
    }
}

// ---- K3 v2: wave per row; float4 gathers; writes att as bf16 ----
__global__ __launch_bounds__(256) void k3_attend(const float* __restrict__ topv,
        const int* __restrict__ topi, const int* __restrict__ flag,
        const float* __restrict__ slots, unsigned short* __restrict__ attb) {
    int tid = threadIdx.x;
    int lane = tid & 63, wv = tid >> 6;
    size_t row = (size_t)blockIdx.x * 4 + wv;
    int kc = flag[0] ? KBIG : KBASE;
    float v0 = topv[row * KBIG];
    float ev = 0.f;
    int mi = 0;
    if (lane < KBIG) {
        float v = topv[row * KBIG + lane];
        ev = (lane < kc) ? expf(-(v - v0)) : 0.f;
        mi = topi[row * KBIG + lane];
    }
    float ssum = ev;
    #pragma unroll
    for (int off = 32; off; off >>= 1) ssum += __shfl_xor(ssum, off);
    float inv = 1.f / ssum;
    float4 acc = make_float4(0.f, 0.f, 0.f, 0.f);
    for (int k = 0; k < kc; k++) {
        float wk = __shfl(ev, k) * inv;
        int m = __shfl(mi, k);
        float4 v = *(const float4*)(slots + (size_t)m * HD + lane * 4);
        acc.x += wk * v.x; acc.y += wk * v.y;
        acc.z += wk * v.z; acc.w += wk * v.w;
    }
    ushort4 o;
    o.x = bf16_rne(acc.x); o.y = bf16_rne(acc.y);
    o.z = bf16_rne(acc.z); o.w = bf16_rne(acc.w);
    *(ushort4*)(attb + row * HD + lane * 4) = o;
}

// ---- K4 v2: out = att(bf16) @ Wo_t(bf16)^T + bo via MFMA 16x16x32 ----
__global__ __launch_bounds__(256) void k4_mfma(const unsigned short* __restrict__ A,
        const unsigned short* __restrict__ Bt, const float* __restrict__ bo,
        float* __restrict__ out) {
    int tid = threadIdx.x;
    int lane = tid & 63, wave = tid >> 6;
    int wm = wave >> 1, wn = wave & 1;
    int mbase = blockIdx.y * 128 + wm * 64;
    int nbase = blockIdx.x * 128 + wn * 64;
    int lm = lane & 15;
    int lk8 = (lane >> 4) * 8;
    f32x4 acc[4][4];
    #pragma unroll
    for (int i = 0; i < 4; i++)
        #pragma unroll
        for (int j = 0; j < 4; j++) acc[i][j] = (f32x4)(0.f);
    #pragma unroll 2
    for (int ks = 0; ks < 8; ks++) {
        int kofs = ks * 32 + lk8;
        short8 a[4], b[4];
        #pragma unroll
        for (int i = 0; i < 4; i++)
            a[i] = *(const short8*)(A + (size_t)(mbase + i * 16 + lm) * HD + kofs);
        #pragma unroll
        for (int j = 0; j < 4; j++)
            b[j] = *(const short8*)(Bt + (size_t)(nbase + j * 16 + lm) * HD + kofs);
        #pragma unroll
        for (int i = 0; i < 4; i++)
            #pragma unroll
            for (int j = 0; j < 4; j++)
                acc[i][j] = __builtin_amdgcn_mfma_f32_16x16x32_bf16(a[i], b[j], acc[i][j], 0, 0, 0);
    }
    int orow = (lane >> 4) * 4;
    #pragma unroll
    for (int i = 0; i < 4; i++)
        #pragma unroll
        for (int j = 0; j < 4; j++) {
            int col = nbase + j * 16 + lm;
            float bias = bo[col];
            #pragma unroll
            for (int r = 0; r < 4; r++) {
                int row = mbase + i * 16 + orow + r;
                out[(size_t)row * INDIM + col] = acc[i][j][r] + bias;
            }
        }
}

// ---- K5: LN + GELU in place on d_out ----
__global__ __launch_bounds__(256) void k5_ln(float* __restrict__ out,
        const float* __restrict__ g, const float* __restrict__ b) {
    __shared__ float red[4];
    int tid = threadIdx.x;
    size_t row = blockIdx.x;
    float4 v = *(const float4*)(out + row * INDIM + tid * 4);
    float s = v.x + v.y + v.z + v.w;
    #pragma unroll
    for (int off = 32; off; off >>= 1) s += __shfl_xor(s, off);
    int wid = tid >> 6, lane = tid & 63;
    if (!lane) red[wid] = s;
    __syncthreads();
    float mean = (red[0] + red[1] + red[2] + red[3]) * (1.f / (float)INDIM);
    __syncthreads();
    float dx = v.x - mean, dy = v.y - mean, dz = v.z - mean, dw = v.w - mean;
    float ss = dx * dx + dy * dy + dz * dz + dw * dw;
    #pragma unroll
    for (int off = 32; off; off >>= 1) ss += __shfl_xor(ss, off);
    if (!lane) red[wid] = ss;
    __syncthreads();
    float var = (red[0] + red[1] + red[2] + red[3]) * (1.f / (float)INDIM);
    float rs = rsqrtf(var + 1e-5f);
    int c = tid * 4;
    float4 o;
    o.x = gelu_exact(dx * rs * g[c + 0] + b[c + 0]);
    o.y = gelu_exact(dy * rs * g[c + 1] + b[c + 1]);
    o.z = gelu_exact(dz * rs * g[c + 2] + b[c + 2]);
    o.w = gelu_exact(dw * rs * g[c + 3] + b[c + 3]);
    *(float4*)(out + row * INDIM + c) = o;
}

extern "C" void kernel_launch(void* const* d_in, const int* in_sizes, int n_in,
                              void* d_out, int out_size, void* d_ws, size_t ws_size,
                              hipStream_t stream) {
    const float* x     = (const float*)d_in[0];
    const float* Wp    = (const float*)d_in[1];
    const float* bp    = (const float*)d_in[2];
    const float* ln1g  = (const float*)d_in[3];
    const float* ln1b  = (const float*)d_in[4];
    const float* oW1   = (const float*)d_in[5];
    const float* ob1   = (const float*)d_in[6];
    const float* oW2   = (const float*)d_in[7];
    const float* ob2   = (const float*)d_in[8];
    const float* slots = (const float*)d_in[9];
    const float* pe    = (const float*)d_in[10];
    const float* curv  = (const float*)d_in[11];
    const float* alpha = (const float*)d_in[12];
    const float* Wo    = (const float*)d_in[13];
    const float* bo    = (const float*)d_in[14];
    const float* ln2g  = (const float*)d_in[15];
    const float* ln2b  = (const float*)d_in[16];
    float* out = (float*)d_out;
    char* ws = (char*)d_ws;

    float* h0     = (float*)(ws + OFF_H);
    float* m2     = (float*)(ws + OFF_M2);
    float* cwv    = (float*)(ws + OFF_CW);
    float* topv   = (float*)(ws + OFF_TOPV);
    int*   topi   = (int*)  (ws + OFF_TOPI);
    float* rowmin = (float*)(ws + OFF_RMIN);
    int*   flag   = (int*)  (ws + OFF_FLAG);
    unsigned short* attb = (unsigned short*)(ws + OFF_ATTB);
    unsigned short* wot  = (unsigned short*)(ws + OFF_WOT);
    float* dist   = (float*)(ws + OFF_DIST);
    float* hpart  = dist;   // aliased: consumed before dist is produced

    k0_prep<<<MSLOT / 256, 256, 0, stream>>>(pe, curv, alpha, m2, cwv);
    k0b_cvt<<<dim3(4, 16), 256, 0, stream>>>(Wo, wot);
    k1_proj<<<dim3(4, NQ / 64), 256, 0, stream>>>(x, Wp, hpart);
    k1b_ode<<<NQ / 32, 256, 0, stream>>>(hpart, bp, ln1g, ln1b, oW1, ob1, oW2, ob2, h0);
    for (int ch = 0; ch < NQ / CHUNK; ch++) {
        k2a_dist<<<dim3(32, 16), 256, 0, stream>>>(h0, pe, m2, cwv, dist, ch * CHUNK);
        k2b_topk<<<CHUNK, 256, 0, stream>>>(dist, topv, topi, rowmin, ch * CHUNK);
    }
    k3a_flag<<<1, 256, 0, stream>>>(rowmin, flag);
    k3_attend<<<NQ / 4, 256, 0, stream>>>(topv, topi, flag, slots, attb);
    k4_mfma<<<dim3(INDIM / 128, NQ / 128), 256, 0, stream>>>(attb, wot, bo, out);
    k5_ln<<<NQ, 256, 0, stream>>>(out, ln2g, ln2b);
}

// Round 4
// 493.012 us; speedup vs baseline: 1.9744x; 1.4800x over previous
//
#include <hip/hip_runtime.h>
#include <math.h>

#define NQ    8192   // B*S
#define T3    48
#define INDIM 1024
#define HID   128
#define MSLOT 8192
#define HD    256
#define KBIG  48
#define KBASE 32
#define CHUNK 1024
#define SPLITK 8
#define KSLICE 128   // INDIM / SPLITK

// ---- workspace layout (bytes) ----
#define OFF_H    ((size_t)0)                         // 8192*48 f32   = 1,572,864
#define OFF_M2   ((size_t)1572864)                   // 8192 f32
#define OFF_CW   ((size_t)1605632)                   // 8192 f32
#define OFF_TOPV ((size_t)1638400)                   // 8192*48 f32
#define OFF_TOPI ((size_t)3211264)                   // 8192*48 i32
#define OFF_RMIN ((size_t)4784128)                   // 8192 f32
#define OFF_FLAG ((size_t)4816896)                   // 1 i32 (+pad)
#define OFF_ATTB ((size_t)4817152)                   // 8192*256 bf16 = 4,194,304
#define OFF_WOT  ((size_t)9011456)                   // 1024*256 bf16 = 524,288
#define OFF_DIST ((size_t)13205760)                  // CHUNK*8192 f32 = 33,554,432
// hpart (8*8192*48 f32 = 12.6MB) aliases OFF_DIST: consumed by k1b before k2a writes dist

typedef __attribute__((ext_vector_type(8))) short short8;
typedef __attribute__((ext_vector_type(4))) float f32x4;

__device__ __forceinline__ float gelu_exact(float x) {
    return 0.5f * x * (1.0f + erff(x * 0.70710678118654752f));
}

__device__ __forceinline__ unsigned short bf16_rne(float f) {
    unsigned int x = __float_as_uint(f);
    unsigned int r = (x + 0x7fffu + ((x >> 16) & 1u)) >> 16;
    return (unsigned short)r;
}

// ---- K0: m2[m] = ||mem_pos[m]||^2 ; cw[m] = exp(-alpha*||curv[m]||) ----
__global__ __launch_bounds__(256) void k0_prep(const float* __restrict__ pe,
        const float* __restrict__ curv, const float* __restrict__ alpha,
        float* __restrict__ m2, float* __restrict__ cw) {
    int m = blockIdx.x * 256 + threadIdx.x;
    float s = 0.f;
    for (int d = 0; d < T3; d++) { float v = pe[(size_t)m * T3 + d]; s += v * v; }
    m2[m] = s;
    float c = 0.f;
    for (int d = 0; d < 16; d++) { float v = curv[m * 16 + d]; c += v * v; }
    cw[m] = expf(-alpha[0] * sqrtf(c));
}

// ---- K0b: Wo_t[n][k] = bf16(Wo[k][n])  (tiled transpose) ----
__global__ __launch_bounds__(256) void k0b_cvt(const float* __restrict__ Wo,
        unsigned short* __restrict__ Wot) {
    __shared__ float t[64][65];
    int k0 = blockIdx.x * 64;   // 4 tiles over K=256
    int n0 = blockIdx.y * 64;   // 16 tiles over N=1024
    int c = threadIdx.x & 63, r4 = threadIdx.x >> 6;
    #pragma unroll
    for (int i = 0; i < 16; i++) {
        int kr = i * 4 + r4;
        t[kr][c] = Wo[(size_t)(k0 + kr) * INDIM + n0 + c];
    }
    __syncthreads();
    #pragma unroll
    for (int i = 0; i < 16; i++) {
        int nr = i * 4 + r4;
        Wot[(size_t)(n0 + nr) * HD + k0 + c] = bf16_rne(t[c][nr]);
    }
}

// ---- K1 v3: hpart[slice] = x[:, slice] @ Wp[slice]; 4r x 12c per thread, b128 LDS ----
__global__ __launch_bounds__(64) void k1_proj(const float* __restrict__ x,
        const float* __restrict__ Wp, float* __restrict__ hpart) {
    __shared__ __align__(16) float xs_t[64][68];   // [k][row], 17.4KB
    __shared__ __align__(16) float ws_s[64][48];   // [k][col], 12.3KB
    int tid = threadIdx.x;
    int slice = blockIdx.x;            // 0..7
    int r0 = blockIdx.y * 64;
    int kbase = slice * KSLICE;
    int rt = tid >> 2, ct = tid & 3;   // 16 x 4: rows rt*4+i, cols ct*12+j
    float acc[4][12];
    #pragma unroll
    for (int i = 0; i < 4; i++)
        #pragma unroll
        for (int j = 0; j < 12; j++) acc[i][j] = 0.f;
    for (int kt = 0; kt < KSLICE; kt += 64) {
        int k0 = kbase + kt;
        for (int idx = tid; idx < 1024; idx += 64) {
            int r = idx >> 4, c4 = idx & 15;
            float4 v = *(const float4*)(x + (size_t)(r0 + r) * INDIM + k0 + c4 * 4);
            xs_t[c4 * 4 + 0][r] = v.x; xs_t[c4 * 4 + 1][r] = v.y;
            xs_t[c4 * 4 + 2][r] = v.z; xs_t[c4 * 4 + 3][r] = v.w;
        }
        for (int idx = tid; idx < 768; idx += 64) {
            int r = idx / 12, c4 = idx % 12;
            float4 v = *(const float4*)(Wp + (size_t)(k0 + r) * T3 + c4 * 4);
            ws_s[r][c4 * 4 + 0] = v.x; ws_s[r][c4 * 4 + 1] = v.y;
            ws_s[r][c4 * 4 + 2] = v.z; ws_s[r][c4 * 4 + 3] = v.w;
        }
        __syncthreads();
        #pragma unroll 4
        for (int kk = 0; kk < 64; kk++) {
            float4 a = *(const float4*)&xs_t[kk][rt * 4];
            float4 b0 = *(const float4*)&ws_s[kk][ct * 12];
            float4 b1 = *(const float4*)&ws_s[kk][ct * 12 + 4];
            float4 b2 = *(const float4*)&ws_s[kk][ct * 12 + 8];
            float av[4] = {a.x, a.y, a.z, a.w};
            #pragma unroll
            for (int i = 0; i < 4; i++) {
                acc[i][0] += av[i] * b0.x; acc[i][1] += av[i] * b0.y;
                acc[i][2] += av[i] * b0.z; acc[i][3] += av[i] * b0.w;
                acc[i][4] += av[i] * b1.x; acc[i][5] += av[i] * b1.y;
                acc[i][6] += av[i] * b1.z; acc[i][7] += av[i] * b1.w;
                acc[i][8] += av[i] * b2.x; acc[i][9] += av[i] * b2.y;
                acc[i][10] += av[i] * b2.z; acc[i][11] += av[i] * b2.w;
            }
        }
        __syncthreads();
    }
    float* dst = hpart + (size_t)slice * NQ * T3;
    #pragma unroll
    for (int i = 0; i < 4; i++) {
        size_t row = (size_t)(r0 + rt * 4 + i);
        #pragma unroll
        for (int jj = 0; jj < 3; jj++) {
            float4 o;
            o.x = acc[i][jj * 4 + 0]; o.y = acc[i][jj * 4 + 1];
            o.z = acc[i][jj * 4 + 2]; o.w = acc[i][jj * 4 + 3];
            *(float4*)(dst + row * T3 + ct * 12 + jj * 4) = o;
        }
    }
}

// ---- K1b: 32 rows/block: sum partials + bias, LN, GELU, 2 ODE steps ----
__global__ __launch_bounds__(256) void k1b_ode(const float* __restrict__ hpart,
        const float* __restrict__ bp,
        const float* __restrict__ g1, const float* __restrict__ b1ln,
        const float* __restrict__ W1, const float* __restrict__ bb1,
        const float* __restrict__ W2, const float* __restrict__ bb2,
        float* __restrict__ h) {
    __shared__ float W1s[T3 * HID];    // 24KB
    __shared__ float W2s[HID * T3];    // 24KB
    __shared__ float hs[32 * T3];      // 6KB
    __shared__ float t1s[32 * HID];    // 16KB (also scratch for pre-LN y)
    int tid = threadIdx.x;
    size_t base = (size_t)blockIdx.x * 32 * T3;
    for (int idx = tid; idx < T3 * HID; idx += 256) {
        W1s[idx] = W1[idx];
        W2s[idx] = W2[idx];
    }
    for (int idx = tid; idx < 32 * T3; idx += 256) {
        int c = idx % T3;
        float a = bp[c];
        #pragma unroll
        for (int s = 0; s < SPLITK; s++) a += hpart[(size_t)s * NQ * T3 + base + idx];
        t1s[idx] = a;
    }
    __syncthreads();
    // LN + GELU -> hs ; 8 lanes per row
    {
        int r = tid >> 3, c8 = tid & 7;
        float v[6];
        float ssum = 0.f;
        #pragma unroll
        for (int i = 0; i < 6; i++) { v[i] = t1s[r * T3 + c8 * 6 + i]; ssum += v[i]; }
        #pragma unroll
        for (int off = 1; off < 8; off <<= 1) ssum += __shfl_xor(ssum, off);
        float mean = ssum * (1.f / T3);
        float vv = 0.f;
        #pragma unroll
        for (int i = 0; i < 6; i++) { v[i] -= mean; vv += v[i] * v[i]; }
        #pragma unroll
        for (int off = 1; off < 8; off <<= 1) vv += __shfl_xor(vv, off);
        float rstd = rsqrtf(vv * (1.f / T3) + 1e-5f);
        #pragma unroll
        for (int i = 0; i < 6; i++) {
            int c = c8 * 6 + i;
            hs[r * T3 + c] = gelu_exact(v[i] * rstd * g1[c] + b1ln[c]);
        }
    }
    __syncthreads();
    for (int step = 0; step < 2; step++) {
        for (int idx = tid; idx < 32 * HID; idx += 256) {
            int rr = idx >> 7, j = idx & 127;
            float a = bb1[j];
            #pragma unroll 8
            for (int d = 0; d < T3; d++) a += hs[rr * T3 + d] * W1s[d * HID + j];
            t1s[idx] = tanhf(a);
        }
        __syncthreads();
        for (int idx = tid; idx < 32 * T3; idx += 256) {
            int rr = idx / T3, c = idx - rr * T3;
            float a = bb2[c];
            #pragma unroll 8
            for (int j = 0; j < HID; j++) a += t1s[rr * HID + j] * W2s[j * T3 + c];
            hs[idx] += 0.5f * a;
        }
        __syncthreads();
    }
    for (int idx = tid; idx < 32 * T3; idx += 256) h[base + idx] = hs[idx];
}

// ---- K2a: transposed LDS + b128 reads; 64q x 256m per block ----
#define QST 68    // qs_t row stride (floats)
#define MST 260   // ms_t row stride (floats)
__global__ __launch_bounds__(256) void k2a_dist(const float* __restrict__ h,
        const float* __restrict__ mp, const float* __restrict__ m2,
        const float* __restrict__ cw, float* __restrict__ dist, int rowbase) {
    __shared__ __align__(16) float qs_t[T3 * QST];   // 13.1KB
    __shared__ __align__(16) float ms_t[T3 * MST];   // 49.9KB
    __shared__ float q2s[64];
    __shared__ float m2s[256];
    __shared__ float cws[256];
    int tid = threadIdx.x;
    int r0 = rowbase + blockIdx.y * 64;
    int c0 = blockIdx.x * 256;
    for (int idx = tid; idx < 64 * T3; idx += 256) {
        int r = idx / T3, c = idx - r * T3;
        qs_t[c * QST + r] = h[(size_t)(r0 + r) * T3 + c];
    }
    for (int idx = tid; idx < 256 * T3; idx += 256) {
        int r = idx / T3, c = idx - r * T3;
        ms_t[c * MST + r] = mp[(size_t)(c0 + r) * T3 + c];
    }
    m2s[tid] = m2[c0 + tid];
    cws[tid] = cw[c0 + tid];
    __syncthreads();
    if (tid < 64) {
        float s = 0.f;
        for (int k = 0; k < T3; k++) { float v = qs_t[k * QST + tid]; s += v * v; }
        q2s[tid] = s;
    }
    __syncthreads();
    int tr = tid >> 4, tc = tid & 15;
    float acc[4][16];
    #pragma unroll
    for (int i = 0; i < 4; i++)
        #pragma unroll
        for (int j = 0; j < 16; j++) acc[i][j] = 0.f;
    #pragma unroll 4
    for (int k = 0; k < T3; k++) {
        float4 av = *(const float4*)&qs_t[k * QST + tr * 4];
        float4 bv[4];
        #pragma unroll
        for (int jj = 0; jj < 4; jj++)
            bv[jj] = *(const float4*)&ms_t[k * MST + tc * 4 + 64 * jj];
        #pragma unroll
        for (int i = 0; i < 4; i++) {
            float a = (i == 0) ? av.x : (i == 1) ? av.y : (i == 2) ? av.z : av.w;
            #pragma unroll
            for (int jj = 0; jj < 4; jj++) {
                acc[i][jj * 4 + 0] += a * bv[jj].x;
                acc[i][jj * 4 + 1] += a * bv[jj].y;
                acc[i][jj * 4 + 2] += a * bv[jj].z;
                acc[i][jj * 4 + 3] += a * bv[jj].w;
            }
        }
    }
    int rl0 = blockIdx.y * 64;
    #pragma unroll
    for (int i = 0; i < 4; i++) {
        int rl = rl0 + tr * 4 + i;
        float q2 = q2s[tr * 4 + i];
        #pragma unroll
        for (int jj = 0; jj < 4; jj++) {
            int c = tc * 4 + 64 * jj;
            float4 o;
            o.x = fmaxf(q2 + m2s[c + 0] - 2.f * acc[i][jj * 4 + 0], 0.f) * cws[c + 0];
            o.y = fmaxf(q2 + m2s[c + 1] - 2.f * acc[i][jj * 4 + 1], 0.f) * cws[c + 1];
            o.z = fmaxf(q2 + m2s[c + 2] - 2.f * acc[i][jj * 4 + 2], 0.f) * cws[c + 2];
            o.w = fmaxf(q2 + m2s[c + 3] - 2.f * acc[i][jj * 4 + 3], 0.f) * cws[c + 3];
            *(float4*)(dist + (size_t)rl * MSLOT + c0 + c) = o;
        }
    }
}

// ---- K2b v3: radix-select top-48 (exact, deterministic) ----
#define NBIN 4096
#define MAXCAND 1024
__global__ __launch_bounds__(256) void k2b_topk(const float* __restrict__ dist,
        float* __restrict__ topv, int* __restrict__ topi,
        float* __restrict__ rowmin, int rowbase) {
    __shared__ unsigned int hist[NBIN];            // 16KB
    __shared__ unsigned long long cand[MAXCAND];   // 8KB
    __shared__ unsigned int wsum[4];
    __shared__ unsigned int s_b1, s_c0, s_b2, s_ncand;
    int tid = threadIdx.x;
    int lane = tid & 63, wv = tid >> 6;
    int rl = blockIdx.x;
    size_t row = (size_t)(rowbase + rl);
    const uint4* src = (const uint4*)(dist + (size_t)rl * MSLOT);
    uint4 k4[8];
    #pragma unroll
    for (int j = 0; j < 8; j++) k4[j] = src[tid + 256 * j];
    for (int i = tid; i < NBIN; i += 256) hist[i] = 0;
    if (tid == 0) s_ncand = 0;
    __syncthreads();
    // level-1 histogram: bits [30:19] (dist >= 0 -> bits order-preserving)
    #pragma unroll
    for (int j = 0; j < 8; j++) {
        atomicAdd(&hist[k4[j].x >> 19], 1u);
        atomicAdd(&hist[k4[j].y >> 19], 1u);
        atomicAdd(&hist[k4[j].z >> 19], 1u);
        atomicAdd(&hist[k4[j].w >> 19], 1u);
    }
    __syncthreads();
    // level-1 scan: find bin B1 containing rank-48, c0 = count strictly below
    {
        unsigned hb[16];
        unsigned s = 0;
        #pragma unroll
        for (int i = 0; i < 16; i++) { hb[i] = hist[tid * 16 + i]; s += hb[i]; }
        unsigned v = s;
        #pragma unroll
        for (int off = 1; off < 64; off <<= 1) {
            unsigned o = __shfl_up(v, off);
            if (lane >= off) v += o;
        }
        if (lane == 63) wsum[wv] = v;
        __syncthreads();
        unsigned wbase = 0;
        for (int w = 0; w < wv; w++) wbase += wsum[w];
        unsigned excl = wbase + v - s;
        if (excl < KBIG && KBIG <= excl + s) {
            unsigned c = excl;
            #pragma unroll
            for (int i = 0; i < 16; i++) {
                if (c < KBIG && KBIG <= c + hb[i]) { s_b1 = tid * 16 + i; s_c0 = c; break; }
                c += hb[i];
            }
        }
        __syncthreads();
    }
    unsigned b1 = s_b1, c0 = s_c0;
    unsigned t2 = KBIG - c0;    // in [1, 48]
    __syncthreads();
    for (int i = tid; i < NBIN; i += 256) hist[i] = 0;
    __syncthreads();
    // level-2 histogram among bin-B1 keys: bits [18:7]
    #pragma unroll
    for (int j = 0; j < 8; j++) {
        if ((k4[j].x >> 19) == b1) atomicAdd(&hist[(k4[j].x >> 7) & 0xFFF], 1u);
        if ((k4[j].y >> 19) == b1) atomicAdd(&hist[(k4[j].y >> 7) & 0xFFF], 1u);
        if ((k4[j].z >> 19) == b1) atomicAdd(&hist[(k4[j].z >> 7) & 0xFFF], 1u);
        if ((k4[j].w >> 19) == b1) atomicAdd(&hist[(k4[j].w >> 7) & 0xFFF], 1u);
    }
    __syncthreads();
    // level-2 scan: find sub-bin B2 where cumulative reaches t2
    {
        unsigned hb[16];
        unsigned s = 0;
        #pragma unroll
        for (int i = 0; i < 16; i++) { hb[i] = hist[tid * 16 + i]; s += hb[i]; }
        unsigned v = s;
        #pragma unroll
        for (int off = 1; off < 64; off <<= 1) {
            unsigned o = __shfl_up(v, off);
            if (lane >= off) v += o;
        }
        if (lane == 63) wsum[wv] = v;
        __syncthreads();
        unsigned wbase = 0;
        for (int w = 0; w < wv; w++) wbase += wsum[w];
        unsigned excl = wbase + v - s;
        if (excl < t2 && t2 <= excl + s) {
            unsigned c = excl;
            #pragma unroll
            for (int i = 0; i < 16; i++) {
                if (c < t2 && t2 <= c + hb[i]) { s_b2 = tid * 16 + i; break; }
                c += hb[i];
            }
        }
        __syncthreads();
    }
    unsigned b2 = s_b2;
    // collect candidates: bin < B1, or (bin == B1 && sub <= B2). count in [48, ~250]
    #pragma unroll
    for (int j = 0; j < 8; j++) {
        int mb = (tid + 256 * j) * 4;
        unsigned kk[4] = {k4[j].x, k4[j].y, k4[j].z, k4[j].w};
        #pragma unroll
        for (int c = 0; c < 4; c++) {
            unsigned key = kk[c];
            unsigned hb_ = key >> 19;
            if (hb_ < b1 || (hb_ == b1 && ((key >> 7) & 0xFFFu) <= b2)) {
                unsigned n = atomicAdd(&s_ncand, 1u);
                if (n < MAXCAND)
                    cand[n] = ((unsigned long long)key << 32) | (unsigned)(mb + c);
            }
        }
    }
    __syncthreads();
    int nc = (int)(s_ncand < MAXCAND ? s_ncand : MAXCAND);
    // exact rank of each candidate (keys unique via idx in low bits)
    for (int i = tid; i < nc; i += 256) {
        unsigned long long me = cand[i];
        int rank = 0;
        for (int j = 0; j < nc; j++) rank += (cand[j] < me) ? 1 : 0;
        if (rank < KBIG) {
            float v = __uint_as_float((unsigned)(me >> 32));
            topv[row * KBIG + rank] = v;
            topi[row * KBIG + rank] = (int)(me & 0xFFFFFFFFu);
            if (rank == 0) rowmin[row] = v;
        }
    }
}

// ---- K3a: fire flag = (mean of row mins) < 0.7 ----
__global__ __launch_bounds__(256) void k3a_flag(const float* __restrict__ rowmin,
        int* __restrict__ flag) {
    __shared__ float red[256];
    int tid = threadIdx.x;
    float s = 0.f;
    for (int j = 0; j < NQ / 256; j++) s += rowmin[tid + 256 * j];
    red[tid] = s;
    __syncthreads();
    for (int st = 128; st; st >>= 1) {
        if (tid < st) red[tid] += red[tid + st];
        __syncthreads();
    }
    if (tid == 0) {
        float top1 = red[0] / (float)NQ;
        flag[0] = (top1 < 0.7f) ? 1 : 0;
    }
}

// ---- K3: wave per row; float4 gathers; writes att as bf16 ----
__global__ __launch_bounds__(256) void k3_attend(const float* __restrict__ topv,
        const int* __restrict__ topi, const int* __restrict__ flag,
        const float* __restrict__ slots, unsigned short* __restrict__ attb) {
    int tid = threadIdx.x;
    int lane = tid & 63, wv = tid >> 6;
    size_t row = (size_t)blockIdx.x * 4 + wv;
    int kc = flag[0] ? KBIG : KBASE;
    float v0 = topv[row * KBIG];
    float ev = 0.f;
    int mi = 0;
    if (lane < KBIG) {
        float v = topv[row * KBIG + lane];
        ev = (lane < kc) ? expf(-(v - v0)) : 0.f;
        mi = topi[row * KBIG + lane];
    }
    float ssum = ev;
    #pragma unroll
    for (int off = 32; off; off >>= 1) ssum += __shfl_xor(ssum, off);
    float inv = 1.f / ssum;
    float4 acc = make_float4(0.f, 0.f, 0.f, 0.f);
    for (int k = 0; k < kc; k++) {
        float wk = __shfl(ev, k) * inv;
        int m = __shfl(mi, k);
        float4 v = *(const float4*)(slots + (size_t)m * HD + lane * 4);
        acc.x += wk * v.x; acc.y += wk * v.y;
        acc.z += wk * v.z; acc.w += wk * v.w;
    }
    ushort4 o;
    o.x = bf16_rne(acc.x); o.y = bf16_rne(acc.y);
    o.z = bf16_rne(acc.z); o.w = bf16_rne(acc.w);
    *(ushort4*)(attb + row * HD + lane * 4) = o;
}

// ---- K4: out = att(bf16) @ Wo_t(bf16)^T + bo via MFMA 16x16x32 ----
__global__ __launch_bounds__(256) void k4_mfma(const unsigned short* __restrict__ A,
        const unsigned short* __restrict__ Bt, const float* __restrict__ bo,
        float* __restrict__ out) {
    int tid = threadIdx.x;
    int lane = tid & 63, wave = tid >> 6;
    int wm = wave >> 1, wn = wave & 1;
    int mbase = blockIdx.y * 128 + wm * 64;
    int nbase = blockIdx.x * 128 + wn * 64;
    int lm = lane & 15;
    int lk8 = (lane >> 4) * 8;
    f32x4 acc[4][4];
    #pragma unroll
    for (int i = 0; i < 4; i++)
        #pragma unroll
        for (int j = 0; j < 4; j++) acc[i][j] = (f32x4)(0.f);
    #pragma unroll 2
    for (int ks = 0; ks < 8; ks++) {
        int kofs = ks * 32 + lk8;
        short8 a[4], b[4];
        #pragma unroll
        for (int i = 0; i < 4; i++)
            a[i] = *(const short8*)(A + (size_t)(mbase + i * 16 + lm) * HD + kofs);
        #pragma unroll
        for (int j = 0; j < 4; j++)
            b[j] = *(const short8*)(Bt + (size_t)(nbase + j * 16 + lm) * HD + kofs);
        #pragma unroll
        for (int i = 0; i < 4; i++)
            #pragma unroll
            for (int j = 0; j < 4; j++)
                acc[i][j] = __builtin_amdgcn_mfma_f32_16x16x32_bf16(a[i], b[j], acc[i][j], 0, 0, 0);
    }
    int orow = (lane >> 4) * 4;
    #pragma unroll
    for (int i = 0; i < 4; i++)
        #pragma unroll
        for (int j = 0; j < 4; j++) {
            int col = nbase + j * 16 + lm;
            float bias = bo[col];
            #pragma unroll
            for (int r = 0; r < 4; r++) {
                int row = mbase + i * 16 + orow + r;
                out[(size_t)row * INDIM + col] = acc[i][j][r] + bias;
            }
        }
}

// ---- K5: LN + GELU in place on d_out ----
__global__ __launch_bounds__(256) void k5_ln(float* __restrict__ out,
        const float* __restrict__ g, const float* __restrict__ b) {
    __shared__ float red[4];
    int tid = threadIdx.x;
    size_t row = blockIdx.x;
    float4 v = *(const float4*)(out + row * INDIM + tid * 4);
    float s = v.x + v.y + v.z + v.w;
    #pragma unroll
    for (int off = 32; off; off >>= 1) s += __shfl_xor(s, off);
    int wid = tid >> 6, lane = tid & 63;
    if (!lane) red[wid] = s;
    __syncthreads();
    float mean = (red[0] + red[1] + red[2] + red[3]) * (1.f / (float)INDIM);
    __syncthreads();
    float dx = v.x - mean, dy = v.y - mean, dz = v.z - mean, dw = v.w - mean;
    float ss = dx * dx + dy * dy + dz * dz + dw * dw;
    #pragma unroll
    for (int off = 32; off; off >>= 1) ss += __shfl_xor(ss, off);
    if (!lane) red[wid] = ss;
    __syncthreads();
    float var = (red[0] + red[1] + red[2] + red[3]) * (1.f / (float)INDIM);
    float rs = rsqrtf(var + 1e-5f);
    int c = tid * 4;
    float4 o;
    o.x = gelu_exact(dx * rs * g[c + 0] + b[c + 0]);
    o.y = gelu_exact(dy * rs * g[c + 1] + b[c + 1]);
    o.z = gelu_exact(dz * rs * g[c + 2] + b[c + 2]);
    o.w = gelu_exact(dw * rs * g[c + 3] + b[c + 3]);
    *(float4*)(out + row * INDIM + c) = o;
}

extern "C" void kernel_launch(void* const* d_in, const int* in_sizes, int n_in,
                              void* d_out, int out_size, void* d_ws, size_t ws_size,
                              hipStream_t stream) {
    const float* x     = (const float*)d_in[0];
    const float* Wp    = (const float*)d_in[1];
    const float* bp    = (const float*)d_in[2];
    const float* ln1g  = (const float*)d_in[3];
    const float* ln1b  = (const float*)d_in[4];
    const float* oW1   = (const float*)d_in[5];
    const float* ob1   = (const float*)d_in[6];
    const float* oW2   = (const float*)d_in[7];
    const float* ob2   = (const float*)d_in[8];
    const float* slots = (const float*)d_in[9];
    const float* pe    = (const float*)d_in[10];
    const float* curv  = (const float*)d_in[11];
    const float* alpha = (const float*)d_in[12];
    const float* Wo    = (const float*)d_in[13];
    const float* bo    = (const float*)d_in[14];
    const float* ln2g  = (const float*)d_in[15];
    const float* ln2b  = (const float*)d_in[16];
    float* out = (float*)d_out;
    char* ws = (char*)d_ws;

    float* h0     = (float*)(ws + OFF_H);
    float* m2     = (float*)(ws + OFF_M2);
    float* cwv    = (float*)(ws + OFF_CW);
    float* topv   = (float*)(ws + OFF_TOPV);
    int*   topi   = (int*)  (ws + OFF_TOPI);
    float* rowmin = (float*)(ws + OFF_RMIN);
    int*   flag   = (int*)  (ws + OFF_FLAG);
    unsigned short* attb = (unsigned short*)(ws + OFF_ATTB);
    unsigned short* wot  = (unsigned short*)(ws + OFF_WOT);
    float* dist   = (float*)(ws + OFF_DIST);
    float* hpart  = dist;   // aliased: consumed before dist is produced

    k0_prep<<<MSLOT / 256, 256, 0, stream>>>(pe, curv, alpha, m2, cwv);
    k0b_cvt<<<dim3(4, 16), 256, 0, stream>>>(Wo, wot);
    k1_proj<<<dim3(SPLITK, NQ / 64), 64, 0, stream>>>(x, Wp, hpart);
    k1b_ode<<<NQ / 32, 256, 0, stream>>>(hpart, bp, ln1g, ln1b, oW1, ob1, oW2, ob2, h0);
    for (int ch = 0; ch < NQ / CHUNK; ch++) {
        k2a_dist<<<dim3(32, 16), 256, 0, stream>>>(h0, pe, m2, cwv, dist, ch * CHUNK);
        k2b_topk<<<CHUNK, 256, 0, stream>>>(dist, topv, topi, rowmin, ch * CHUNK);
    }
    k3a_flag<<<1, 256, 0, stream>>>(rowmin, flag);
    k3_attend<<<NQ / 4, 256, 0, stream>>>(topv, topi, flag, slots, attb);
    k4_mfma<<<dim3(INDIM / 128, NQ / 128), 256, 0, stream>>>(attb, wot, bo, out);
    k5_ln<<<NQ, 256, 0, stream>>>(out, ln2g, ln2b);
}

// Round 5
// 484.933 us; speedup vs baseline: 2.0073x; 1.0167x over previous
//
#include <hip/hip_runtime.h>
#include <math.h>

#define NQ    8192   // B*S
#define T3    48
#define INDIM 1024
#define HID   128
#define MSLOT 8192
#define HD    256
#define KBIG  48
#define KBASE 32
#define SPLITK 8
#define KSLICE 128   // INDIM / SPLITK

// ---- workspace layout (bytes) ----
#define OFF_H    ((size_t)0)                         // 8192*48 f32   = 1,572,864
#define OFF_M2   ((size_t)1572864)                   // 8192 f32
#define OFF_CW   ((size_t)1605632)                   // 8192 f32
#define OFF_TOPV ((size_t)1638400)                   // 8192*48 f32
#define OFF_TOPI ((size_t)3211264)                   // 8192*48 i32
#define OFF_RMIN ((size_t)4784128)                   // 8192 f32
#define OFF_FLAG ((size_t)4816896)                   // 1 i32 (+pad)
#define OFF_ATTB ((size_t)4817152)                   // 8192*256 bf16 = 4,194,304
#define OFF_WOT  ((size_t)9011456)                   // 1024*256 bf16 = 524,288
#define OFF_HPART ((size_t)13205760)                 // 8*8192*48 f32 = 12.6MB

typedef __attribute__((ext_vector_type(8))) short short8;
typedef __attribute__((ext_vector_type(4))) float f32x4;

__device__ __forceinline__ float gelu_exact(float x) {
    return 0.5f * x * (1.0f + erff(x * 0.70710678118654752f));
}

__device__ __forceinline__ unsigned short bf16_rne(float f) {
    unsigned int x = __float_as_uint(f);
    unsigned int r = (x + 0x7fffu + ((x >> 16) & 1u)) >> 16;
    return (unsigned short)r;
}

__device__ __forceinline__ unsigned long long shfl_up1_u64(unsigned long long v) {
    unsigned lo = (unsigned)v, hi = (unsigned)(v >> 32);
    lo = (unsigned)__shfl_up((int)lo, 1);
    hi = (unsigned)__shfl_up((int)hi, 1);
    return ((unsigned long long)hi << 32) | lo;
}

// ---- K0: m2[m] = ||mem_pos[m]||^2 ; cw[m] = exp(-alpha*||curv[m]||) ----
__global__ __launch_bounds__(256) void k0_prep(const float* __restrict__ pe,
        const float* __restrict__ curv, const float* __restrict__ alpha,
        float* __restrict__ m2, float* __restrict__ cw) {
    int m = blockIdx.x * 256 + threadIdx.x;
    float s = 0.f;
    for (int d = 0; d < T3; d++) { float v = pe[(size_t)m * T3 + d]; s += v * v; }
    m2[m] = s;
    float c = 0.f;
    for (int d = 0; d < 16; d++) { float v = curv[m * 16 + d]; c += v * v; }
    cw[m] = expf(-alpha[0] * sqrtf(c));
}

// ---- K0b: Wo_t[n][k] = bf16(Wo[k][n])  (tiled transpose) ----
__global__ __launch_bounds__(256) void k0b_cvt(const float* __restrict__ Wo,
        unsigned short* __restrict__ Wot) {
    __shared__ float t[64][65];
    int k0 = blockIdx.x * 64;
    int n0 = blockIdx.y * 64;
    int c = threadIdx.x & 63, r4 = threadIdx.x >> 6;
    #pragma unroll
    for (int i = 0; i < 16; i++) {
        int kr = i * 4 + r4;
        t[kr][c] = Wo[(size_t)(k0 + kr) * INDIM + n0 + c];
    }
    __syncthreads();
    #pragma unroll
    for (int i = 0; i < 16; i++) {
        int nr = i * 4 + r4;
        Wot[(size_t)(n0 + nr) * HD + k0 + c] = bf16_rne(t[c][nr]);
    }
}

// ---- K1: hpart[slice] = x[:, slice] @ Wp[slice]; 4r x 12c per thread, b128 LDS ----
__global__ __launch_bounds__(64) void k1_proj(const float* __restrict__ x,
        const float* __restrict__ Wp, float* __restrict__ hpart) {
    __shared__ __align__(16) float xs_t[64][68];
    __shared__ __align__(16) float ws_s[64][48];
    int tid = threadIdx.x;
    int slice = blockIdx.x;
    int r0 = blockIdx.y * 64;
    int kbase = slice * KSLICE;
    int rt = tid >> 2, ct = tid & 3;
    float acc[4][12];
    #pragma unroll
    for (int i = 0; i < 4; i++)
        #pragma unroll
        for (int j = 0; j < 12; j++) acc[i][j] = 0.f;
    for (int kt = 0; kt < KSLICE; kt += 64) {
        int k0 = kbase + kt;
        for (int idx = tid; idx < 1024; idx += 64) {
            int r = idx >> 4, c4 = idx & 15;
            float4 v = *(const float4*)(x + (size_t)(r0 + r) * INDIM + k0 + c4 * 4);
            xs_t[c4 * 4 + 0][r] = v.x; xs_t[c4 * 4 + 1][r] = v.y;
            xs_t[c4 * 4 + 2][r] = v.z; xs_t[c4 * 4 + 3][r] = v.w;
        }
        for (int idx = tid; idx < 768; idx += 64) {
            int r = idx / 12, c4 = idx % 12;
            float4 v = *(const float4*)(Wp + (size_t)(k0 + r) * T3 + c4 * 4);
            ws_s[r][c4 * 4 + 0] = v.x; ws_s[r][c4 * 4 + 1] = v.y;
            ws_s[r][c4 * 4 + 2] = v.z; ws_s[r][c4 * 4 + 3] = v.w;
        }
        __syncthreads();
        #pragma unroll 4
        for (int kk = 0; kk < 64; kk++) {
            float4 a = *(const float4*)&xs_t[kk][rt * 4];
            float4 b0 = *(const float4*)&ws_s[kk][ct * 12];
            float4 b1 = *(const float4*)&ws_s[kk][ct * 12 + 4];
            float4 b2 = *(const float4*)&ws_s[kk][ct * 12 + 8];
            float av[4] = {a.x, a.y, a.z, a.w};
            #pragma unroll
            for (int i = 0; i < 4; i++) {
                acc[i][0] += av[i] * b0.x; acc[i][1] += av[i] * b0.y;
                acc[i][2] += av[i] * b0.z; acc[i][3] += av[i] * b0.w;
                acc[i][4] += av[i] * b1.x; acc[i][5] += av[i] * b1.y;
                acc[i][6] += av[i] * b1.z; acc[i][7] += av[i] * b1.w;
                acc[i][8] += av[i] * b2.x; acc[i][9] += av[i] * b2.y;
                acc[i][10] += av[i] * b2.z; acc[i][11] += av[i] * b2.w;
            }
        }
        __syncthreads();
    }
    float* dst = hpart + (size_t)slice * NQ * T3;
    #pragma unroll
    for (int i = 0; i < 4; i++) {
        size_t row = (size_t)(r0 + rt * 4 + i);
        #pragma unroll
        for (int jj = 0; jj < 3; jj++) {
            float4 o;
            o.x = acc[i][jj * 4 + 0]; o.y = acc[i][jj * 4 + 1];
            o.z = acc[i][jj * 4 + 2]; o.w = acc[i][jj * 4 + 3];
            *(float4*)(dst + row * T3 + ct * 12 + jj * 4) = o;
        }
    }
}

// ---- K1b v3: 16 rows/block (512 blocks), b128 LDS everywhere ----
__global__ __launch_bounds__(256) void k1b_ode(const float* __restrict__ hpart,
        const float* __restrict__ bp,
        const float* __restrict__ g1, const float* __restrict__ b1ln,
        const float* __restrict__ W1, const float* __restrict__ bb1,
        const float* __restrict__ W2, const float* __restrict__ bb2,
        float* __restrict__ h) {
    __shared__ __align__(16) float W1s[T3 * HID];     // [d][j] 24KB
    __shared__ __align__(16) float W2s[HID * T3];     // [j][c] 24KB
    __shared__ __align__(16) float hs[16 * T3];       // 3KB
    __shared__ __align__(16) float t1s[16 * 132];     // 8.25KB (padded stride)
    int tid = threadIdx.x;
    size_t base = (size_t)blockIdx.x * 16 * T3;
    for (int i = tid; i < 1536; i += 256) {
        *(float4*)&W1s[i * 4] = *(const float4*)&W1[i * 4];
        *(float4*)&W2s[i * 4] = *(const float4*)&W2[i * 4];
    }
    for (int idx = tid; idx < 16 * T3; idx += 256) {
        int c = idx % T3;
        float a = bp[c];
        #pragma unroll
        for (int s = 0; s < SPLITK; s++) a += hpart[(size_t)s * NQ * T3 + base + idx];
        t1s[idx] = a;                 // flat temp for pre-LN values
    }
    __syncthreads();
    {   // LN + GELU: 16 lanes per row, 3 elems each
        int r = tid >> 4, c16 = tid & 15;
        float v[3];
        float ssum = 0.f;
        #pragma unroll
        for (int i = 0; i < 3; i++) { v[i] = t1s[r * T3 + c16 * 3 + i]; ssum += v[i]; }
        #pragma unroll
        for (int off = 1; off < 16; off <<= 1) ssum += __shfl_xor(ssum, off);
        float mean = ssum * (1.f / T3);
        float vv = 0.f;
        #pragma unroll
        for (int i = 0; i < 3; i++) { v[i] -= mean; vv += v[i] * v[i]; }
        #pragma unroll
        for (int off = 1; off < 16; off <<= 1) vv += __shfl_xor(vv, off);
        float rstd = rsqrtf(vv * (1.f / T3) + 1e-5f);
        #pragma unroll
        for (int i = 0; i < 3; i++) {
            int c = c16 * 3 + i;
            hs[r * T3 + c] = gelu_exact(v[i] * rstd * g1[c] + b1ln[c]);
        }
    }
    __syncthreads();
    for (int step = 0; step < 2; step++) {
        // loop1: 512 output-quads (rr, j4)
        #pragma unroll
        for (int it = 0; it < 2; it++) {
            int idx = tid + it * 256;
            int rr = idx >> 5, j4 = idx & 31;
            float4 a = *(const float4*)&bb1[j4 * 4];
            #pragma unroll 3
            for (int d4 = 0; d4 < 12; d4++) {
                float4 qv = *(const float4*)&hs[rr * T3 + d4 * 4];
                float qa[4] = {qv.x, qv.y, qv.z, qv.w};
                #pragma unroll
                for (int dd = 0; dd < 4; dd++) {
                    float4 wv = *(const float4*)&W1s[(d4 * 4 + dd) * HID + j4 * 4];
                    a.x += qa[dd] * wv.x; a.y += qa[dd] * wv.y;
                    a.z += qa[dd] * wv.z; a.w += qa[dd] * wv.w;
                }
            }
            a.x = tanhf(a.x); a.y = tanhf(a.y); a.z = tanhf(a.z); a.w = tanhf(a.w);
            *(float4*)&t1s[rr * 132 + j4 * 4] = a;
        }
        __syncthreads();
        // loop2: 192 output-quads (rr, c4)
        if (tid < 192) {
            int rr = tid / 12, c4 = tid % 12;
            float4 a = *(const float4*)&bb2[c4 * 4];
            #pragma unroll 4
            for (int j4 = 0; j4 < 32; j4++) {
                float4 tv = *(const float4*)&t1s[rr * 132 + j4 * 4];
                float ta[4] = {tv.x, tv.y, tv.z, tv.w};
                #pragma unroll
                for (int jj = 0; jj < 4; jj++) {
                    float4 wv = *(const float4*)&W2s[(j4 * 4 + jj) * T3 + c4 * 4];
                    a.x += ta[jj] * wv.x; a.y += ta[jj] * wv.y;
                    a.z += ta[jj] * wv.z; a.w += ta[jj] * wv.w;
                }
            }
            float4 cur = *(const float4*)&hs[rr * T3 + c4 * 4];
            cur.x += 0.5f * a.x; cur.y += 0.5f * a.y;
            cur.z += 0.5f * a.z; cur.w += 0.5f * a.w;
            *(float4*)&hs[rr * T3 + c4 * 4] = cur;
        }
        __syncthreads();
    }
    for (int idx = tid; idx < 16 * T3; idx += 256) h[base + idx] = hs[idx];
}

// ---- K2 fused: dist + exact top-48, no materialization ----
// 512 blocks x 256 thr; block = 16 q-rows; wave = 4 rows; lane = 4 consecutive cols.
// Wave-register sorted list: lane j holds rank-j (valbits<<32|idx); insert via ballot+shfl.
#define MT 260
__global__ __launch_bounds__(256) void k2_fused(const float* __restrict__ h,
        const float* __restrict__ pe, const float* __restrict__ m2,
        const float* __restrict__ cw, float* __restrict__ topv,
        int* __restrict__ topi, float* __restrict__ rowmin) {
    __shared__ __align__(16) float ms_t[T3 * MT];   // [d][col] 49.9KB
    __shared__ __align__(16) float qs[16 * 52];     // [r][d] 3.3KB
    __shared__ float q2s[16];
    int tid = threadIdx.x, lane = tid & 63, wv = tid >> 6;
    int r0 = blockIdx.x * 16;
    int wr0 = wv * 4;
    for (int idx = tid; idx < 192; idx += 256) {
        int r = idx / 12, d4 = idx % 12;
        *(float4*)&qs[r * 52 + d4 * 4] = *(const float4*)(h + (size_t)(r0 + r) * T3 + d4 * 4);
    }
    __syncthreads();
    if (tid < 16) {
        float s = 0.f;
        for (int k = 0; k < T3; k++) { float v = qs[tid * 52 + k]; s += v * v; }
        q2s[tid] = s;
    }
    unsigned long long list[4];
    float bound[4];
    #pragma unroll
    for (int r = 0; r < 4; r++) {
        list[r] = 0x7F800000FFFFFFFFULL;            // +inf sentinel, max idx
        bound[r] = __uint_as_float(0x7F800000u);    // +inf
    }
    for (int t = 0; t < MSLOT / 256; t++) {
        int c0 = t * 256;
        __syncthreads();
        #pragma unroll 3
        for (int it = 0; it < 12; it++) {
            float4 v = *(const float4*)(pe + (size_t)(c0 + tid) * T3 + it * 4);
            ms_t[(it * 4 + 0) * MT + tid] = v.x;
            ms_t[(it * 4 + 1) * MT + tid] = v.y;
            ms_t[(it * 4 + 2) * MT + tid] = v.z;
            ms_t[(it * 4 + 3) * MT + tid] = v.w;
        }
        __syncthreads();
        float acc[4][4];
        #pragma unroll
        for (int r = 0; r < 4; r++)
            #pragma unroll
            for (int g = 0; g < 4; g++) acc[r][g] = 0.f;
        #pragma unroll 3
        for (int d4 = 0; d4 < 12; d4++) {
            float4 qv[4];
            #pragma unroll
            for (int r = 0; r < 4; r++)
                qv[r] = *(const float4*)&qs[(wr0 + r) * 52 + d4 * 4];
            #pragma unroll
            for (int dd = 0; dd < 4; dd++) {
                float4 mv = *(const float4*)&ms_t[(d4 * 4 + dd) * MT + 4 * lane];
                #pragma unroll
                for (int r = 0; r < 4; r++) {
                    float a = (dd == 0) ? qv[r].x : (dd == 1) ? qv[r].y
                            : (dd == 2) ? qv[r].z : qv[r].w;
                    acc[r][0] += a * mv.x; acc[r][1] += a * mv.y;
                    acc[r][2] += a * mv.z; acc[r][3] += a * mv.w;
                }
            }
        }
        float4 m2v = *(const float4*)(m2 + c0 + 4 * lane);
        float4 cwv4 = *(const float4*)(cw + c0 + 4 * lane);
        float m2a[4] = {m2v.x, m2v.y, m2v.z, m2v.w};
        float cwa[4] = {cwv4.x, cwv4.y, cwv4.z, cwv4.w};
        float dv[4][4];
        #pragma unroll
        for (int r = 0; r < 4; r++) {
            float q2 = q2s[wr0 + r];
            #pragma unroll
            for (int g = 0; g < 4; g++)
                dv[r][g] = fmaxf(q2 + m2a[g] - 2.f * acc[r][g], 0.f) * cwa[g];
        }
        #pragma unroll
        for (int r = 0; r < 4; r++) {
            #pragma unroll
            for (int g = 0; g < 4; g++) {
                unsigned long long mask = __ballot(dv[r][g] <= bound[r]);
                while (mask) {
                    int l = __ffsll((unsigned long long)mask) - 1;
                    mask &= mask - 1;
                    float v = __shfl(dv[r][g], l);
                    unsigned long long key =
                        ((unsigned long long)__float_as_uint(v) << 32)
                        | (unsigned)(c0 + 4 * l + g);
                    unsigned long long gtmask = __ballot(list[r] > key);
                    if (gtmask == 0ULL) continue;   // worse than whole list
                    unsigned long long sh = shfl_up1_u64(list[r]);
                    int p = __ffsll((unsigned long long)gtmask) - 1;
                    if (lane == p) list[r] = key;
                    else if (lane > p) list[r] = sh;
                    unsigned bhi = (unsigned)(list[r] >> 32);
                    bound[r] = __uint_as_float(__shfl((int)bhi, 47));
                }
            }
        }
    }
    #pragma unroll
    for (int r = 0; r < 4; r++) {
        size_t row = (size_t)(r0 + wr0 + r);
        float v = __uint_as_float((unsigned)(list[r] >> 32));
        int idx = (int)(list[r] & 0xFFFFFFFFu);
        if (lane < KBIG) {
            topv[row * KBIG + lane] = v;
            topi[row * KBIG + lane] = idx;
        }
        if (lane == 0) rowmin[row] = v;
    }
}

// ---- K3a: fire flag = (mean of row mins) < 0.7 ----
__global__ __launch_bounds__(256) void k3a_flag(const float* __restrict__ rowmin,
        int* __restrict__ flag) {
    __shared__ float red[256];
    int tid = threadIdx.x;
    float s = 0.f;
    for (int j = 0; j < NQ / 256; j++) s += rowmin[tid + 256 * j];
    red[tid] = s;
    __syncthreads();
    for (int st = 128; st; st >>= 1) {
        if (tid < st) red[tid] += red[tid + st];
        __syncthreads();
    }
    if (tid == 0) {
        float top1 = red[0] / (float)NQ;
        flag[0] = (top1 < 0.7f) ? 1 : 0;
    }
}

// ---- K3: wave per row; float4 gathers; writes att as bf16 ----
__global__ __launch_bounds__(256) void k3_attend(const float* __restrict__ topv,
        const int* __restrict__ topi, const int* __restrict__ flag,
        const float* __restrict__ slots, unsigned short* __restrict__ attb) {
    int tid = threadIdx.x;
    int lane = tid & 63, wv = tid >> 6;
    size_t row = (size_t)blockIdx.x * 4 + wv;
    int kc = flag[0] ? KBIG : KBASE;
    float v0 = topv[row * KBIG];
    float ev = 0.f;
    int mi = 0;
    if (lane < KBIG) {
        float v = topv[row * KBIG + lane];
        ev = (lane < kc) ? expf(-(v - v0)) : 0.f;
        mi = topi[row * KBIG + lane];
    }
    float ssum = ev;
    #pragma unroll
    for (int off = 32; off; off >>= 1) ssum += __shfl_xor(ssum, off);
    float inv = 1.f / ssum;
    float4 acc = make_float4(0.f, 0.f, 0.f, 0.f);
    for (int k = 0; k < kc; k++) {
        float wk = __shfl(ev, k) * inv;
        int m = __shfl(mi, k);
        float4 v = *(const float4*)(slots + (size_t)m * HD + lane * 4);
        acc.x += wk * v.x; acc.y += wk * v.y;
        acc.z += wk * v.z; acc.w += wk * v.w;
    }
    ushort4 o;
    o.x = bf16_rne(acc.x); o.y = bf16_rne(acc.y);
    o.z = bf16_rne(acc.z); o.w = bf16_rne(acc.w);
    *(ushort4*)(attb + row * HD + lane * 4) = o;
}

// ---- K4: out = att(bf16) @ Wo_t(bf16)^T + bo via MFMA 16x16x32 ----
__global__ __launch_bounds__(256) void k4_mfma(const unsigned short* __restrict__ A,
        const unsigned short* __restrict__ Bt, const float* __restrict__ bo,
        float* __restrict__ out) {
    int tid = threadIdx.x;
    int lane = tid & 63, wave = tid >> 6;
    int wm = wave >> 1, wn = wave & 1;
    int mbase = blockIdx.y * 128 + wm * 64;
    int nbase = blockIdx.x * 128 + wn * 64;
    int lm = lane & 15;
    int lk8 = (lane >> 4) * 8;
    f32x4 acc[4][4];
    #pragma unroll
    for (int i = 0; i < 4; i++)
        #pragma unroll
        for (int j = 0; j < 4; j++) acc[i][j] = (f32x4)(0.f);
    #pragma unroll 2
    for (int ks = 0; ks < 8; ks++) {
        int kofs = ks * 32 + lk8;
        short8 a[4], b[4];
        #pragma unroll
        for (int i = 0; i < 4; i++)
            a[i] = *(const short8*)(A + (size_t)(mbase + i * 16 + lm) * HD + kofs);
        #pragma unroll
        for (int j = 0; j < 4; j++)
            b[j] = *(const short8*)(Bt + (size_t)(nbase + j * 16 + lm) * HD + kofs);
        #pragma unroll
        for (int i = 0; i < 4; i++)
            #pragma unroll
            for (int j = 0; j < 4; j++)
                acc[i][j] = __builtin_amdgcn_mfma_f32_16x16x32_bf16(a[i], b[j], acc[i][j], 0, 0, 0);
    }
    int orow = (lane >> 4) * 4;
    #pragma unroll
    for (int i = 0; i < 4; i++)
        #pragma unroll
        for (int j = 0; j < 4; j++) {
            int col = nbase + j * 16 + lm;
            float bias = bo[col];
            #pragma unroll
            for (int r = 0; r < 4; r++) {
                int row = mbase + i * 16 + orow + r;
                out[(size_t)row * INDIM + col] = acc[i][j][r] + bias;
            }
        }
}

// ---- K5: LN + GELU in place on d_out ----
__global__ __launch_bounds__(256) void k5_ln(float* __restrict__ out,
        const float* __restrict__ g, const float* __restrict__ b) {
    __shared__ float red[4];
    int tid = threadIdx.x;
    size_t row = blockIdx.x;
    float4 v = *(const float4*)(out + row * INDIM + tid * 4);
    float s = v.x + v.y + v.z + v.w;
    #pragma unroll
    for (int off = 32; off; off >>= 1) s += __shfl_xor(s, off);
    int wid = tid >> 6, lane = tid & 63;
    if (!lane) red[wid] = s;
    __syncthreads();
    float mean = (red[0] + red[1] + red[2] + red[3]) * (1.f / (float)INDIM);
    __syncthreads();
    float dx = v.x - mean, dy = v.y - mean, dz = v.z - mean, dw = v.w - mean;
    float ss = dx * dx + dy * dy + dz * dz + dw * dw;
    #pragma unroll
    for (int off = 32; off; off >>= 1) ss += __shfl_xor(ss, off);
    if (!lane) red[wid] = ss;
    __syncthreads();
    float var = (red[0] + red[1] + red[2] + red[3]) * (1.f / (float)INDIM);
    float rs = rsqrtf(var + 1e-5f);
    int c = tid * 4;
    float4 o;
    o.x = gelu_exact(dx * rs * g[c + 0] + b[c + 0]);
    o.y = gelu_exact(dy * rs * g[c + 1] + b[c + 1]);
    o.z = gelu_exact(dz * rs * g[c + 2] + b[c + 2]);
    o.w = gelu_exact(dw * rs * g[c + 3] + b[c + 3]);
    *(float4*)(out + row * INDIM + c) = o;
}

extern "C" void kernel_launch(void* const* d_in, const int* in_sizes, int n_in,
                              void* d_out, int out_size, void* d_ws, size_t ws_size,
                              hipStream_t stream) {
    const float* x     = (const float*)d_in[0];
    const float* Wp    = (const float*)d_in[1];
    const float* bp    = (const float*)d_in[2];
    const float* ln1g  = (const float*)d_in[3];
    const float* ln1b  = (const float*)d_in[4];
    const float* oW1   = (const float*)d_in[5];
    const float* ob1   = (const float*)d_in[6];
    const float* oW2   = (const float*)d_in[7];
    const float* ob2   = (const float*)d_in[8];
    const float* slots = (const float*)d_in[9];
    const float* pe    = (const float*)d_in[10];
    const float* curv  = (const float*)d_in[11];
    const float* alpha = (const float*)d_in[12];
    const float* Wo    = (const float*)d_in[13];
    const float* bo    = (const float*)d_in[14];
    const float* ln2g  = (const float*)d_in[15];
    const float* ln2b  = (const float*)d_in[16];
    float* out = (float*)d_out;
    char* ws = (char*)d_ws;

    float* h0     = (float*)(ws + OFF_H);
    float* m2     = (float*)(ws + OFF_M2);
    float* cwv    = (float*)(ws + OFF_CW);
    float* topv   = (float*)(ws + OFF_TOPV);
    int*   topi   = (int*)  (ws + OFF_TOPI);
    float* rowmin = (float*)(ws + OFF_RMIN);
    int*   flag   = (int*)  (ws + OFF_FLAG);
    unsigned short* attb = (unsigned short*)(ws + OFF_ATTB);
    unsigned short* wot  = (unsigned short*)(ws + OFF_WOT);
    float* hpart  = (float*)(ws + OFF_HPART);

    k0_prep<<<MSLOT / 256, 256, 0, stream>>>(pe, curv, alpha, m2, cwv);
    k0b_cvt<<<dim3(4, 16), 256, 0, stream>>>(Wo, wot);
    k1_proj<<<dim3(SPLITK, NQ / 64), 64, 0, stream>>>(x, Wp, hpart);
    k1b_ode<<<NQ / 16, 256, 0, stream>>>(hpart, bp, ln1g, ln1b, oW1, ob1, oW2, ob2, h0);
    k2_fused<<<NQ / 16, 256, 0, stream>>>(h0, pe, m2, cwv, topv, topi, rowmin);
    k3a_flag<<<1, 256, 0, stream>>>(rowmin, flag);
    k3_attend<<<NQ / 4, 256, 0, stream>>>(topv, topi, flag, slots, attb);
    k4_mfma<<<dim3(INDIM / 128, NQ / 128), 256, 0, stream>>>(attb, wot, bo, out);
    k5_ln<<<NQ, 256, 0, stream>>>(out, ln2g, ln2b);
}

// Round 6
// 418.209 us; speedup vs baseline: 2.3275x; 1.1595x over previous
//
#include <hip/hip_runtime.h>
#include <math.h>

#define NQ    8192   // B*S
#define T3    48
#define INDIM 1024
#define HID   128
#define MSLOT 8192
#define HD    256
#define KBIG  48
#define KBASE 32
#define CHUNK 1024
#define SPLITK 8
#define KSLICE 128   // INDIM / SPLITK

// ---- workspace layout (bytes) ----
#define OFF_QH    ((size_t)0)           // 8192*64 bf16 = 1,048,576
#define OFF_QL    ((size_t)1048576)     // 8192*64 bf16
#define OFF_Q2    ((size_t)2097152)     // 8192 f32
#define OFF_M2    ((size_t)2129920)     // 8192 f32
#define OFF_CW    ((size_t)2162688)     // 8192 f32
#define OFF_TOPV  ((size_t)2195456)     // 8192*48 f32
#define OFF_TOPI  ((size_t)3768320)     // 8192*48 i32
#define OFF_RMIN  ((size_t)5341184)     // 8192 f32
#define OFF_FLAG  ((size_t)5373952)     // 1 i32
#define OFF_ATTB  ((size_t)5374208)     // 8192*256 bf16 = 4,194,304
#define OFF_WOT   ((size_t)9568512)     // 1024*256 bf16 = 524,288
#define OFF_PEH   ((size_t)10092800)    // 8192*64 bf16 = 1,048,576
#define OFF_PEL   ((size_t)11141376)    // 8192*64 bf16
#define OFF_HPART ((size_t)12189952)    // 8*8192*48 f32 = 12.58MB (dead after k1b)
#define OFF_DIST  ((size_t)12189952)    // CHUNK*8192 f32 = 33.55MB (aliases hpart)
// end = 45,744,384 < proven 46.76MB ws footprint

typedef __attribute__((ext_vector_type(8))) short short8;
typedef __attribute__((ext_vector_type(4))) float f32x4;

__device__ __forceinline__ float gelu_exact(float x) {
    return 0.5f * x * (1.0f + erff(x * 0.70710678118654752f));
}

__device__ __forceinline__ unsigned short bf16_rne(float f) {
    unsigned int x = __float_as_uint(f);
    unsigned int r = (x + 0x7fffu + ((x >> 16) & 1u)) >> 16;
    return (unsigned short)r;
}

// ---- K0: m2, cw, and pe hi/lo bf16 (K padded to 64) ----
__global__ __launch_bounds__(256) void k0_prep(const float* __restrict__ pe,
        const float* __restrict__ curv, const float* __restrict__ alpha,
        float* __restrict__ m2, float* __restrict__ cw,
        unsigned short* __restrict__ ph, unsigned short* __restrict__ pl) {
    int m = blockIdx.x * 256 + threadIdx.x;
    float s = 0.f;
    for (int d = 0; d < T3; d++) { float v = pe[(size_t)m * T3 + d]; s += v * v; }
    m2[m] = s;
    float c = 0.f;
    for (int d = 0; d < 16; d++) { float v = curv[m * 16 + d]; c += v * v; }
    cw[m] = expf(-alpha[0] * sqrtf(c));
    int base = blockIdx.x * 256;
    for (int idx = threadIdx.x; idx < 256 * 64; idx += 256) {
        int r = idx >> 6, cc = idx & 63;
        unsigned short hi = 0, lo = 0;
        if (cc < T3) {
            float x = pe[(size_t)(base + r) * T3 + cc];
            hi = bf16_rne(x);
            lo = bf16_rne(x - __uint_as_float((unsigned)hi << 16));
        }
        size_t o = (size_t)(base + r) * 64 + cc;
        ph[o] = hi; pl[o] = lo;
    }
}

// ---- K0b: Wo_t[n][k] = bf16(Wo[k][n]) ----
__global__ __launch_bounds__(256) void k0b_cvt(const float* __restrict__ Wo,
        unsigned short* __restrict__ Wot) {
    __shared__ float t[64][65];
    int k0 = blockIdx.x * 64;
    int n0 = blockIdx.y * 64;
    int c = threadIdx.x & 63, r4 = threadIdx.x >> 6;
    #pragma unroll
    for (int i = 0; i < 16; i++) {
        int kr = i * 4 + r4;
        t[kr][c] = Wo[(size_t)(k0 + kr) * INDIM + n0 + c];
    }
    __syncthreads();
    #pragma unroll
    for (int i = 0; i < 16; i++) {
        int nr = i * 4 + r4;
        Wot[(size_t)(n0 + nr) * HD + k0 + c] = bf16_rne(t[c][nr]);
    }
}

// ---- K1: hpart[slice] = x[:, slice] @ Wp[slice] ----
__global__ __launch_bounds__(64) void k1_proj(const float* __restrict__ x,
        const float* __restrict__ Wp, float* __restrict__ hpart) {
    __shared__ __align__(16) float xs_t[64][68];
    __shared__ __align__(16) float ws_s[64][48];
    int tid = threadIdx.x;
    int slice = blockIdx.x;
    int r0 = blockIdx.y * 64;
    int kbase = slice * KSLICE;
    int rt = tid >> 2, ct = tid & 3;
    float acc[4][12];
    #pragma unroll
    for (int i = 0; i < 4; i++)
        #pragma unroll
        for (int j = 0; j < 12; j++) acc[i][j] = 0.f;
    for (int kt = 0; kt < KSLICE; kt += 64) {
        int k0 = kbase + kt;
        for (int idx = tid; idx < 1024; idx += 64) {
            int r = idx >> 4, c4 = idx & 15;
            float4 v = *(const float4*)(x + (size_t)(r0 + r) * INDIM + k0 + c4 * 4);
            xs_t[c4 * 4 + 0][r] = v.x; xs_t[c4 * 4 + 1][r] = v.y;
            xs_t[c4 * 4 + 2][r] = v.z; xs_t[c4 * 4 + 3][r] = v.w;
        }
        for (int idx = tid; idx < 768; idx += 64) {
            int r = idx / 12, c4 = idx % 12;
            float4 v = *(const float4*)(Wp + (size_t)(k0 + r) * T3 + c4 * 4);
            ws_s[r][c4 * 4 + 0] = v.x; ws_s[r][c4 * 4 + 1] = v.y;
            ws_s[r][c4 * 4 + 2] = v.z; ws_s[r][c4 * 4 + 3] = v.w;
        }
        __syncthreads();
        #pragma unroll 4
        for (int kk = 0; kk < 64; kk++) {
            float4 a = *(const float4*)&xs_t[kk][rt * 4];
            float4 b0 = *(const float4*)&ws_s[kk][ct * 12];
            float4 b1 = *(const float4*)&ws_s[kk][ct * 12 + 4];
            float4 b2 = *(const float4*)&ws_s[kk][ct * 12 + 8];
            float av[4] = {a.x, a.y, a.z, a.w};
            #pragma unroll
            for (int i = 0; i < 4; i++) {
                acc[i][0] += av[i] * b0.x; acc[i][1] += av[i] * b0.y;
                acc[i][2] += av[i] * b0.z; acc[i][3] += av[i] * b0.w;
                acc[i][4] += av[i] * b1.x; acc[i][5] += av[i] * b1.y;
                acc[i][6] += av[i] * b1.z; acc[i][7] += av[i] * b1.w;
                acc[i][8] += av[i] * b2.x; acc[i][9] += av[i] * b2.y;
                acc[i][10] += av[i] * b2.z; acc[i][11] += av[i] * b2.w;
            }
        }
        __syncthreads();
    }
    float* dst = hpart + (size_t)slice * NQ * T3;
    #pragma unroll
    for (int i = 0; i < 4; i++) {
        size_t row = (size_t)(r0 + rt * 4 + i);
        #pragma unroll
        for (int jj = 0; jj < 3; jj++) {
            float4 o;
            o.x = acc[i][jj * 4 + 0]; o.y = acc[i][jj * 4 + 1];
            o.z = acc[i][jj * 4 + 2]; o.w = acc[i][jj * 4 + 3];
            *(float4*)(dst + row * T3 + ct * 12 + jj * 4) = o;
        }
    }
}

// ---- K1b: 16 rows/block: sum partials + LN + GELU + 2 ODE steps -> qh/ql/q2 ----
__global__ __launch_bounds__(256) void k1b_ode(const float* __restrict__ hpart,
        const float* __restrict__ bp,
        const float* __restrict__ g1, const float* __restrict__ b1ln,
        const float* __restrict__ W1, const float* __restrict__ bb1,
        const float* __restrict__ W2, const float* __restrict__ bb2,
        unsigned short* __restrict__ qh, unsigned short* __restrict__ ql,
        float* __restrict__ q2out) {
    __shared__ __align__(16) float W1s[T3 * HID];
    __shared__ __align__(16) float W2s[HID * T3];
    __shared__ __align__(16) float hs[16 * T3];
    __shared__ __align__(16) float t1s[16 * 132];
    int tid = threadIdx.x;
    size_t base = (size_t)blockIdx.x * 16 * T3;
    for (int i = tid; i < 1536; i += 256) {
        *(float4*)&W1s[i * 4] = *(const float4*)&W1[i * 4];
        *(float4*)&W2s[i * 4] = *(const float4*)&W2[i * 4];
    }
    for (int idx = tid; idx < 16 * T3; idx += 256) {
        int c = idx % T3;
        float a = bp[c];
        #pragma unroll
        for (int s = 0; s < SPLITK; s++) a += hpart[(size_t)s * NQ * T3 + base + idx];
        t1s[idx] = a;
    }
    __syncthreads();
    {
        int r = tid >> 4, c16 = tid & 15;
        float v[3];
        float ssum = 0.f;
        #pragma unroll
        for (int i = 0; i < 3; i++) { v[i] = t1s[r * T3 + c16 * 3 + i]; ssum += v[i]; }
        #pragma unroll
        for (int off = 1; off < 16; off <<= 1) ssum += __shfl_xor(ssum, off);
        float mean = ssum * (1.f / T3);
        float vv = 0.f;
        #pragma unroll
        for (int i = 0; i < 3; i++) { v[i] -= mean; vv += v[i] * v[i]; }
        #pragma unroll
        for (int off = 1; off < 16; off <<= 1) vv += __shfl_xor(vv, off);
        float rstd = rsqrtf(vv * (1.f / T3) + 1e-5f);
        #pragma unroll
        for (int i = 0; i < 3; i++) {
            int c = c16 * 3 + i;
            hs[r * T3 + c] = gelu_exact(v[i] * rstd * g1[c] + b1ln[c]);
        }
    }
    __syncthreads();
    for (int step = 0; step < 2; step++) {
        #pragma unroll
        for (int it = 0; it < 2; it++) {
            int idx = tid + it * 256;
            int rr = idx >> 5, j4 = idx & 31;
            float4 a = *(const float4*)&bb1[j4 * 4];
            #pragma unroll 3
            for (int d4 = 0; d4 < 12; d4++) {
                float4 qv = *(const float4*)&hs[rr * T3 + d4 * 4];
                float qa[4] = {qv.x, qv.y, qv.z, qv.w};
                #pragma unroll
                for (int dd = 0; dd < 4; dd++) {
                    float4 wv = *(const float4*)&W1s[(d4 * 4 + dd) * HID + j4 * 4];
                    a.x += qa[dd] * wv.x; a.y += qa[dd] * wv.y;
                    a.z += qa[dd] * wv.z; a.w += qa[dd] * wv.w;
                }
            }
            a.x = tanhf(a.x); a.y = tanhf(a.y); a.z = tanhf(a.z); a.w = tanhf(a.w);
            *(float4*)&t1s[rr * 132 + j4 * 4] = a;
        }
        __syncthreads();
        if (tid < 192) {
            int rr = tid / 12, c4 = tid % 12;
            float4 a = *(const float4*)&bb2[c4 * 4];
            #pragma unroll 4
            for (int j4 = 0; j4 < 32; j4++) {
                float4 tv = *(const float4*)&t1s[rr * 132 + j4 * 4];
                float ta[4] = {tv.x, tv.y, tv.z, tv.w};
                #pragma unroll
                for (int jj = 0; jj < 4; jj++) {
                    float4 wv = *(const float4*)&W2s[(j4 * 4 + jj) * T3 + c4 * 4];
                    a.x += ta[jj] * wv.x; a.y += ta[jj] * wv.y;
                    a.z += ta[jj] * wv.z; a.w += ta[jj] * wv.w;
                }
            }
            float4 cur = *(const float4*)&hs[rr * T3 + c4 * 4];
            cur.x += 0.5f * a.x; cur.y += 0.5f * a.y;
            cur.z += 0.5f * a.z; cur.w += 0.5f * a.w;
            *(float4*)&hs[rr * T3 + c4 * 4] = cur;
        }
        __syncthreads();
    }
    // q2 per row
    {
        int r = tid >> 4, c16 = tid & 15;
        float sq = 0.f;
        #pragma unroll
        for (int i = 0; i < 3; i++) { float v = hs[r * T3 + c16 * 3 + i]; sq += v * v; }
        #pragma unroll
        for (int off = 1; off < 16; off <<= 1) sq += __shfl_xor(sq, off);
        if (c16 == 0) q2out[(size_t)blockIdx.x * 16 + r] = sq;
    }
    // qh/ql (K padded to 64)
    for (int idx = tid; idx < 16 * 64; idx += 256) {
        int r = idx >> 6, c = idx & 63;
        unsigned short hi = 0, lo = 0;
        if (c < T3) {
            float xv = hs[r * T3 + c];
            hi = bf16_rne(xv);
            lo = bf16_rne(xv - __uint_as_float((unsigned)hi << 16));
        }
        size_t o = ((size_t)blockIdx.x * 16 + r) * 64 + c;
        qh[o] = hi; ql[o] = lo;
    }
}

// ---- K2a: dist = max(q2+m2-2*q.m,0)*cw via exact bf16x3 MFMA ----
// block: 64 q-rows x 256 m-cols; wave: 64 m x 64 q; A=pe(m), B=q -> lane stores float4 over m
#define PES 72
__global__ __launch_bounds__(256) void k2a_mfma(
        const unsigned short* __restrict__ qh, const unsigned short* __restrict__ ql,
        const float* __restrict__ q2g,
        const unsigned short* __restrict__ ph, const unsigned short* __restrict__ pl,
        const float* __restrict__ m2, const float* __restrict__ cw,
        float* __restrict__ dist, int rowbase) {
    __shared__ __align__(16) unsigned short pesh[256 * PES];   // 36.9KB
    __shared__ __align__(16) unsigned short pesl[256 * PES];   // 36.9KB
    __shared__ float q2s[64];
    int tid = threadIdx.x, lane = tid & 63, wv = tid >> 6;
    int c0 = blockIdx.x * 256;
    int r0 = blockIdx.y * 64;
    int grow0 = rowbase + r0;
    for (int idx = tid; idx < 2048; idx += 256) {
        int col = idx >> 3, ch = idx & 7;
        *(uint4*)&pesh[col * PES + ch * 8] = *(const uint4*)&ph[(size_t)(c0 + col) * 64 + ch * 8];
        *(uint4*)&pesl[col * PES + ch * 8] = *(const uint4*)&pl[(size_t)(c0 + col) * 64 + ch * 8];
    }
    if (tid < 64) q2s[tid] = q2g[grow0 + tid];
    int lm = lane & 15, lk8 = (lane >> 4) * 8;
    short8 bqh[4][2], bql[4][2];
    #pragma unroll
    for (int qs = 0; qs < 4; qs++)
        #pragma unroll
        for (int ks = 0; ks < 2; ks++) {
            size_t o = (size_t)(grow0 + qs * 16 + lm) * 64 + ks * 32 + lk8;
            bqh[qs][ks] = *(const short8*)&qh[o];
            bql[qs][ks] = *(const short8*)&ql[o];
        }
    __syncthreads();
    f32x4 acc[4][4];
    #pragma unroll
    for (int i = 0; i < 4; i++)
        #pragma unroll
        for (int j = 0; j < 4; j++) acc[i][j] = (f32x4)(0.f);
    int mco = wv * 64;
    #pragma unroll
    for (int ms = 0; ms < 4; ms++) {
        int arow = mco + ms * 16 + lm;
        short8 ah0 = *(const short8*)&pesh[arow * PES + lk8];
        short8 ah1 = *(const short8*)&pesh[arow * PES + 32 + lk8];
        short8 al0 = *(const short8*)&pesl[arow * PES + lk8];
        short8 al1 = *(const short8*)&pesl[arow * PES + 32 + lk8];
        #pragma unroll
        for (int qs = 0; qs < 4; qs++) {
            f32x4 a = acc[ms][qs];
            a = __builtin_amdgcn_mfma_f32_16x16x32_bf16(ah0, bqh[qs][0], a, 0, 0, 0);
            a = __builtin_amdgcn_mfma_f32_16x16x32_bf16(ah1, bqh[qs][1], a, 0, 0, 0);
            a = __builtin_amdgcn_mfma_f32_16x16x32_bf16(ah0, bql[qs][0], a, 0, 0, 0);
            a = __builtin_amdgcn_mfma_f32_16x16x32_bf16(ah1, bql[qs][1], a, 0, 0, 0);
            a = __builtin_amdgcn_mfma_f32_16x16x32_bf16(al0, bqh[qs][0], a, 0, 0, 0);
            a = __builtin_amdgcn_mfma_f32_16x16x32_bf16(al1, bqh[qs][1], a, 0, 0, 0);
            acc[ms][qs] = a;
        }
    }
    int mr4 = (lane >> 4) * 4;
    #pragma unroll
    for (int ms = 0; ms < 4; ms++) {
        int gm = c0 + mco + ms * 16 + mr4;
        float4 m2v = *(const float4*)&m2[gm];
        float4 cwv = *(const float4*)&cw[gm];
        #pragma unroll
        for (int qs = 0; qs < 4; qs++) {
            int lr = r0 + qs * 16 + lm;
            float q2 = q2s[qs * 16 + lm];
            f32x4 a = acc[ms][qs];
            float4 o;
            o.x = fmaxf(q2 + m2v.x - 2.f * a[0], 0.f) * cwv.x;
            o.y = fmaxf(q2 + m2v.y - 2.f * a[1], 0.f) * cwv.y;
            o.z = fmaxf(q2 + m2v.z - 2.f * a[2], 0.f) * cwv.z;
            o.w = fmaxf(q2 + m2v.w - 2.f * a[3], 0.f) * cwv.w;
            *(float4*)&dist[(size_t)lr * MSLOT + gm] = o;
        }
    }
}

// ---- K2b: radix-select top-48 (exact, deterministic) ----
#define NBIN 4096
#define MAXCAND 1024
__global__ __launch_bounds__(256) void k2b_topk(const float* __restrict__ dist,
        float* __restrict__ topv, int* __restrict__ topi,
        float* __restrict__ rowmin, int rowbase) {
    __shared__ unsigned int hist[NBIN];
    __shared__ unsigned long long cand[MAXCAND];
    __shared__ unsigned int wsum[4];
    __shared__ unsigned int s_b1, s_c0, s_b2, s_ncand;
    int tid = threadIdx.x;
    int lane = tid & 63, wv = tid >> 6;
    int rl = blockIdx.x;
    size_t row = (size_t)(rowbase + rl);
    const uint4* src = (const uint4*)(dist + (size_t)rl * MSLOT);
    uint4 k4[8];
    #pragma unroll
    for (int j = 0; j < 8; j++) k4[j] = src[tid + 256 * j];
    for (int i = tid; i < NBIN; i += 256) hist[i] = 0;
    if (tid == 0) s_ncand = 0;
    __syncthreads();
    #pragma unroll
    for (int j = 0; j < 8; j++) {
        atomicAdd(&hist[k4[j].x >> 19], 1u);
        atomicAdd(&hist[k4[j].y >> 19], 1u);
        atomicAdd(&hist[k4[j].z >> 19], 1u);
        atomicAdd(&hist[k4[j].w >> 19], 1u);
    }
    __syncthreads();
    {
        unsigned hb[16];
        unsigned s = 0;
        #pragma unroll
        for (int i = 0; i < 16; i++) { hb[i] = hist[tid * 16 + i]; s += hb[i]; }
        unsigned v = s;
        #pragma unroll
        for (int off = 1; off < 64; off <<= 1) {
            unsigned o = __shfl_up(v, off);
            if (lane >= off) v += o;
        }
        if (lane == 63) wsum[wv] = v;
        __syncthreads();
        unsigned wbase = 0;
        for (int w = 0; w < wv; w++) wbase += wsum[w];
        unsigned excl = wbase + v - s;
        if (excl < KBIG && KBIG <= excl + s) {
            unsigned c = excl;
            #pragma unroll
            for (int i = 0; i < 16; i++) {
                if (c < KBIG && KBIG <= c + hb[i]) { s_b1 = tid * 16 + i; s_c0 = c; break; }
                c += hb[i];
            }
        }
        __syncthreads();
    }
    unsigned b1 = s_b1, c0 = s_c0;
    unsigned t2 = KBIG - c0;
    __syncthreads();
    for (int i = tid; i < NBIN; i += 256) hist[i] = 0;
    __syncthreads();
    #pragma unroll
    for (int j = 0; j < 8; j++) {
        if ((k4[j].x >> 19) == b1) atomicAdd(&hist[(k4[j].x >> 7) & 0xFFF], 1u);
        if ((k4[j].y >> 19) == b1) atomicAdd(&hist[(k4[j].y >> 7) & 0xFFF], 1u);
        if ((k4[j].z >> 19) == b1) atomicAdd(&hist[(k4[j].z >> 7) & 0xFFF], 1u);
        if ((k4[j].w >> 19) == b1) atomicAdd(&hist[(k4[j].w >> 7) & 0xFFF], 1u);
    }
    __syncthreads();
    {
        unsigned hb[16];
        unsigned s = 0;
        #pragma unroll
        for (int i = 0; i < 16; i++) { hb[i] = hist[tid * 16 + i]; s += hb[i]; }
        unsigned v = s;
        #pragma unroll
        for (int off = 1; off < 64; off <<= 1) {
            unsigned o = __shfl_up(v, off);
            if (lane >= off) v += o;
        }
        if (lane == 63) wsum[wv] = v;
        __syncthreads();
        unsigned wbase = 0;
        for (int w = 0; w < wv; w++) wbase += wsum[w];
        unsigned excl = wbase + v - s;
        if (excl < t2 && t2 <= excl + s) {
            unsigned c = excl;
            #pragma unroll
            for (int i = 0; i < 16; i++) {
                if (c < t2 && t2 <= c + hb[i]) { s_b2 = tid * 16 + i; break; }
                c += hb[i];
            }
        }
        __syncthreads();
    }
    unsigned b2 = s_b2;
    #pragma unroll
    for (int j = 0; j < 8; j++) {
        int mb = (tid + 256 * j) * 4;
        unsigned kk[4] = {k4[j].x, k4[j].y, k4[j].z, k4[j].w};
        #pragma unroll
        for (int c = 0; c < 4; c++) {
            unsigned key = kk[c];
            unsigned hb_ = key >> 19;
            if (hb_ < b1 || (hb_ == b1 && ((key >> 7) & 0xFFFu) <= b2)) {
                unsigned n = atomicAdd(&s_ncand, 1u);
                if (n < MAXCAND)
                    cand[n] = ((unsigned long long)key << 32) | (unsigned)(mb + c);
            }
        }
    }
    __syncthreads();
    int nc = (int)(s_ncand < MAXCAND ? s_ncand : MAXCAND);
    for (int i = tid; i < nc; i += 256) {
        unsigned long long me = cand[i];
        int rank = 0;
        for (int j = 0; j < nc; j++) rank += (cand[j] < me) ? 1 : 0;
        if (rank < KBIG) {
            float v = __uint_as_float((unsigned)(me >> 32));
            topv[row * KBIG + rank] = v;
            topi[row * KBIG + rank] = (int)(me & 0xFFFFFFFFu);
            if (rank == 0) rowmin[row] = v;
        }
    }
}

// ---- K3a: fire flag ----
__global__ __launch_bounds__(256) void k3a_flag(const float* __restrict__ rowmin,
        int* __restrict__ flag) {
    __shared__ float red[256];
    int tid = threadIdx.x;
    float s = 0.f;
    for (int j = 0; j < NQ / 256; j++) s += rowmin[tid + 256 * j];
    red[tid] = s;
    __syncthreads();
    for (int st = 128; st; st >>= 1) {
        if (tid < st) red[tid] += red[tid + st];
        __syncthreads();
    }
    if (tid == 0) {
        float top1 = red[0] / (float)NQ;
        flag[0] = (top1 < 0.7f) ? 1 : 0;
    }
}

// ---- K3: wave per row; float4 gathers; writes att as bf16 ----
__global__ __launch_bounds__(256) void k3_attend(const float* __restrict__ topv,
        const int* __restrict__ topi, const int* __restrict__ flag,
        const float* __restrict__ slots, unsigned short* __restrict__ attb) {
    int tid = threadIdx.x;
    int lane = tid & 63, wv = tid >> 6;
    size_t row = (size_t)blockIdx.x * 4 + wv;
    int kc = flag[0] ? KBIG : KBASE;
    float v0 = topv[row * KBIG];
    float ev = 0.f;
    int mi = 0;
    if (lane < KBIG) {
        float v = topv[row * KBIG + lane];
        ev = (lane < kc) ? expf(-(v - v0)) : 0.f;
        mi = topi[row * KBIG + lane];
    }
    float ssum = ev;
    #pragma unroll
    for (int off = 32; off; off >>= 1) ssum += __shfl_xor(ssum, off);
    float inv = 1.f / ssum;
    float4 acc = make_float4(0.f, 0.f, 0.f, 0.f);
    for (int k = 0; k < kc; k++) {
        float wk = __shfl(ev, k) * inv;
        int m = __shfl(mi, k);
        float4 v = *(const float4*)(slots + (size_t)m * HD + lane * 4);
        acc.x += wk * v.x; acc.y += wk * v.y;
        acc.z += wk * v.z; acc.w += wk * v.w;
    }
    ushort4 o;
    o.x = bf16_rne(acc.x); o.y = bf16_rne(acc.y);
    o.z = bf16_rne(acc.z); o.w = bf16_rne(acc.w);
    *(ushort4*)(attb + row * HD + lane * 4) = o;
}

// ---- K4: out = att(bf16) @ Wo_t(bf16)^T + bo via MFMA ----
__global__ __launch_bounds__(256) void k4_mfma(const unsigned short* __restrict__ A,
        const unsigned short* __restrict__ Bt, const float* __restrict__ bo,
        float* __restrict__ out) {
    int tid = threadIdx.x;
    int lane = tid & 63, wave = tid >> 6;
    int wm = wave >> 1, wn = wave & 1;
    int mbase = blockIdx.y * 128 + wm * 64;
    int nbase = blockIdx.x * 128 + wn * 64;
    int lm = lane & 15;
    int lk8 = (lane >> 4) * 8;
    f32x4 acc[4][4];
    #pragma unroll
    for (int i = 0; i < 4; i++)
        #pragma unroll
        for (int j = 0; j < 4; j++) acc[i][j] = (f32x4)(0.f);
    #pragma unroll 2
    for (int ks = 0; ks < 8; ks++) {
        int kofs = ks * 32 + lk8;
        short8 a[4], b[4];
        #pragma unroll
        for (int i = 0; i < 4; i++)
            a[i] = *(const short8*)(A + (size_t)(mbase + i * 16 + lm) * HD + kofs);
        #pragma unroll
        for (int j = 0; j < 4; j++)
            b[j] = *(const short8*)(Bt + (size_t)(nbase + j * 16 + lm) * HD + kofs);
        #pragma unroll
        for (int i = 0; i < 4; i++)
            #pragma unroll
            for (int j = 0; j < 4; j++)
                acc[i][j] = __builtin_amdgcn_mfma_f32_16x16x32_bf16(a[i], b[j], acc[i][j], 0, 0, 0);
    }
    int orow = (lane >> 4) * 4;
    #pragma unroll
    for (int i = 0; i < 4; i++)
        #pragma unroll
        for (int j = 0; j < 4; j++) {
            int col = nbase + j * 16 + lm;
            float bias = bo[col];
            #pragma unroll
            for (int r = 0; r < 4; r++) {
                int row = mbase + i * 16 + orow + r;
                out[(size_t)row * INDIM + col] = acc[i][j][r] + bias;
            }
        }
}

// ---- K5: LN + GELU in place ----
__global__ __launch_bounds__(256) void k5_ln(float* __restrict__ out,
        const float* __restrict__ g, const float* __restrict__ b) {
    __shared__ float red[4];
    int tid = threadIdx.x;
    size_t row = blockIdx.x;
    float4 v = *(const float4*)(out + row * INDIM + tid * 4);
    float s = v.x + v.y + v.z + v.w;
    #pragma unroll
    for (int off = 32; off; off >>= 1) s += __shfl_xor(s, off);
    int wid = tid >> 6, lane = tid & 63;
    if (!lane) red[wid] = s;
    __syncthreads();
    float mean = (red[0] + red[1] + red[2] + red[3]) * (1.f / (float)INDIM);
    __syncthreads();
    float dx = v.x - mean, dy = v.y - mean, dz = v.z - mean, dw = v.w - mean;
    float ss = dx * dx + dy * dy + dz * dz + dw * dw;
    #pragma unroll
    for (int off = 32; off; off >>= 1) ss += __shfl_xor(ss, off);
    if (!lane) red[wid] = ss;
    __syncthreads();
    float var = (red[0] + red[1] + red[2] + red[3]) * (1.f / (float)INDIM);
    float rs = rsqrtf(var + 1e-5f);
    int c = tid * 4;
    float4 o;
    o.x = gelu_exact(dx * rs * g[c + 0] + b[c + 0]);
    o.y = gelu_exact(dy * rs * g[c + 1] + b[c + 1]);
    o.z = gelu_exact(dz * rs * g[c + 2] + b[c + 2]);
    o.w = gelu_exact(dw * rs * g[c + 3] + b[c + 3]);
    *(float4*)(out + row * INDIM + c) = o;
}

extern "C" void kernel_launch(void* const* d_in, const int* in_sizes, int n_in,
                              void* d_out, int out_size, void* d_ws, size_t ws_size,
                              hipStream_t stream) {
    const float* x     = (const float*)d_in[0];
    const float* Wp    = (const float*)d_in[1];
    const float* bp    = (const float*)d_in[2];
    const float* ln1g  = (const float*)d_in[3];
    const float* ln1b  = (const float*)d_in[4];
    const float* oW1   = (const float*)d_in[5];
    const float* ob1   = (const float*)d_in[6];
    const float* oW2   = (const float*)d_in[7];
    const float* ob2   = (const float*)d_in[8];
    const float* slots = (const float*)d_in[9];
    const float* pe    = (const float*)d_in[10];
    const float* curv  = (const float*)d_in[11];
    const float* alpha = (const float*)d_in[12];
    const float* Wo    = (const float*)d_in[13];
    const float* bo    = (const float*)d_in[14];
    const float* ln2g  = (const float*)d_in[15];
    const float* ln2b  = (const float*)d_in[16];
    float* out = (float*)d_out;
    char* ws = (char*)d_ws;

    unsigned short* qhp = (unsigned short*)(ws + OFF_QH);
    unsigned short* qlp = (unsigned short*)(ws + OFF_QL);
    float* q2p    = (float*)(ws + OFF_Q2);
    float* m2     = (float*)(ws + OFF_M2);
    float* cwv    = (float*)(ws + OFF_CW);
    float* topv   = (float*)(ws + OFF_TOPV);
    int*   topi   = (int*)  (ws + OFF_TOPI);
    float* rowmin = (float*)(ws + OFF_RMIN);
    int*   flag   = (int*)  (ws + OFF_FLAG);
    unsigned short* attb = (unsigned short*)(ws + OFF_ATTB);
    unsigned short* wot  = (unsigned short*)(ws + OFF_WOT);
    unsigned short* peh  = (unsigned short*)(ws + OFF_PEH);
    unsigned short* pel  = (unsigned short*)(ws + OFF_PEL);
    float* hpart  = (float*)(ws + OFF_HPART);
    float* dist   = (float*)(ws + OFF_DIST);   // aliases hpart (dead after k1b)

    k0_prep<<<MSLOT / 256, 256, 0, stream>>>(pe, curv, alpha, m2, cwv, peh, pel);
    k0b_cvt<<<dim3(4, 16), 256, 0, stream>>>(Wo, wot);
    k1_proj<<<dim3(SPLITK, NQ / 64), 64, 0, stream>>>(x, Wp, hpart);
    k1b_ode<<<NQ / 16, 256, 0, stream>>>(hpart, bp, ln1g, ln1b, oW1, ob1, oW2, ob2,
                                         qhp, qlp, q2p);
    for (int ch = 0; ch < NQ / CHUNK; ch++) {
        k2a_mfma<<<dim3(MSLOT / 256, CHUNK / 64), 256, 0, stream>>>(
            qhp, qlp, q2p, peh, pel, m2, cwv, dist, ch * CHUNK);
        k2b_topk<<<CHUNK, 256, 0, stream>>>(dist, topv, topi, rowmin, ch * CHUNK);
    }
    k3a_flag<<<1, 256, 0, stream>>>(rowmin, flag);
    k3_attend<<<NQ / 4, 256, 0, stream>>>(topv, topi, flag, slots, attb);
    k4_mfma<<<dim3(INDIM / 128, NQ / 128), 256, 0, stream>>>(attb, wot, bo, out);
    k5_ln<<<NQ, 256, 0, stream>>>(out, ln2g, ln2b);
}

// Round 7
// 396.679 us; speedup vs baseline: 2.4539x; 1.0543x over previous
//
#include <hip/hip_runtime.h>
#include <math.h>

#define NQ    8192   // B*S
#define T3    48
#define INDIM 1024
#define HID   128
#define MSLOT 8192
#define HD    256
#define KBIG  48
#define KBASE 32
#define CHUNK 1024

// ---- workspace layout (bytes) ----
#define OFF_QH    ((size_t)0)           // 8192*64 bf16 = 1,048,576
#define OFF_QL    ((size_t)1048576)
#define OFF_Q2    ((size_t)2097152)     // 8192 f32
#define OFF_M2    ((size_t)2129920)
#define OFF_CW    ((size_t)2162688)
#define OFF_TOPV  ((size_t)2195456)     // 8192*48 f32
#define OFF_TOPI  ((size_t)3768320)
#define OFF_RMIN  ((size_t)5341184)
#define OFF_FLAG  ((size_t)5373952)
#define OFF_WOT   ((size_t)5374208)     // 1024*256 bf16 = 524,288
#define OFF_PEH   ((size_t)5898496)     // 8192*64 bf16
#define OFF_PEL   ((size_t)6947072)
#define OFF_WPTH  ((size_t)7995648)     // 48*1024 bf16 = 98,304
#define OFF_WPTL  ((size_t)8093952)
#define OFF_H0    ((size_t)8192256)     // 8192*48 f32 = 1,572,864
#define OFF_BIG   ((size_t)9765120)     // 33,554,432 region, time-shared:
//   xh = BIG, xl = BIG+16,777,216   (k0c writes, k1_mfma reads, then dead)
//   dist = BIG                      (k2a writes, k2b reads, then dead)
//   attb = BIG                      (k3 writes, k4 reads)
// end = 43,319,552 (< proven 45.7MB footprint)

typedef __attribute__((ext_vector_type(8))) short short8;
typedef __attribute__((ext_vector_type(4))) float f32x4;

__device__ __forceinline__ float gelu_exact(float x) {
    return 0.5f * x * (1.0f + erff(x * 0.70710678118654752f));
}

__device__ __forceinline__ unsigned short bf16_rne(float f) {
    unsigned int x = __float_as_uint(f);
    unsigned int r = (x + 0x7fffu + ((x >> 16) & 1u)) >> 16;
    return (unsigned short)r;
}

__device__ __forceinline__ void split2(float x, unsigned short& h, unsigned short& l) {
    h = bf16_rne(x);
    l = bf16_rne(x - __uint_as_float((unsigned)h << 16));
}

// ---- K0: m2, cw, pe hi/lo bf16 (K padded to 64) ----
__global__ __launch_bounds__(256) void k0_prep(const float* __restrict__ pe,
        const float* __restrict__ curv, const float* __restrict__ alpha,
        float* __restrict__ m2, float* __restrict__ cw,
        unsigned short* __restrict__ ph, unsigned short* __restrict__ pl) {
    int m = blockIdx.x * 256 + threadIdx.x;
    float s = 0.f;
    for (int d = 0; d < T3; d++) { float v = pe[(size_t)m * T3 + d]; s += v * v; }
    m2[m] = s;
    float c = 0.f;
    for (int d = 0; d < 16; d++) { float v = curv[m * 16 + d]; c += v * v; }
    cw[m] = expf(-alpha[0] * sqrtf(c));
    int base = blockIdx.x * 256;
    for (int idx = threadIdx.x; idx < 256 * 64; idx += 256) {
        int r = idx >> 6, cc = idx & 63;
        unsigned short hi = 0, lo = 0;
        if (cc < T3) split2(pe[(size_t)(base + r) * T3 + cc], hi, lo);
        size_t o = (size_t)(base + r) * 64 + cc;
        ph[o] = hi; pl[o] = lo;
    }
}

// ---- K0b: Wo_t[n][k] = bf16(Wo[k][n]) ----
__global__ __launch_bounds__(256) void k0b_cvt(const float* __restrict__ Wo,
        unsigned short* __restrict__ Wot) {
    __shared__ float t[64][65];
    int k0 = blockIdx.x * 64;
    int n0 = blockIdx.y * 64;
    int c = threadIdx.x & 63, r4 = threadIdx.x >> 6;
    #pragma unroll
    for (int i = 0; i < 16; i++) {
        int kr = i * 4 + r4;
        t[kr][c] = Wo[(size_t)(k0 + kr) * INDIM + n0 + c];
    }
    __syncthreads();
    #pragma unroll
    for (int i = 0; i < 16; i++) {
        int nr = i * 4 + r4;
        Wot[(size_t)(n0 + nr) * HD + k0 + c] = bf16_rne(t[c][nr]);
    }
}

// ---- K0c: split x into bf16 hi/lo ----
__global__ __launch_bounds__(256) void k0c_xsplit(const float* __restrict__ x,
        unsigned short* __restrict__ xh, unsigned short* __restrict__ xl) {
    size_t base = ((size_t)blockIdx.x * 256 + threadIdx.x) * 8;
    float4 a = *(const float4*)(x + base);
    float4 b = *(const float4*)(x + base + 4);
    unsigned short h[8], l[8];
    split2(a.x, h[0], l[0]); split2(a.y, h[1], l[1]);
    split2(a.z, h[2], l[2]); split2(a.w, h[3], l[3]);
    split2(b.x, h[4], l[4]); split2(b.y, h[5], l[5]);
    split2(b.z, h[6], l[6]); split2(b.w, h[7], l[7]);
    uint4 hv, lv;
    hv.x = h[0] | ((unsigned)h[1] << 16); hv.y = h[2] | ((unsigned)h[3] << 16);
    hv.z = h[4] | ((unsigned)h[5] << 16); hv.w = h[6] | ((unsigned)h[7] << 16);
    lv.x = l[0] | ((unsigned)l[1] << 16); lv.y = l[2] | ((unsigned)l[3] << 16);
    lv.z = l[4] | ((unsigned)l[5] << 16); lv.w = l[6] | ((unsigned)l[7] << 16);
    *(uint4*)(xh + base) = hv;
    *(uint4*)(xl + base) = lv;
}

// ---- K0d: WpT hi/lo: wpt[n][k] = Wp[k][n] ----
__global__ __launch_bounds__(256) void k0d_wpt(const float* __restrict__ Wp,
        unsigned short* __restrict__ wph, unsigned short* __restrict__ wpl) {
    int n = blockIdx.x;
    for (int k = threadIdx.x; k < INDIM; k += 256) {
        unsigned short h, l;
        split2(Wp[(size_t)k * T3 + n], h, l);
        wph[(size_t)n * INDIM + k] = h;
        wpl[(size_t)n * INDIM + k] = l;
    }
}

// ---- K1: h0 = x @ Wp via hi/lo bf16 MFMA (exact to ~1e-5) ----
// 256 blocks x 256 thr; block = 32 rows x 48 cols; wave = K-quarter (256)
__global__ __launch_bounds__(256) void k1_mfma(const unsigned short* __restrict__ xh,
        const unsigned short* __restrict__ xl,
        const unsigned short* __restrict__ wph, const unsigned short* __restrict__ wpl,
        float* __restrict__ h0) {
    __shared__ float part[4][32][48];
    int tid = threadIdx.x, lane = tid & 63, wv = tid >> 6;
    int r0 = blockIdx.x * 32;
    int lm = lane & 15, lk8 = (lane >> 4) * 8;
    f32x4 acc[2][3];
    #pragma unroll
    for (int i = 0; i < 2; i++)
        #pragma unroll
        for (int j = 0; j < 3; j++) acc[i][j] = (f32x4)(0.f);
    int kw = wv * 256;
    #pragma unroll 2
    for (int ks = 0; ks < 8; ks++) {
        int kofs = kw + ks * 32 + lk8;
        short8 ah[2], al[2], bh[3], bl[3];
        #pragma unroll
        for (int i = 0; i < 2; i++) {
            size_t ao = (size_t)(r0 + i * 16 + lm) * INDIM + kofs;
            ah[i] = *(const short8*)(xh + ao);
            al[i] = *(const short8*)(xl + ao);
        }
        #pragma unroll
        for (int j = 0; j < 3; j++) {
            size_t bo = (size_t)(j * 16 + lm) * INDIM + kofs;
            bh[j] = *(const short8*)(wph + bo);
            bl[j] = *(const short8*)(wpl + bo);
        }
        #pragma unroll
        for (int i = 0; i < 2; i++)
            #pragma unroll
            for (int j = 0; j < 3; j++) {
                f32x4 a = acc[i][j];
                a = __builtin_amdgcn_mfma_f32_16x16x32_bf16(ah[i], bh[j], a, 0, 0, 0);
                a = __builtin_amdgcn_mfma_f32_16x16x32_bf16(ah[i], bl[j], a, 0, 0, 0);
                a = __builtin_amdgcn_mfma_f32_16x16x32_bf16(al[i], bh[j], a, 0, 0, 0);
                acc[i][j] = a;
            }
    }
    int orow = (lane >> 4) * 4;
    #pragma unroll
    for (int i = 0; i < 2; i++)
        #pragma unroll
        for (int j = 0; j < 3; j++)
            #pragma unroll
            for (int r = 0; r < 4; r++)
                part[wv][i * 16 + orow + r][j * 16 + lm] = acc[i][j][r];
    __syncthreads();
    for (int idx = tid; idx < 32 * 48; idx += 256) {
        int rr = idx / 48, cc = idx - rr * 48;
        float s = part[0][rr][cc] + part[1][rr][cc] + part[2][rr][cc] + part[3][rr][cc];
        h0[(size_t)(r0 + rr) * T3 + cc] = s;
    }
}

// ---- K1b: 16 rows/block: bias + LN + GELU + 2 ODE steps -> qh/ql/q2 ----
__global__ __launch_bounds__(256) void k1b_ode(const float* __restrict__ h0,
        const float* __restrict__ bp,
        const float* __restrict__ g1, const float* __restrict__ b1ln,
        const float* __restrict__ W1, const float* __restrict__ bb1,
        const float* __restrict__ W2, const float* __restrict__ bb2,
        unsigned short* __restrict__ qh, unsigned short* __restrict__ ql,
        float* __restrict__ q2out) {
    __shared__ __align__(16) float W1s[T3 * HID];
    __shared__ __align__(16) float W2s[HID * T3];
    __shared__ __align__(16) float hs[16 * T3];
    __shared__ __align__(16) float t1s[16 * 132];
    int tid = threadIdx.x;
    size_t base = (size_t)blockIdx.x * 16 * T3;
    for (int i = tid; i < 1536; i += 256) {
        *(float4*)&W1s[i * 4] = *(const float4*)&W1[i * 4];
        *(float4*)&W2s[i * 4] = *(const float4*)&W2[i * 4];
    }
    for (int idx = tid; idx < 16 * T3; idx += 256) {
        int c = idx % T3;
        t1s[idx] = bp[c] + h0[base + idx];
    }
    __syncthreads();
    {
        int r = tid >> 4, c16 = tid & 15;
        float v[3];
        float ssum = 0.f;
        #pragma unroll
        for (int i = 0; i < 3; i++) { v[i] = t1s[r * T3 + c16 * 3 + i]; ssum += v[i]; }
        #pragma unroll
        for (int off = 1; off < 16; off <<= 1) ssum += __shfl_xor(ssum, off);
        float mean = ssum * (1.f / T3);
        float vv = 0.f;
        #pragma unroll
        for (int i = 0; i < 3; i++) { v[i] -= mean; vv += v[i] * v[i]; }
        #pragma unroll
        for (int off = 1; off < 16; off <<= 1) vv += __shfl_xor(vv, off);
        float rstd = rsqrtf(vv * (1.f / T3) + 1e-5f);
        #pragma unroll
        for (int i = 0; i < 3; i++) {
            int c = c16 * 3 + i;
            hs[r * T3 + c] = gelu_exact(v[i] * rstd * g1[c] + b1ln[c]);
        }
    }
    __syncthreads();
    for (int step = 0; step < 2; step++) {
        #pragma unroll
        for (int it = 0; it < 2; it++) {
            int idx = tid + it * 256;
            int rr = idx >> 5, j4 = idx & 31;
            float4 a = *(const float4*)&bb1[j4 * 4];
            #pragma unroll 3
            for (int d4 = 0; d4 < 12; d4++) {
                float4 qv = *(const float4*)&hs[rr * T3 + d4 * 4];
                float qa[4] = {qv.x, qv.y, qv.z, qv.w};
                #pragma unroll
                for (int dd = 0; dd < 4; dd++) {
                    float4 wv = *(const float4*)&W1s[(d4 * 4 + dd) * HID + j4 * 4];
                    a.x += qa[dd] * wv.x; a.y += qa[dd] * wv.y;
                    a.z += qa[dd] * wv.z; a.w += qa[dd] * wv.w;
                }
            }
            a.x = tanhf(a.x); a.y = tanhf(a.y); a.z = tanhf(a.z); a.w = tanhf(a.w);
            *(float4*)&t1s[rr * 132 + j4 * 4] = a;
        }
        __syncthreads();
        if (tid < 192) {
            int rr = tid / 12, c4 = tid % 12;
            float4 a = *(const float4*)&bb2[c4 * 4];
            #pragma unroll 4
            for (int j4 = 0; j4 < 32; j4++) {
                float4 tv = *(const float4*)&t1s[rr * 132 + j4 * 4];
                float ta[4] = {tv.x, tv.y, tv.z, tv.w};
                #pragma unroll
                for (int jj = 0; jj < 4; jj++) {
                    float4 wv = *(const float4*)&W2s[(j4 * 4 + jj) * T3 + c4 * 4];
                    a.x += ta[jj] * wv.x; a.y += ta[jj] * wv.y;
                    a.z += ta[jj] * wv.z; a.w += ta[jj] * wv.w;
                }
            }
            float4 cur = *(const float4*)&hs[rr * T3 + c4 * 4];
            cur.x += 0.5f * a.x; cur.y += 0.5f * a.y;
            cur.z += 0.5f * a.z; cur.w += 0.5f * a.w;
            *(float4*)&hs[rr * T3 + c4 * 4] = cur;
        }
        __syncthreads();
    }
    {
        int r = tid >> 4, c16 = tid & 15;
        float sq = 0.f;
        #pragma unroll
        for (int i = 0; i < 3; i++) { float v = hs[r * T3 + c16 * 3 + i]; sq += v * v; }
        #pragma unroll
        for (int off = 1; off < 16; off <<= 1) sq += __shfl_xor(sq, off);
        if (c16 == 0) q2out[(size_t)blockIdx.x * 16 + r] = sq;
    }
    for (int idx = tid; idx < 16 * 64; idx += 256) {
        int r = idx >> 6, c = idx & 63;
        unsigned short hi = 0, lo = 0;
        if (c < T3) split2(hs[r * T3 + c], hi, lo);
        size_t o = ((size_t)blockIdx.x * 16 + r) * 64 + c;
        qh[o] = hi; ql[o] = lo;
    }
}

// ---- K2a: dist via exact bf16x3 MFMA ----
#define PES 72
__global__ __launch_bounds__(256) void k2a_mfma(
        const unsigned short* __restrict__ qh, const unsigned short* __restrict__ ql,
        const float* __restrict__ q2g,
        const unsigned short* __restrict__ ph, const unsigned short* __restrict__ pl,
        const float* __restrict__ m2, const float* __restrict__ cw,
        float* __restrict__ dist, int rowbase) {
    __shared__ __align__(16) unsigned short pesh[256 * PES];
    __shared__ __align__(16) unsigned short pesl[256 * PES];
    __shared__ float q2s[64];
    int tid = threadIdx.x, lane = tid & 63, wv = tid >> 6;
    int c0 = blockIdx.x * 256;
    int r0 = blockIdx.y * 64;
    int grow0 = rowbase + r0;
    for (int idx = tid; idx < 2048; idx += 256) {
        int col = idx >> 3, ch = idx & 7;
        *(uint4*)&pesh[col * PES + ch * 8] = *(const uint4*)&ph[(size_t)(c0 + col) * 64 + ch * 8];
        *(uint4*)&pesl[col * PES + ch * 8] = *(const uint4*)&pl[(size_t)(c0 + col) * 64 + ch * 8];
    }
    if (tid < 64) q2s[tid] = q2g[grow0 + tid];
    int lm = lane & 15, lk8 = (lane >> 4) * 8;
    short8 bqh[4][2], bql[4][2];
    #pragma unroll
    for (int qs = 0; qs < 4; qs++)
        #pragma unroll
        for (int ks = 0; ks < 2; ks++) {
            size_t o = (size_t)(grow0 + qs * 16 + lm) * 64 + ks * 32 + lk8;
            bqh[qs][ks] = *(const short8*)&qh[o];
            bql[qs][ks] = *(const short8*)&ql[o];
        }
    __syncthreads();
    f32x4 acc[4][4];
    #pragma unroll
    for (int i = 0; i < 4; i++)
        #pragma unroll
        for (int j = 0; j < 4; j++) acc[i][j] = (f32x4)(0.f);
    int mco = wv * 64;
    #pragma unroll
    for (int ms = 0; ms < 4; ms++) {
        int arow = mco + ms * 16 + lm;
        short8 ah0 = *(const short8*)&pesh[arow * PES + lk8];
        short8 ah1 = *(const short8*)&pesh[arow * PES + 32 + lk8];
        short8 al0 = *(const short8*)&pesl[arow * PES + lk8];
        short8 al1 = *(const short8*)&pesl[arow * PES + 32 + lk8];
        #pragma unroll
        for (int qs = 0; qs < 4; qs++) {
            f32x4 a = acc[ms][qs];
            a = __builtin_amdgcn_mfma_f32_16x16x32_bf16(ah0, bqh[qs][0], a, 0, 0, 0);
            a = __builtin_amdgcn_mfma_f32_16x16x32_bf16(ah1, bqh[qs][1], a, 0, 0, 0);
            a = __builtin_amdgcn_mfma_f32_16x16x32_bf16(ah0, bql[qs][0], a, 0, 0, 0);
            a = __builtin_amdgcn_mfma_f32_16x16x32_bf16(ah1, bql[qs][1], a, 0, 0, 0);
            a = __builtin_amdgcn_mfma_f32_16x16x32_bf16(al0, bqh[qs][0], a, 0, 0, 0);
            a = __builtin_amdgcn_mfma_f32_16x16x32_bf16(al1, bqh[qs][1], a, 0, 0, 0);
            acc[ms][qs] = a;
        }
    }
    int mr4 = (lane >> 4) * 4;
    #pragma unroll
    for (int ms = 0; ms < 4; ms++) {
        int gm = c0 + mco + ms * 16 + mr4;
        float4 m2v = *(const float4*)&m2[gm];
        float4 cwv = *(const float4*)&cw[gm];
        #pragma unroll
        for (int qs = 0; qs < 4; qs++) {
            int lr = r0 + qs * 16 + lm;
            float q2 = q2s[qs * 16 + lm];
            f32x4 a = acc[ms][qs];
            float4 o;
            o.x = fmaxf(q2 + m2v.x - 2.f * a[0], 0.f) * cwv.x;
            o.y = fmaxf(q2 + m2v.y - 2.f * a[1], 0.f) * cwv.y;
            o.z = fmaxf(q2 + m2v.z - 2.f * a[2], 0.f) * cwv.z;
            o.w = fmaxf(q2 + m2v.w - 2.f * a[3], 0.f) * cwv.w;
            *(float4*)&dist[(size_t)lr * MSLOT + gm] = o;
        }
    }
}

// ---- K2b v4: narrow-window histogram top-48 (exact, deterministic) ----
#define NBIN2 2048
#define MAXCAND 1024
__global__ __launch_bounds__(256) void k2b_topk(const float* __restrict__ dist,
        float* __restrict__ topv, int* __restrict__ topi,
        float* __restrict__ rowmin, int rowbase) {
    __shared__ unsigned int hist[NBIN2];           // 8KB
    __shared__ unsigned long long cand[MAXCAND];   // 8KB
    __shared__ float s_wmin[4], s_wmax[4];
    __shared__ unsigned int wsum[4];
    __shared__ unsigned int s_B, s_ncand;
    int tid = threadIdx.x, lane = tid & 63, wv = tid >> 6;
    int rl = blockIdx.x;
    size_t row = (size_t)(rowbase + rl);
    const float4* src = (const float4*)(dist + (size_t)rl * MSLOT);
    float fv[32];
    #pragma unroll
    for (int j = 0; j < 8; j++) {
        float4 v = src[tid + 256 * j];
        fv[j * 4 + 0] = v.x; fv[j * 4 + 1] = v.y;
        fv[j * 4 + 2] = v.z; fv[j * 4 + 3] = v.w;
    }
    float mn = fv[0], mx = fv[0];
    #pragma unroll
    for (int j = 1; j < 32; j++) { mn = fminf(mn, fv[j]); mx = fmaxf(mx, fv[j]); }
    #pragma unroll
    for (int off = 32; off; off >>= 1) {
        mn = fminf(mn, __shfl_xor(mn, off));
        mx = fmaxf(mx, __shfl_xor(mx, off));
    }
    if (lane == 0) { s_wmin[wv] = mn; s_wmax[wv] = mx; }
    __syncthreads();
    float m0 = fminf(fminf(s_wmin[0], s_wmin[1]), fminf(s_wmin[2], s_wmin[3]));
    float mX = fmaxf(fmaxf(s_wmax[0], s_wmax[1]), fmaxf(s_wmax[2], s_wmax[3]));
    float lo = m0;
    float width = fmaxf(m0 * 0.5f, 1e-3f);
    float fullw = fmaxf((mX - m0) * 1.0001f, 1e-3f) + 1e-6f;
    unsigned B = 0;
    float scale = 0.f, hiT = 0.f;
    for (int att = 0; att < 7; att++) {
        if (att == 6 || width > fullw) width = fullw;
        hiT = lo + width;
        scale = (float)NBIN2 / width;
        for (int i = tid; i < NBIN2; i += 256) hist[i] = 0;
        __syncthreads();
        #pragma unroll
        for (int j = 0; j < 32; j++) {
            float v = fv[j];
            if (v < hiT) {
                int b = (int)((v - lo) * scale);
                b = b < NBIN2 - 1 ? b : NBIN2 - 1;
                atomicAdd(&hist[b], 1u);
            }
        }
        __syncthreads();
        unsigned hb[8];
        unsigned s = 0;
        #pragma unroll
        for (int i = 0; i < 8; i++) { hb[i] = hist[tid * 8 + i]; s += hb[i]; }
        unsigned v = s;
        #pragma unroll
        for (int off = 1; off < 64; off <<= 1) {
            unsigned o = __shfl_up(v, off);
            if (lane >= off) v += o;
        }
        if (lane == 63) wsum[wv] = v;
        __syncthreads();
        unsigned wbase = 0;
        for (int w = 0; w < wv; w++) wbase += wsum[w];
        unsigned total = wsum[0] + wsum[1] + wsum[2] + wsum[3];
        if (total >= KBIG) {
            unsigned excl = wbase + v - s;
            if (excl < KBIG && KBIG <= excl + s) {
                unsigned c = excl;
                #pragma unroll
                for (int i = 0; i < 8; i++) {
                    if (c < KBIG && KBIG <= c + hb[i]) { s_B = tid * 8 + i; break; }
                    c += hb[i];
                }
            }
            __syncthreads();
            B = s_B;
            break;
        }
        width *= 8.f;
        __syncthreads();
    }
    if (tid == 0) s_ncand = 0;
    __syncthreads();
    #pragma unroll
    for (int j = 0; j < 32; j++) {
        float v = fv[j];
        if (v < hiT) {
            int b = (int)((v - lo) * scale);
            b = b < NBIN2 - 1 ? b : NBIN2 - 1;
            if ((unsigned)b <= B) {
                unsigned n = atomicAdd(&s_ncand, 1u);
                if (n < MAXCAND) {
                    int m = ((tid + 256 * (j >> 2)) << 2) + (j & 3);
                    cand[n] = ((unsigned long long)__float_as_uint(v) << 32) | (unsigned)m;
                }
            }
        }
    }
    __syncthreads();
    int nc = (int)(s_ncand < MAXCAND ? s_ncand : MAXCAND);
    for (int i = tid; i < nc; i += 256) {
        unsigned long long me = cand[i];
        int rank = 0;
        for (int j = 0; j < nc; j++) rank += (cand[j] < me) ? 1 : 0;
        if (rank < KBIG) {
            float v = __uint_as_float((unsigned)(me >> 32));
            topv[row * KBIG + rank] = v;
            topi[row * KBIG + rank] = (int)(me & 0xFFFFFFFFu);
            if (rank == 0) rowmin[row] = v;
        }
    }
}

// ---- K3a: fire flag ----
__global__ __launch_bounds__(256) void k3a_flag(const float* __restrict__ rowmin,
        int* __restrict__ flag) {
    __shared__ float red[256];
    int tid = threadIdx.x;
    float s = 0.f;
    for (int j = 0; j < NQ / 256; j++) s += rowmin[tid + 256 * j];
    red[tid] = s;
    __syncthreads();
    for (int st = 128; st; st >>= 1) {
        if (tid < st) red[tid] += red[tid + st];
        __syncthreads();
    }
    if (tid == 0) {
        float top1 = red[0] / (float)NQ;
        flag[0] = (top1 < 0.7f) ? 1 : 0;
    }
}

// ---- K3: wave per row; float4 gathers; writes att as bf16 ----
__global__ __launch_bounds__(256) void k3_attend(const float* __restrict__ topv,
        const int* __restrict__ topi, const int* __restrict__ flag,
        const float* __restrict__ slots, unsigned short* __restrict__ attb) {
    int tid = threadIdx.x;
    int lane = tid & 63, wv = tid >> 6;
    size_t row = (size_t)blockIdx.x * 4 + wv;
    int kc = flag[0] ? KBIG : KBASE;
    float v0 = topv[row * KBIG];
    float ev = 0.f;
    int mi = 0;
    if (lane < KBIG) {
        float v = topv[row * KBIG + lane];
        ev = (lane < kc) ? expf(-(v - v0)) : 0.f;
        mi = topi[row * KBIG + lane];
    }
    float ssum = ev;
    #pragma unroll
    for (int off = 32; off; off >>= 1) ssum += __shfl_xor(ssum, off);
    float inv = 1.f / ssum;
    float4 acc = make_float4(0.f, 0.f, 0.f, 0.f);
    for (int k = 0; k < kc; k++) {
        float wk = __shfl(ev, k) * inv;
        int m = __shfl(mi, k);
        float4 v = *(const float4*)(slots + (size_t)m * HD + lane * 4);
        acc.x += wk * v.x; acc.y += wk * v.y;
        acc.z += wk * v.z; acc.w += wk * v.w;
    }
    ushort4 o;
    o.x = bf16_rne(acc.x); o.y = bf16_rne(acc.y);
    o.z = bf16_rne(acc.z); o.w = bf16_rne(acc.w);
    *(ushort4*)(attb + row * HD + lane * 4) = o;
}

// ---- K4: out = att(bf16) @ Wo_t(bf16)^T + bo via MFMA ----
__global__ __launch_bounds__(256) void k4_mfma(const unsigned short* __restrict__ A,
        const unsigned short* __restrict__ Bt, const float* __restrict__ bo,
        float* __restrict__ out) {
    int tid = threadIdx.x;
    int lane = tid & 63, wave = tid >> 6;
    int wm = wave >> 1, wn = wave & 1;
    int mbase = blockIdx.y * 128 + wm * 64;
    int nbase = blockIdx.x * 128 + wn * 64;
    int lm = lane & 15;
    int lk8 = (lane >> 4) * 8;
    f32x4 acc[4][4];
    #pragma unroll
    for (int i = 0; i < 4; i++)
        #pragma unroll
        for (int j = 0; j < 4; j++) acc[i][j] = (f32x4)(0.f);
    #pragma unroll 2
    for (int ks = 0; ks < 8; ks++) {
        int kofs = ks * 32 + lk8;
        short8 a[4], b[4];
        #pragma unroll
        for (int i = 0; i < 4; i++)
            a[i] = *(const short8*)(A + (size_t)(mbase + i * 16 + lm) * HD + kofs);
        #pragma unroll
        for (int j = 0; j < 4; j++)
            b[j] = *(const short8*)(Bt + (size_t)(nbase + j * 16 + lm) * HD + kofs);
        #pragma unroll
        for (int i = 0; i < 4; i++)
            #pragma unroll
            for (int j = 0; j < 4; j++)
                acc[i][j] = __builtin_amdgcn_mfma_f32_16x16x32_bf16(a[i], b[j], acc[i][j], 0, 0, 0);
    }
    int orow = (lane >> 4) * 4;
    #pragma unroll
    for (int i = 0; i < 4; i++)
        #pragma unroll
        for (int j = 0; j < 4; j++) {
            int col = nbase + j * 16 + lm;
            float bias = bo[col];
            #pragma unroll
            for (int r = 0; r < 4; r++) {
                int row = mbase + i * 16 + orow + r;
                out[(size_t)row * INDIM + col] = acc[i][j][r] + bias;
            }
        }
}

// ---- K5: LN + GELU in place ----
__global__ __launch_bounds__(256) void k5_ln(float* __restrict__ out,
        const float* __restrict__ g, const float* __restrict__ b) {
    __shared__ float red[4];
    int tid = threadIdx.x;
    size_t row = blockIdx.x;
    float4 v = *(const float4*)(out + row * INDIM + tid * 4);
    float s = v.x + v.y + v.z + v.w;
    #pragma unroll
    for (int off = 32; off; off >>= 1) s += __shfl_xor(s, off);
    int wid = tid >> 6, lane = tid & 63;
    if (!lane) red[wid] = s;
    __syncthreads();
    float mean = (red[0] + red[1] + red[2] + red[3]) * (1.f / (float)INDIM);
    __syncthreads();
    float dx = v.x - mean, dy = v.y - mean, dz = v.z - mean, dw = v.w - mean;
    float ss = dx * dx + dy * dy + dz * dz + dw * dw;
    #pragma unroll
    for (int off = 32; off; off >>= 1) ss += __shfl_xor(ss, off);
    if (!lane) red[wid] = ss;
    __syncthreads();
    float var = (red[0] + red[1] + red[2] + red[3]) * (1.f / (float)INDIM);
    float rs = rsqrtf(var + 1e-5f);
    int c = tid * 4;
    float4 o;
    o.x = gelu_exact(dx * rs * g[c + 0] + b[c + 0]);
    o.y = gelu_exact(dy * rs * g[c + 1] + b[c + 1]);
    o.z = gelu_exact(dz * rs * g[c + 2] + b[c + 2]);
    o.w = gelu_exact(dw * rs * g[c + 3] + b[c + 3]);
    *(float4*)(out + row * INDIM + c) = o;
}

extern "C" void kernel_launch(void* const* d_in, const int* in_sizes, int n_in,
                              void* d_out, int out_size, void* d_ws, size_t ws_size,
                              hipStream_t stream) {
    const float* x     = (const float*)d_in[0];
    const float* Wp    = (const float*)d_in[1];
    const float* bp    = (const float*)d_in[2];
    const float* ln1g  = (const float*)d_in[3];
    const float* ln1b  = (const float*)d_in[4];
    const float* oW1   = (const float*)d_in[5];
    const float* ob1   = (const float*)d_in[6];
    const float* oW2   = (const float*)d_in[7];
    const float* ob2   = (const float*)d_in[8];
    const float* slots = (const float*)d_in[9];
    const float* pe    = (const float*)d_in[10];
    const float* curv  = (const float*)d_in[11];
    const float* alpha = (const float*)d_in[12];
    const float* Wo    = (const float*)d_in[13];
    const float* bo    = (const float*)d_in[14];
    const float* ln2g  = (const float*)d_in[15];
    const float* ln2b  = (const float*)d_in[16];
    float* out = (float*)d_out;
    char* ws = (char*)d_ws;

    unsigned short* qhp = (unsigned short*)(ws + OFF_QH);
    unsigned short* qlp = (unsigned short*)(ws + OFF_QL);
    float* q2p    = (float*)(ws + OFF_Q2);
    float* m2     = (float*)(ws + OFF_M2);
    float* cwv    = (float*)(ws + OFF_CW);
    float* topv   = (float*)(ws + OFF_TOPV);
    int*   topi   = (int*)  (ws + OFF_TOPI);
    float* rowmin = (float*)(ws + OFF_RMIN);
    int*   flag   = (int*)  (ws + OFF_FLAG);
    unsigned short* wot  = (unsigned short*)(ws + OFF_WOT);
    unsigned short* peh  = (unsigned short*)(ws + OFF_PEH);
    unsigned short* pel  = (unsigned short*)(ws + OFF_PEL);
    unsigned short* wpth = (unsigned short*)(ws + OFF_WPTH);
    unsigned short* wptl = (unsigned short*)(ws + OFF_WPTL);
    float* h0     = (float*)(ws + OFF_H0);
    unsigned short* xh = (unsigned short*)(ws + OFF_BIG);
    unsigned short* xl = (unsigned short*)(ws + OFF_BIG + (size_t)16777216);
    float* dist   = (float*)(ws + OFF_BIG);              // after xh/xl dead
    unsigned short* attb = (unsigned short*)(ws + OFF_BIG);  // after dist dead

    k0_prep<<<MSLOT / 256, 256, 0, stream>>>(pe, curv, alpha, m2, cwv, peh, pel);
    k0b_cvt<<<dim3(4, 16), 256, 0, stream>>>(Wo, wot);
    k0c_xsplit<<<(NQ * INDIM) / 2048, 256, 0, stream>>>(x, xh, xl);
    k0d_wpt<<<T3, 256, 0, stream>>>(Wp, wpth, wptl);
    k1_mfma<<<NQ / 32, 256, 0, stream>>>(xh, xl, wpth, wptl, h0);
    k1b_ode<<<NQ / 16, 256, 0, stream>>>(h0, bp, ln1g, ln1b, oW1, ob1, oW2, ob2,
                                         qhp, qlp, q2p);
    for (int ch = 0; ch < NQ / CHUNK; ch++) {
        k2a_mfma<<<dim3(MSLOT / 256, CHUNK / 64), 256, 0, stream>>>(
            qhp, qlp, q2p, peh, pel, m2, cwv, dist, ch * CHUNK);
        k2b_topk<<<CHUNK, 256, 0, stream>>>(dist, topv, topi, rowmin, ch * CHUNK);
    }
    k3a_flag<<<1, 256, 0, stream>>>(rowmin, flag);
    k3_attend<<<NQ / 4, 256, 0, stream>>>(topv, topi, flag, slots, attb);
    k4_mfma<<<dim3(INDIM / 128, NQ / 128), 256, 0, stream>>>(attb, wot, bo, out);
    k5_ln<<<NQ, 256, 0, stream>>>(out, ln2g, ln2b);
}

// Round 8
// 296.424 us; speedup vs baseline: 3.2838x; 1.3382x over previous
//
#include <hip/hip_runtime.h>
#include <math.h>

#define NQ    8192   // B*S
#define T3    48
#define INDIM 1024
#define HID   128
#define MSLOT 8192
#define HD    256
#define KBIG  48
#define KBASE 32
#define CHUNK 4096

// ---- workspace layout (bytes); ws = 256 MiB (poison fill shows 262144 KB) ----
#define OFF_QH    ((size_t)0)           // 8192*64 bf16 = 1,048,576
#define OFF_QL    ((size_t)1048576)
#define OFF_Q2    ((size_t)2097152)     // 8192 f32
#define OFF_M2    ((size_t)2129920)
#define OFF_CW    ((size_t)2162688)
#define OFF_TOPV  ((size_t)2195456)     // 8192*48 f32
#define OFF_TOPI  ((size_t)3768320)
#define OFF_RMIN  ((size_t)5341184)
#define OFF_FLAG  ((size_t)5373952)
#define OFF_WOT   ((size_t)5374208)     // 1024*256 bf16 = 524,288
#define OFF_PEH   ((size_t)5898496)     // 8192*64 bf16
#define OFF_PEL   ((size_t)6947072)
#define OFF_WPTH  ((size_t)7995648)     // 48*1024 bf16 = 98,304
#define OFF_WPTL  ((size_t)8093952)
#define OFF_H0    ((size_t)8192256)     // 8192*48 f32 = 1,572,864
#define OFF_BIG   ((size_t)9765120)     // time-shared region:
//   xh = BIG, xl = BIG+16,777,216   (k0c writes, k1_mfma reads, then dead)
//   dist = BIG (4096*8192 f32 = 134.2MB)  (k2a writes, k2b reads, then dead)
//   attb = BIG                      (k3 writes, k4 reads)
// end = 9,765,120 + 134,217,728 = 143,982,848 < 256 MiB

typedef __attribute__((ext_vector_type(8))) short short8;
typedef __attribute__((ext_vector_type(4))) float f32x4;

__device__ __forceinline__ float gelu_exact(float x) {
    return 0.5f * x * (1.0f + erff(x * 0.70710678118654752f));
}

__device__ __forceinline__ unsigned short bf16_rne(float f) {
    unsigned int x = __float_as_uint(f);
    unsigned int r = (x + 0x7fffu + ((x >> 16) & 1u)) >> 16;
    return (unsigned short)r;
}

__device__ __forceinline__ void split2(float x, unsigned short& h, unsigned short& l) {
    h = bf16_rne(x);
    l = bf16_rne(x - __uint_as_float((unsigned)h << 16));
}

// ---- K0: m2, cw, pe hi/lo bf16 (K padded to 64) ----
__global__ __launch_bounds__(256) void k0_prep(const float* __restrict__ pe,
        const float* __restrict__ curv, const float* __restrict__ alpha,
        float* __restrict__ m2, float* __restrict__ cw,
        unsigned short* __restrict__ ph, unsigned short* __restrict__ pl) {
    int m = blockIdx.x * 256 + threadIdx.x;
    float s = 0.f;
    for (int d = 0; d < T3; d++) { float v = pe[(size_t)m * T3 + d]; s += v * v; }
    m2[m] = s;
    float c = 0.f;
    for (int d = 0; d < 16; d++) { float v = curv[m * 16 + d]; c += v * v; }
    cw[m] = expf(-alpha[0] * sqrtf(c));
    int base = blockIdx.x * 256;
    for (int idx = threadIdx.x; idx < 256 * 64; idx += 256) {
        int r = idx >> 6, cc = idx & 63;
        unsigned short hi = 0, lo = 0;
        if (cc < T3) split2(pe[(size_t)(base + r) * T3 + cc], hi, lo);
        size_t o = (size_t)(base + r) * 64 + cc;
        ph[o] = hi; pl[o] = lo;
    }
}

// ---- K0b: Wo_t[n][k] = bf16(Wo[k][n]) ----
__global__ __launch_bounds__(256) void k0b_cvt(const float* __restrict__ Wo,
        unsigned short* __restrict__ Wot) {
    __shared__ float t[64][65];
    int k0 = blockIdx.x * 64;
    int n0 = blockIdx.y * 64;
    int c = threadIdx.x & 63, r4 = threadIdx.x >> 6;
    #pragma unroll
    for (int i = 0; i < 16; i++) {
        int kr = i * 4 + r4;
        t[kr][c] = Wo[(size_t)(k0 + kr) * INDIM + n0 + c];
    }
    __syncthreads();
    #pragma unroll
    for (int i = 0; i < 16; i++) {
        int nr = i * 4 + r4;
        Wot[(size_t)(n0 + nr) * HD + k0 + c] = bf16_rne(t[c][nr]);
    }
}

// ---- K0c: split x into bf16 hi/lo ----
__global__ __launch_bounds__(256) void k0c_xsplit(const float* __restrict__ x,
        unsigned short* __restrict__ xh, unsigned short* __restrict__ xl) {
    size_t base = ((size_t)blockIdx.x * 256 + threadIdx.x) * 8;
    float4 a = *(const float4*)(x + base);
    float4 b = *(const float4*)(x + base + 4);
    unsigned short h[8], l[8];
    split2(a.x, h[0], l[0]); split2(a.y, h[1], l[1]);
    split2(a.z, h[2], l[2]); split2(a.w, h[3], l[3]);
    split2(b.x, h[4], l[4]); split2(b.y, h[5], l[5]);
    split2(b.z, h[6], l[6]); split2(b.w, h[7], l[7]);
    uint4 hv, lv;
    hv.x = h[0] | ((unsigned)h[1] << 16); hv.y = h[2] | ((unsigned)h[3] << 16);
    hv.z = h[4] | ((unsigned)h[5] << 16); hv.w = h[6] | ((unsigned)h[7] << 16);
    lv.x = l[0] | ((unsigned)l[1] << 16); lv.y = l[2] | ((unsigned)l[3] << 16);
    lv.z = l[4] | ((unsigned)l[5] << 16); lv.w = l[6] | ((unsigned)l[7] << 16);
    *(uint4*)(xh + base) = hv;
    *(uint4*)(xl + base) = lv;
}

// ---- K0d: WpT hi/lo: wpt[n][k] = Wp[k][n] ----
__global__ __launch_bounds__(256) void k0d_wpt(const float* __restrict__ Wp,
        unsigned short* __restrict__ wph, unsigned short* __restrict__ wpl) {
    int n = blockIdx.x;
    for (int k = threadIdx.x; k < INDIM; k += 256) {
        unsigned short h, l;
        split2(Wp[(size_t)k * T3 + n], h, l);
        wph[(size_t)n * INDIM + k] = h;
        wpl[(size_t)n * INDIM + k] = l;
    }
}

// ---- K1: h0 = x @ Wp via hi/lo bf16 MFMA (exact to ~1e-5) ----
__global__ __launch_bounds__(256) void k1_mfma(const unsigned short* __restrict__ xh,
        const unsigned short* __restrict__ xl,
        const unsigned short* __restrict__ wph, const unsigned short* __restrict__ wpl,
        float* __restrict__ h0) {
    __shared__ float part[4][32][48];
    int tid = threadIdx.x, lane = tid & 63, wv = tid >> 6;
    int r0 = blockIdx.x * 32;
    int lm = lane & 15, lk8 = (lane >> 4) * 8;
    f32x4 acc[2][3];
    #pragma unroll
    for (int i = 0; i < 2; i++)
        #pragma unroll
        for (int j = 0; j < 3; j++) acc[i][j] = (f32x4)(0.f);
    int kw = wv * 256;
    #pragma unroll 2
    for (int ks = 0; ks < 8; ks++) {
        int kofs = kw + ks * 32 + lk8;
        short8 ah[2], al[2], bh[3], bl[3];
        #pragma unroll
        for (int i = 0; i < 2; i++) {
            size_t ao = (size_t)(r0 + i * 16 + lm) * INDIM + kofs;
            ah[i] = *(const short8*)(xh + ao);
            al[i] = *(const short8*)(xl + ao);
        }
        #pragma unroll
        for (int j = 0; j < 3; j++) {
            size_t bo = (size_t)(j * 16 + lm) * INDIM + kofs;
            bh[j] = *(const short8*)(wph + bo);
            bl[j] = *(const short8*)(wpl + bo);
        }
        #pragma unroll
        for (int i = 0; i < 2; i++)
            #pragma unroll
            for (int j = 0; j < 3; j++) {
                f32x4 a = acc[i][j];
                a = __builtin_amdgcn_mfma_f32_16x16x32_bf16(ah[i], bh[j], a, 0, 0, 0);
                a = __builtin_amdgcn_mfma_f32_16x16x32_bf16(ah[i], bl[j], a, 0, 0, 0);
                a = __builtin_amdgcn_mfma_f32_16x16x32_bf16(al[i], bh[j], a, 0, 0, 0);
                acc[i][j] = a;
            }
    }
    int orow = (lane >> 4) * 4;
    #pragma unroll
    for (int i = 0; i < 2; i++)
        #pragma unroll
        for (int j = 0; j < 3; j++)
            #pragma unroll
            for (int r = 0; r < 4; r++)
                part[wv][i * 16 + orow + r][j * 16 + lm] = acc[i][j][r];
    __syncthreads();
    for (int idx = tid; idx < 32 * 48; idx += 256) {
        int rr = idx / 48, cc = idx - rr * 48;
        float s = part[0][rr][cc] + part[1][rr][cc] + part[2][rr][cc] + part[3][rr][cc];
        h0[(size_t)(r0 + rr) * T3 + cc] = s;
    }
}

// ---- K1b: 16 rows/block: bias + LN + GELU + 2 ODE steps -> qh/ql/q2 ----
__global__ __launch_bounds__(256) void k1b_ode(const float* __restrict__ h0,
        const float* __restrict__ bp,
        const float* __restrict__ g1, const float* __restrict__ b1ln,
        const float* __restrict__ W1, const float* __restrict__ bb1,
        const float* __restrict__ W2, const float* __restrict__ bb2,
        unsigned short* __restrict__ qh, unsigned short* __restrict__ ql,
        float* __restrict__ q2out) {
    __shared__ __align__(16) float W1s[T3 * HID];
    __shared__ __align__(16) float W2s[HID * T3];
    __shared__ __align__(16) float hs[16 * T3];
    __shared__ __align__(16) float t1s[16 * 132];
    int tid = threadIdx.x;
    size_t base = (size_t)blockIdx.x * 16 * T3;
    for (int i = tid; i < 1536; i += 256) {
        *(float4*)&W1s[i * 4] = *(const float4*)&W1[i * 4];
        *(float4*)&W2s[i * 4] = *(const float4*)&W2[i * 4];
    }
    for (int idx = tid; idx < 16 * T3; idx += 256) {
        int c = idx % T3;
        t1s[idx] = bp[c] + h0[base + idx];
    }
    __syncthreads();
    {
        int r = tid >> 4, c16 = tid & 15;
        float v[3];
        float ssum = 0.f;
        #pragma unroll
        for (int i = 0; i < 3; i++) { v[i] = t1s[r * T3 + c16 * 3 + i]; ssum += v[i]; }
        #pragma unroll
        for (int off = 1; off < 16; off <<= 1) ssum += __shfl_xor(ssum, off);
        float mean = ssum * (1.f / T3);
        float vv = 0.f;
        #pragma unroll
        for (int i = 0; i < 3; i++) { v[i] -= mean; vv += v[i] * v[i]; }
        #pragma unroll
        for (int off = 1; off < 16; off <<= 1) vv += __shfl_xor(vv, off);
        float rstd = rsqrtf(vv * (1.f / T3) + 1e-5f);
        #pragma unroll
        for (int i = 0; i < 3; i++) {
            int c = c16 * 3 + i;
            hs[r * T3 + c] = gelu_exact(v[i] * rstd * g1[c] + b1ln[c]);
        }
    }
    __syncthreads();
    for (int step = 0; step < 2; step++) {
        #pragma unroll
        for (int it = 0; it < 2; it++) {
            int idx = tid + it * 256;
            int rr = idx >> 5, j4 = idx & 31;
            float4 a = *(const float4*)&bb1[j4 * 4];
            #pragma unroll 3
            for (int d4 = 0; d4 < 12; d4++) {
                float4 qv = *(const float4*)&hs[rr * T3 + d4 * 4];
                float qa[4] = {qv.x, qv.y, qv.z, qv.w};
                #pragma unroll
                for (int dd = 0; dd < 4; dd++) {
                    float4 wv = *(const float4*)&W1s[(d4 * 4 + dd) * HID + j4 * 4];
                    a.x += qa[dd] * wv.x; a.y += qa[dd] * wv.y;
                    a.z += qa[dd] * wv.z; a.w += qa[dd] * wv.w;
                }
            }
            a.x = tanhf(a.x); a.y = tanhf(a.y); a.z = tanhf(a.z); a.w = tanhf(a.w);
            *(float4*)&t1s[rr * 132 + j4 * 4] = a;
        }
        __syncthreads();
        if (tid < 192) {
            int rr = tid / 12, c4 = tid % 12;
            float4 a = *(const float4*)&bb2[c4 * 4];
            #pragma unroll 4
            for (int j4 = 0; j4 < 32; j4++) {
                float4 tv = *(const float4*)&t1s[rr * 132 + j4 * 4];
                float ta[4] = {tv.x, tv.y, tv.z, tv.w};
                #pragma unroll
                for (int jj = 0; jj < 4; jj++) {
                    float4 wv = *(const float4*)&W2s[(j4 * 4 + jj) * T3 + c4 * 4];
                    a.x += ta[jj] * wv.x; a.y += ta[jj] * wv.y;
                    a.z += ta[jj] * wv.z; a.w += ta[jj] * wv.w;
                }
            }
            float4 cur = *(const float4*)&hs[rr * T3 + c4 * 4];
            cur.x += 0.5f * a.x; cur.y += 0.5f * a.y;
            cur.z += 0.5f * a.z; cur.w += 0.5f * a.w;
            *(float4*)&hs[rr * T3 + c4 * 4] = cur;
        }
        __syncthreads();
    }
    {
        int r = tid >> 4, c16 = tid & 15;
        float sq = 0.f;
        #pragma unroll
        for (int i = 0; i < 3; i++) { float v = hs[r * T3 + c16 * 3 + i]; sq += v * v; }
        #pragma unroll
        for (int off = 1; off < 16; off <<= 1) sq += __shfl_xor(sq, off);
        if (c16 == 0) q2out[(size_t)blockIdx.x * 16 + r] = sq;
    }
    for (int idx = tid; idx < 16 * 64; idx += 256) {
        int r = idx >> 6, c = idx & 63;
        unsigned short hi = 0, lo = 0;
        if (c < T3) split2(hs[r * T3 + c], hi, lo);
        size_t o = ((size_t)blockIdx.x * 16 + r) * 64 + c;
        qh[o] = hi; ql[o] = lo;
    }
}

// ---- K2a: dist via exact bf16x3 MFMA; LDS-transposed coalesced stores ----
#define PES 72
__global__ __launch_bounds__(256) void k2a_mfma(
        const unsigned short* __restrict__ qh, const unsigned short* __restrict__ ql,
        const float* __restrict__ q2g,
        const unsigned short* __restrict__ ph, const unsigned short* __restrict__ pl,
        const float* __restrict__ m2, const float* __restrict__ cw,
        float* __restrict__ dist, int rowbase) {
    __shared__ __align__(16) char smem[2 * 256 * PES * 2];   // 73,728 B (pes; later dt)
    __shared__ float q2s[64];
    unsigned short* pesh = (unsigned short*)smem;
    unsigned short* pesl = (unsigned short*)smem + 256 * PES;
    int tid = threadIdx.x, lane = tid & 63, wv = tid >> 6;
    int c0 = blockIdx.x * 256;
    int r0 = blockIdx.y * 64;
    int grow0 = rowbase + r0;
    for (int idx = tid; idx < 2048; idx += 256) {
        int col = idx >> 3, ch = idx & 7;
        *(uint4*)&pesh[col * PES + ch * 8] = *(const uint4*)&ph[(size_t)(c0 + col) * 64 + ch * 8];
        *(uint4*)&pesl[col * PES + ch * 8] = *(const uint4*)&pl[(size_t)(c0 + col) * 64 + ch * 8];
    }
    if (tid < 64) q2s[tid] = q2g[grow0 + tid];
    int lm = lane & 15, lk8 = (lane >> 4) * 8;
    short8 bqh[4][2], bql[4][2];
    #pragma unroll
    for (int qs = 0; qs < 4; qs++)
        #pragma unroll
        for (int ks = 0; ks < 2; ks++) {
            size_t o = (size_t)(grow0 + qs * 16 + lm) * 64 + ks * 32 + lk8;
            bqh[qs][ks] = *(const short8*)&qh[o];
            bql[qs][ks] = *(const short8*)&ql[o];
        }
    __syncthreads();
    f32x4 acc[4][4];
    #pragma unroll
    for (int i = 0; i < 4; i++)
        #pragma unroll
        for (int j = 0; j < 4; j++) acc[i][j] = (f32x4)(0.f);
    int mco = wv * 64;
    #pragma unroll
    for (int ms = 0; ms < 4; ms++) {
        int arow = mco + ms * 16 + lm;
        short8 ah0 = *(const short8*)&pesh[arow * PES + lk8];
        short8 ah1 = *(const short8*)&pesh[arow * PES + 32 + lk8];
        short8 al0 = *(const short8*)&pesl[arow * PES + lk8];
        short8 al1 = *(const short8*)&pesl[arow * PES + 32 + lk8];
        #pragma unroll
        for (int qs = 0; qs < 4; qs++) {
            f32x4 a = acc[ms][qs];
            a = __builtin_amdgcn_mfma_f32_16x16x32_bf16(ah0, bqh[qs][0], a, 0, 0, 0);
            a = __builtin_amdgcn_mfma_f32_16x16x32_bf16(ah1, bqh[qs][1], a, 0, 0, 0);
            a = __builtin_amdgcn_mfma_f32_16x16x32_bf16(ah0, bql[qs][0], a, 0, 0, 0);
            a = __builtin_amdgcn_mfma_f32_16x16x32_bf16(ah1, bql[qs][1], a, 0, 0, 0);
            a = __builtin_amdgcn_mfma_f32_16x16x32_bf16(al0, bqh[qs][0], a, 0, 0, 0);
            a = __builtin_amdgcn_mfma_f32_16x16x32_bf16(al1, bqh[qs][1], a, 0, 0, 0);
            acc[ms][qs] = a;
        }
    }
    // transform in registers
    int mr4 = (lane >> 4) * 4;
    float4 ov[4][4];
    #pragma unroll
    for (int ms = 0; ms < 4; ms++) {
        int gm = c0 + mco + ms * 16 + mr4;
        float4 m2v = *(const float4*)&m2[gm];
        float4 cwv = *(const float4*)&cw[gm];
        #pragma unroll
        for (int qs = 0; qs < 4; qs++) {
            float q2 = q2s[qs * 16 + lm];
            f32x4 a = acc[ms][qs];
            float4 o;
            o.x = fmaxf(q2 + m2v.x - 2.f * a[0], 0.f) * cwv.x;
            o.y = fmaxf(q2 + m2v.y - 2.f * a[1], 0.f) * cwv.y;
            o.z = fmaxf(q2 + m2v.z - 2.f * a[2], 0.f) * cwv.z;
            o.w = fmaxf(q2 + m2v.w - 2.f * a[3], 0.f) * cwv.w;
            ov[ms][qs] = o;
        }
    }
    __syncthreads();   // all waves done reading pes
    float (*dt)[260] = (float(*)[260])smem;   // 64 x 260 f32 = 66,560 B
    #pragma unroll
    for (int ms = 0; ms < 4; ms++)
        #pragma unroll
        for (int qs = 0; qs < 4; qs++)
            *(float4*)&dt[qs * 16 + lm][mco + ms * 16 + mr4] = ov[ms][qs];
    __syncthreads();
    // coalesced stores: wave wv streams rows wv*16 .. wv*16+15 (1KB per row)
    #pragma unroll
    for (int i = 0; i < 16; i++) {
        int qrow = wv * 16 + i;
        float4 v = *(const float4*)&dt[qrow][lane * 4];
        *(float4*)&dist[(size_t)(r0 + qrow) * MSLOT + c0 + lane * 4] = v;
    }
}

// ---- K2b: narrow-window histogram top-48 (exact, deterministic) ----
#define NBIN2 2048
#define MAXCAND 1024
__global__ __launch_bounds__(256) void k2b_topk(const float* __restrict__ dist,
        float* __restrict__ topv, int* __restrict__ topi,
        float* __restrict__ rowmin, int rowbase) {
    __shared__ unsigned int hist[NBIN2];
    __shared__ unsigned long long cand[MAXCAND];
    __shared__ float s_wmin[4], s_wmax[4];
    __shared__ unsigned int wsum[4];
    __shared__ unsigned int s_B, s_ncand;
    int tid = threadIdx.x, lane = tid & 63, wv = tid >> 6;
    int rl = blockIdx.x;
    size_t row = (size_t)(rowbase + rl);
    const float4* src = (const float4*)(dist + (size_t)rl * MSLOT);
    float fv[32];
    #pragma unroll
    for (int j = 0; j < 8; j++) {
        float4 v = src[tid + 256 * j];
        fv[j * 4 + 0] = v.x; fv[j * 4 + 1] = v.y;
        fv[j * 4 + 2] = v.z; fv[j * 4 + 3] = v.w;
    }
    float mn = fv[0], mx = fv[0];
    #pragma unroll
    for (int j = 1; j < 32; j++) { mn = fminf(mn, fv[j]); mx = fmaxf(mx, fv[j]); }
    #pragma unroll
    for (int off = 32; off; off >>= 1) {
        mn = fminf(mn, __shfl_xor(mn, off));
        mx = fmaxf(mx, __shfl_xor(mx, off));
    }
    if (lane == 0) { s_wmin[wv] = mn; s_wmax[wv] = mx; }
    __syncthreads();
    float m0 = fminf(fminf(s_wmin[0], s_wmin[1]), fminf(s_wmin[2], s_wmin[3]));
    float mX = fmaxf(fmaxf(s_wmax[0], s_wmax[1]), fmaxf(s_wmax[2], s_wmax[3]));
    float lo = m0;
    float width = fmaxf(m0 * 0.5f, 1e-3f);
    float fullw = fmaxf((mX - m0) * 1.0001f, 1e-3f) + 1e-6f;
    unsigned B = 0;
    float scale = 0.f, hiT = 0.f;
    for (int att = 0; att < 7; att++) {
        if (att == 6 || width > fullw) width = fullw;
        hiT = lo + width;
        scale = (float)NBIN2 / width;
        for (int i = tid; i < NBIN2; i += 256) hist[i] = 0;
        __syncthreads();
        #pragma unroll
        for (int j = 0; j < 32; j++) {
            float v = fv[j];
            if (v < hiT) {
                int b = (int)((v - lo) * scale);
                b = b < NBIN2 - 1 ? b : NBIN2 - 1;
                atomicAdd(&hist[b], 1u);
            }
        }
        __syncthreads();
        unsigned hb[8];
        unsigned s = 0;
        #pragma unroll
        for (int i = 0; i < 8; i++) { hb[i] = hist[tid * 8 + i]; s += hb[i]; }
        unsigned v = s;
        #pragma unroll
        for (int off = 1; off < 64; off <<= 1) {
            unsigned o = __shfl_up(v, off);
            if (lane >= off) v += o;
        }
        if (lane == 63) wsum[wv] = v;
        __syncthreads();
        unsigned wbase = 0;
        for (int w = 0; w < wv; w++) wbase += wsum[w];
        unsigned total = wsum[0] + wsum[1] + wsum[2] + wsum[3];
        if (total >= KBIG) {
            unsigned excl = wbase + v - s;
            if (excl < KBIG && KBIG <= excl + s) {
                unsigned c = excl;
                #pragma unroll
                for (int i = 0; i < 8; i++) {
                    if (c < KBIG && KBIG <= c + hb[i]) { s_B = tid * 8 + i; break; }
                    c += hb[i];
                }
            }
            __syncthreads();
            B = s_B;
            break;
        }
        width *= 8.f;
        __syncthreads();
    }
    if (tid == 0) s_ncand = 0;
    __syncthreads();
    #pragma unroll
    for (int j = 0; j < 32; j++) {
        float v = fv[j];
        if (v < hiT) {
            int b = (int)((v - lo) * scale);
            b = b < NBIN2 - 1 ? b : NBIN2 - 1;
            if ((unsigned)b <= B) {
                unsigned n = atomicAdd(&s_ncand, 1u);
                if (n < MAXCAND) {
                    int m = ((tid + 256 * (j >> 2)) << 2) + (j & 3);
                    cand[n] = ((unsigned long long)__float_as_uint(v) << 32) | (unsigned)m;
                }
            }
        }
    }
    __syncthreads();
    int nc = (int)(s_ncand < MAXCAND ? s_ncand : MAXCAND);
    for (int i = tid; i < nc; i += 256) {
        unsigned long long me = cand[i];
        int rank = 0;
        for (int j = 0; j < nc; j++) rank += (cand[j] < me) ? 1 : 0;
        if (rank < KBIG) {
            float v = __uint_as_float((unsigned)(me >> 32));
            topv[row * KBIG + rank] = v;
            topi[row * KBIG + rank] = (int)(me & 0xFFFFFFFFu);
            if (rank == 0) rowmin[row] = v;
        }
    }
}

// ---- K3a: fire flag ----
__global__ __launch_bounds__(256) void k3a_flag(const float* __restrict__ rowmin,
        int* __restrict__ flag) {
    __shared__ float red[256];
    int tid = threadIdx.x;
    float s = 0.f;
    for (int j = 0; j < NQ / 256; j++) s += rowmin[tid + 256 * j];
    red[tid] = s;
    __syncthreads();
    for (int st = 128; st; st >>= 1) {
        if (tid < st) red[tid] += red[tid + st];
        __syncthreads();
    }
    if (tid == 0) {
        float top1 = red[0] / (float)NQ;
        flag[0] = (top1 < 0.7f) ? 1 : 0;
    }
}

// ---- K3: wave per row; float4 gathers; writes att as bf16 ----
__global__ __launch_bounds__(256) void k3_attend(const float* __restrict__ topv,
        const int* __restrict__ topi, const int* __restrict__ flag,
        const float* __restrict__ slots, unsigned short* __restrict__ attb) {
    int tid = threadIdx.x;
    int lane = tid & 63, wv = tid >> 6;
    size_t row = (size_t)blockIdx.x * 4 + wv;
    int kc = flag[0] ? KBIG : KBASE;
    float v0 = topv[row * KBIG];
    float ev = 0.f;
    int mi = 0;
    if (lane < KBIG) {
        float v = topv[row * KBIG + lane];
        ev = (lane < kc) ? expf(-(v - v0)) : 0.f;
        mi = topi[row * KBIG + lane];
    }
    float ssum = ev;
    #pragma unroll
    for (int off = 32; off; off >>= 1) ssum += __shfl_xor(ssum, off);
    float inv = 1.f / ssum;
    float4 acc = make_float4(0.f, 0.f, 0.f, 0.f);
    for (int k = 0; k < kc; k++) {
        float wk = __shfl(ev, k) * inv;
        int m = __shfl(mi, k);
        float4 v = *(const float4*)(slots + (size_t)m * HD + lane * 4);
        acc.x += wk * v.x; acc.y += wk * v.y;
        acc.z += wk * v.z; acc.w += wk * v.w;
    }
    ushort4 o;
    o.x = bf16_rne(acc.x); o.y = bf16_rne(acc.y);
    o.z = bf16_rne(acc.z); o.w = bf16_rne(acc.w);
    *(ushort4*)(attb + row * HD + lane * 4) = o;
}

// ---- K4: out = att(bf16) @ Wo_t(bf16)^T + bo via MFMA ----
__global__ __launch_bounds__(256) void k4_mfma(const unsigned short* __restrict__ A,
        const unsigned short* __restrict__ Bt, const float* __restrict__ bo,
        float* __restrict__ out) {
    int tid = threadIdx.x;
    int lane = tid & 63, wave = tid >> 6;
    int wm = wave >> 1, wn = wave & 1;
    int mbase = blockIdx.y * 128 + wm * 64;
    int nbase = blockIdx.x * 128 + wn * 64;
    int lm = lane & 15;
    int lk8 = (lane >> 4) * 8;
    f32x4 acc[4][4];
    #pragma unroll
    for (int i = 0; i < 4; i++)
        #pragma unroll
        for (int j = 0; j < 4; j++) acc[i][j] = (f32x4)(0.f);
    #pragma unroll 2
    for (int ks = 0; ks < 8; ks++) {
        int kofs = ks * 32 + lk8;
        short8 a[4], b[4];
        #pragma unroll
        for (int i = 0; i < 4; i++)
            a[i] = *(const short8*)(A + (size_t)(mbase + i * 16 + lm) * HD + kofs);
        #pragma unroll
        for (int j = 0; j < 4; j++)
            b[j] = *(const short8*)(Bt + (size_t)(nbase + j * 16 + lm) * HD + kofs);
        #pragma unroll
        for (int i = 0; i < 4; i++)
            #pragma unroll
            for (int j = 0; j < 4; j++)
                acc[i][j] = __builtin_amdgcn_mfma_f32_16x16x32_bf16(a[i], b[j], acc[i][j], 0, 0, 0);
    }
    int orow = (lane >> 4) * 4;
    #pragma unroll
    for (int i = 0; i < 4; i++)
        #pragma unroll
        for (int j = 0; j < 4; j++) {
            int col = nbase + j * 16 + lm;
            float bias = bo[col];
            #pragma unroll
            for (int r = 0; r < 4; r++) {
                int row = mbase + i * 16 + orow + r;
                out[(size_t)row * INDIM + col] = acc[i][j][r] + bias;
            }
        }
}

// ---- K5: LN + GELU in place ----
__global__ __launch_bounds__(256) void k5_ln(float* __restrict__ out,
        const float* __restrict__ g, const float* __restrict__ b) {
    __shared__ float red[4];
    int tid = threadIdx.x;
    size_t row = blockIdx.x;
    float4 v = *(const float4*)(out + row * INDIM + tid * 4);
    float s = v.x + v.y + v.z + v.w;
    #pragma unroll
    for (int off = 32; off; off >>= 1) s += __shfl_xor(s, off);
    int wid = tid >> 6, lane = tid & 63;
    if (!lane) red[wid] = s;
    __syncthreads();
    float mean = (red[0] + red[1] + red[2] + red[3]) * (1.f / (float)INDIM);
    __syncthreads();
    float dx = v.x - mean, dy = v.y - mean, dz = v.z - mean, dw = v.w - mean;
    float ss = dx * dx + dy * dy + dz * dz + dw * dw;
    #pragma unroll
    for (int off = 32; off; off >>= 1) ss += __shfl_xor(ss, off);
    if (!lane) red[wid] = ss;
    __syncthreads();
    float var = (red[0] + red[1] + red[2] + red[3]) * (1.f / (float)INDIM);
    float rs = rsqrtf(var + 1e-5f);
    int c = tid * 4;
    float4 o;
    o.x = gelu_exact(dx * rs * g[c + 0] + b[c + 0]);
    o.y = gelu_exact(dy * rs * g[c + 1] + b[c + 1]);
    o.z = gelu_exact(dz * rs * g[c + 2] + b[c + 2]);
    o.w = gelu_exact(dw * rs * g[c + 3] + b[c + 3]);
    *(float4*)(out + row * INDIM + c) = o;
}

extern "C" void kernel_launch(void* const* d_in, const int* in_sizes, int n_in,
                              void* d_out, int out_size, void* d_ws, size_t ws_size,
                              hipStream_t stream) {
    const float* x     = (const float*)d_in[0];
    const float* Wp    = (const float*)d_in[1];
    const float* bp    = (const float*)d_in[2];
    const float* ln1g  = (const float*)d_in[3];
    const float* ln1b  = (const float*)d_in[4];
    const float* oW1   = (const float*)d_in[5];
    const float* ob1   = (const float*)d_in[6];
    const float* oW2   = (const float*)d_in[7];
    const float* ob2   = (const float*)d_in[8];
    const float* slots = (const float*)d_in[9];
    const float* pe    = (const float*)d_in[10];
    const float* curv  = (const float*)d_in[11];
    const float* alpha = (const float*)d_in[12];
    const float* Wo    = (const float*)d_in[13];
    const float* bo    = (const float*)d_in[14];
    const float* ln2g  = (const float*)d_in[15];
    const float* ln2b  = (const float*)d_in[16];
    float* out = (float*)d_out;
    char* ws = (char*)d_ws;

    unsigned short* qhp = (unsigned short*)(ws + OFF_QH);
    unsigned short* qlp = (unsigned short*)(ws + OFF_QL);
    float* q2p    = (float*)(ws + OFF_Q2);
    float* m2     = (float*)(ws + OFF_M2);
    float* cwv    = (float*)(ws + OFF_CW);
    float* topv   = (float*)(ws + OFF_TOPV);
    int*   topi   = (int*)  (ws + OFF_TOPI);
    float* rowmin = (float*)(ws + OFF_RMIN);
    int*   flag   = (int*)  (ws + OFF_FLAG);
    unsigned short* wot  = (unsigned short*)(ws + OFF_WOT);
    unsigned short* peh  = (unsigned short*)(ws + OFF_PEH);
    unsigned short* pel  = (unsigned short*)(ws + OFF_PEL);
    unsigned short* wpth = (unsigned short*)(ws + OFF_WPTH);
    unsigned short* wptl = (unsigned short*)(ws + OFF_WPTL);
    float* h0     = (float*)(ws + OFF_H0);
    unsigned short* xh = (unsigned short*)(ws + OFF_BIG);
    unsigned short* xl = (unsigned short*)(ws + OFF_BIG + (size_t)16777216);
    float* dist   = (float*)(ws + OFF_BIG);                  // after xh/xl dead
    unsigned short* attb = (unsigned short*)(ws + OFF_BIG);  // after dist dead

    k0_prep<<<MSLOT / 256, 256, 0, stream>>>(pe, curv, alpha, m2, cwv, peh, pel);
    k0b_cvt<<<dim3(4, 16), 256, 0, stream>>>(Wo, wot);
    k0c_xsplit<<<(NQ * INDIM) / 2048, 256, 0, stream>>>(x, xh, xl);
    k0d_wpt<<<T3, 256, 0, stream>>>(Wp, wpth, wptl);
    k1_mfma<<<NQ / 32, 256, 0, stream>>>(xh, xl, wpth, wptl, h0);
    k1b_ode<<<NQ / 16, 256, 0, stream>>>(h0, bp, ln1g, ln1b, oW1, ob1, oW2, ob2,
                                         qhp, qlp, q2p);
    for (int ch = 0; ch < NQ / CHUNK; ch++) {
        k2a_mfma<<<dim3(MSLOT / 256, CHUNK / 64), 256, 0, stream>>>(
            qhp, qlp, q2p, peh, pel, m2, cwv, dist, ch * CHUNK);
        k2b_topk<<<CHUNK, 256, 0, stream>>>(dist, topv, topi, rowmin, ch * CHUNK);
    }
    k3a_flag<<<1, 256, 0, stream>>>(rowmin, flag);
    k3_attend<<<NQ / 4, 256, 0, stream>>>(topv, topi, flag, slots, attb);
    k4_mfma<<<dim3(INDIM / 128, NQ / 128), 256, 0, stream>>>(attb, wot, bo, out);
    k5_ln<<<NQ, 256, 0, stream>>>(out, ln2g, ln2b);
}